// Round 1
// baseline (902.293 us; speedup 1.0000x reference)
//
#include <hip/hip_runtime.h>

#define NPOS 1600
#define DIMC 128
#define NHEADS 8
#define CHD 16

// ---------------- workspace layout (floats) ----------------
// 0        xr      204800   (x + LN(pe(x)))
// 204800   qraw    204800
// 409600   kv1t    409600   (1600 x 256, position-major)
// 819200   kbuf    204800
// 1024000  vbuf    204800
// 1228800  qn      204800
// 1433600  kn      204800
// 1638400  outA    204800
// 1843200  w1t     147456   (aspp_w1 transposed [k][o][i])
// 1990656  w2t     147456
// total 2138112 floats = 8.55 MB

__device__ __forceinline__ float wsum(float v) {
#pragma unroll
  for (int off = 1; off < 64; off <<= 1) v += __shfl_xor(v, off);
  return v;
}
__device__ __forceinline__ float wmax(float v) {
#pragma unroll
  for (int off = 1; off < 64; off <<= 1) v = fmaxf(v, __shfl_xor(v, off));
  return v;
}

// -------- transpose 3x3 conv weights: [o][i][k] -> [k][o][i] --------
__global__ void k_transw(const float* __restrict__ w1, const float* __restrict__ w2,
                         float* __restrict__ w1t, float* __restrict__ w2t) {
  int idx = blockIdx.x * 256 + threadIdx.x;
  if (idx < DIMC * DIMC * 9) {
    int k = idx / (DIMC * DIMC);
    int rem = idx % (DIMC * DIMC);
    int o = rem / DIMC, i = rem % DIMC;
    w1t[idx] = w1[(o * DIMC + i) * 9 + k];
    w2t[idx] = w2[(o * DIMC + i) * 9 + k];
  }
}

// -------- pe (1x1 conv) + LayerNorm(ch) + residual --------
__global__ __launch_bounds__(128) void k_pe_ln(
    const float* __restrict__ x, const float* __restrict__ pw,
    const float* __restrict__ pb, const float* __restrict__ lg,
    const float* __restrict__ lb, float* __restrict__ xr) {
  int n = blockIdx.x, t = threadIdx.x;
  __shared__ float xcol[DIMC];
  __shared__ float wred[2];
  float xv = x[t * NPOS + n];
  xcol[t] = xv;
  __syncthreads();
  float acc = pb[t];
  const float4* w4 = (const float4*)(pw + t * DIMC);
  const float4* x4 = (const float4*)xcol;
#pragma unroll
  for (int i = 0; i < 32; i++) {
    float4 w = w4[i];
    float4 xx = x4[i];
    acc += w.x * xx.x + w.y * xx.y + w.z * xx.z + w.w * xx.w;
  }
  float s = wsum(acc);
  if ((t & 63) == 0) wred[t >> 6] = s;
  __syncthreads();
  float mu = (wred[0] + wred[1]) * (1.0f / 128.0f);
  float d = acc - mu;
  __syncthreads();
  float s2 = wsum(d * d);
  if ((t & 63) == 0) wred[t >> 6] = s2;
  __syncthreads();
  float var = (wred[0] + wred[1]) * (1.0f / 128.0f);
  float tv = d * rsqrtf(var + 1e-5f) * lg[t] + lb[t];
  xr[t * NPOS + n] = xv + tv;
}

// -------- ASPP branches (3x3 dil 3 and 5) + bn/relu + proj (1x1) + bn/relu --------
__global__ __launch_bounds__(128) void k_aspp(
    const float* __restrict__ xr, const float* __restrict__ w1t,
    const float* __restrict__ w2t, const float* __restrict__ bg1,
    const float* __restrict__ bb1, const float* __restrict__ bm1,
    const float* __restrict__ bv1, const float* __restrict__ bg2,
    const float* __restrict__ bb2, const float* __restrict__ bm2,
    const float* __restrict__ bv2, const float* __restrict__ pw,
    const float* __restrict__ bgp, const float* __restrict__ bbp,
    const float* __restrict__ bmp, const float* __restrict__ bvp,
    float* __restrict__ q) {
  int strip = blockIdx.x;
  int r = strip / 5, c0 = (strip % 5) * 8;
  int t = threadIdx.x;
  __shared__ float x3[DIMC][9];
  __shared__ float x5[DIMC][9];
  __shared__ float cat[2 * DIMC][9];
  float a1a[8] = {0.f, 0.f, 0.f, 0.f, 0.f, 0.f, 0.f, 0.f};
  float a2a[8] = {0.f, 0.f, 0.f, 0.f, 0.f, 0.f, 0.f, 0.f};
  for (int k = 0; k < 9; k++) {
    int dr = k / 3 - 1, dc = k % 3 - 1;
    int r3 = r + 3 * dr, r5 = r + 5 * dr;
#pragma unroll
    for (int p = 0; p < 8; p++) {
      int c3 = c0 + p + 3 * dc;
      x3[t][p] = (r3 >= 0 && r3 < 40 && c3 >= 0 && c3 < 40) ? xr[t * NPOS + r3 * 40 + c3] : 0.f;
      int c5 = c0 + p + 5 * dc;
      x5[t][p] = (r5 >= 0 && r5 < 40 && c5 >= 0 && c5 < 40) ? xr[t * NPOS + r5 * 40 + c5] : 0.f;
    }
    __syncthreads();
    const float* w1r = w1t + (k * DIMC + t) * DIMC;
    const float* w2r = w2t + (k * DIMC + t) * DIMC;
    for (int i = 0; i < DIMC; i++) {
      float wa = w1r[i], wb = w2r[i];
#pragma unroll
      for (int p = 0; p < 8; p++) {
        a1a[p] += wa * x3[i][p];
        a2a[p] += wb * x5[i][p];
      }
    }
    __syncthreads();
  }
  float sc1 = bg1[t] * rsqrtf(bv1[t] + 1e-5f);
  float sc2 = bg2[t] * rsqrtf(bv2[t] + 1e-5f);
#pragma unroll
  for (int p = 0; p < 8; p++) {
    cat[t][p] = fmaxf((a1a[p] - bm1[t]) * sc1 + bb1[t], 0.f);
    cat[DIMC + t][p] = fmaxf((a2a[p] - bm2[t]) * sc2 + bb2[t], 0.f);
  }
  __syncthreads();
  float qa[8] = {0.f, 0.f, 0.f, 0.f, 0.f, 0.f, 0.f, 0.f};
  const float* pr = pw + t * 256;
  for (int j = 0; j < 256; j++) {
    float w = pr[j];
#pragma unroll
    for (int p = 0; p < 8; p++) qa[p] += w * cat[j][p];
  }
  float scp = bgp[t] * rsqrtf(bvp[t] + 1e-5f);
#pragma unroll
  for (int p = 0; p < 8; p++)
    q[t * NPOS + r * 40 + c0 + p] = fmaxf((qa[p] - bmp[t]) * scp + bbp[t], 0.f);
}

// -------- kv 1x1 conv: xr(128) -> kv1 (256), stored position-major --------
__global__ __launch_bounds__(256) void k_kv1(const float* __restrict__ xr,
                                             const float* __restrict__ kw,
                                             float* __restrict__ kv1t) {
  int n0 = blockIdx.x * 8;
  int t = threadIdx.x;
  __shared__ float xc[DIMC][9];
  for (int j = t; j < DIMC * 8; j += 256) {
    int i = j >> 3, p = j & 7;
    xc[i][p] = xr[i * NPOS + n0 + p];
  }
  __syncthreads();
  float acc[8] = {0.f, 0.f, 0.f, 0.f, 0.f, 0.f, 0.f, 0.f};
  const float* wr = kw + t * DIMC;
  for (int i = 0; i < DIMC; i++) {
    float w = wr[i];
#pragma unroll
    for (int p = 0; p < 8; p++) acc[p] += w * xc[i][p];
  }
#pragma unroll
  for (int p = 0; p < 8; p++) kv1t[(n0 + p) * 256 + t] = acc[p];
}

// -------- depthwise 3x3 (pad 1) -> split into k, v (channel-major) --------
__global__ __launch_bounds__(256) void k_dw(const float* __restrict__ kv1t,
                                            const float* __restrict__ dww,
                                            float* __restrict__ kbuf,
                                            float* __restrict__ vbuf) {
  int strip = blockIdx.x;
  int r = strip / 5, c0 = (strip % 5) * 8;
  int t = threadIdx.x;
  float wl[9];
#pragma unroll
  for (int k = 0; k < 9; k++) wl[k] = dww[t * 9 + k];
  for (int p = 0; p < 8; p++) {
    int c = c0 + p;
    float acc = 0.f;
#pragma unroll
    for (int kh = 0; kh < 3; kh++) {
      int rr = r + kh - 1;
      if (rr < 0 || rr >= 40) continue;
#pragma unroll
      for (int kw_ = 0; kw_ < 3; kw_++) {
        int cc = c + kw_ - 1;
        if (cc < 0 || cc >= 40) continue;
        acc += wl[kh * 3 + kw_] * kv1t[(rr * 40 + cc) * 256 + t];
      }
    }
    int pos = r * 40 + c;
    if (t < DIMC) kbuf[t * NPOS + pos] = acc;
    else vbuf[(t - DIMC) * NPOS + pos] = acc;
  }
}

// -------- per-channel L2 normalization over N --------
__global__ __launch_bounds__(256) void k_norm(const float* __restrict__ in,
                                              float* __restrict__ out) {
  int ch = blockIdx.x, t = threadIdx.x;
  __shared__ float wred[4];
  float ss = 0.f;
  for (int m = t; m < NPOS; m += 256) {
    float v = in[ch * NPOS + m];
    ss += v * v;
  }
  ss = wsum(ss);
  if ((t & 63) == 0) wred[t >> 6] = ss;
  __syncthreads();
  float tot = wred[0] + wred[1] + wred[2] + wred[3];
  float inv = 1.0f / fmaxf(sqrtf(tot), 1e-12f);
  for (int m = t; m < NPOS; m += 256) out[ch * NPOS + m] = in[ch * NPOS + m] * inv;
}

// -------- fused attention: QK^T, 4x exact top-k radix-select, fused 4-softmax PV --------
__global__ __launch_bounds__(256) void k_attn(
    const float* __restrict__ qn, const float* __restrict__ kn,
    const float* __restrict__ vb, const float* __restrict__ temp,
    const float* __restrict__ a1p, const float* __restrict__ a2p,
    const float* __restrict__ a3p, const float* __restrict__ a4p,
    float* __restrict__ outA) {
  __shared__ float S[4][NPOS];
  __shared__ unsigned char Bk[4][NPOS];
  __shared__ unsigned int hist[8][256];
  __shared__ int sAB[2][256];
  __shared__ float wred[4][64];
  __shared__ float qrow[4][CHD];
  __shared__ int winBin[4], winAbove[4];
  __shared__ float thrS[4][4];
  __shared__ float ctab[4][5];

  int tid = threadIdx.x;
  int lane = tid & 63, wave = tid >> 6;
  int bid = blockIdx.x;
  int h = bid / 400;
  int n0 = (bid % 400) * 4;

  if (tid < 64) {
    int r = tid >> 4, c = tid & 15;
    qrow[r][c] = qn[(h * CHD + c) * NPOS + n0 + r];
  }
  __syncthreads();

  // ---- QK^T (4 rows) + row max ----
  float tmpr = temp[h];
  float lm0 = -1e30f, lm1 = -1e30f, lm2 = -1e30f, lm3 = -1e30f;
  for (int it = 0; it < 7; it++) {
    int m = tid + it * 256;
    if (m < NPOS) {
      float d0 = 0.f, d1 = 0.f, d2 = 0.f, d3 = 0.f;
#pragma unroll
      for (int c = 0; c < CHD; c++) {
        float kv = kn[(h * CHD + c) * NPOS + m];
        d0 += qrow[0][c] * kv;
        d1 += qrow[1][c] * kv;
        d2 += qrow[2][c] * kv;
        d3 += qrow[3][c] * kv;
      }
      d0 *= tmpr; d1 *= tmpr; d2 *= tmpr; d3 *= tmpr;
      S[0][m] = d0; S[1][m] = d1; S[2][m] = d2; S[3][m] = d3;
      lm0 = fmaxf(lm0, d0); lm1 = fmaxf(lm1, d1);
      lm2 = fmaxf(lm2, d2); lm3 = fmaxf(lm3, d3);
    }
  }
  {
    float v0 = wmax(lm0), v1 = wmax(lm1), v2 = wmax(lm2), v3 = wmax(lm3);
    if (lane == 0) { wred[wave][0] = v0; wred[wave][1] = v1; wred[wave][2] = v2; wred[wave][3] = v3; }
  }
  __syncthreads();
  float rmax[4];
#pragma unroll
  for (int r = 0; r < 4; r++)
    rmax[r] = fmaxf(fmaxf(wred[0][r], wred[1][r]), fmaxf(wred[2][r], wred[3][r]));

  // ---- exact k-th largest for k = 800,1066,1200,1280 per row (radix select on bits) ----
  for (int r = 0; r < 4; r++) {
    unsigned pref0 = 0, pref1 = 0, pref2 = 0, pref3 = 0;
    int rem0 = 800, rem1 = 1066, rem2 = 1200, rem3 = 1280;
    for (int level = 3; level >= 0; level--) {
      int hs = (level + 1) * 8;
      unsigned procMask = 0;
      for (int j0 = 0; j0 < 4; j0++) {
        if (procMask & (1u << j0)) continue;
        unsigned pj0 = (j0 == 0) ? pref0 : (j0 == 1) ? pref1 : (j0 == 2) ? pref2 : pref3;
        unsigned hp = (level == 3) ? 0u : (pj0 >> hs);
        unsigned gmask = 0;
        if (!(procMask & 1u) && (level == 3 || (pref0 >> hs) == hp)) gmask |= 1u;
        if (!(procMask & 2u) && (level == 3 || (pref1 >> hs) == hp)) gmask |= 2u;
        if (!(procMask & 4u) && (level == 3 || (pref2 >> hs) == hp)) gmask |= 4u;
        if (!(procMask & 8u) && (level == 3 || (pref3 >> hs) == hp)) gmask |= 8u;
        // zero histogram
        for (int z = tid; z < 8 * 256; z += 256) (&hist[0][0])[z] = 0u;
        __syncthreads();
        for (int it = 0; it < 7; it++) {
          int m = tid + it * 256;
          if (m < NPOS) {
            int bi = __float_as_int(S[r][m]);
            unsigned ub = (unsigned)bi;
            unsigned u = ub ^ ((bi < 0) ? 0xFFFFFFFFu : 0x80000000u);
            if (level == 3 || (u >> hs) == hp)
              atomicAdd(&hist[tid & 7][(u >> (level * 8)) & 255], 1u);
          }
        }
        __syncthreads();
        int sum8 = 0;
#pragma unroll
        for (int s8 = 0; s8 < 8; s8++) sum8 += (int)hist[s8][tid];
        sAB[0][tid] = sum8;
        __syncthreads();
        int pp = 0;
        for (int d = 1; d < 256; d <<= 1) {
          int v = sAB[pp][tid] + ((tid + d < 256) ? sAB[pp][tid + d] : 0);
          sAB[pp ^ 1][tid] = v;
          __syncthreads();
          pp ^= 1;
        }
        {
          int here = sAB[pp][tid];
          int above = (tid == 255) ? 0 : sAB[pp][tid + 1];
#pragma unroll
          for (int j = 0; j < 4; j++) {
            if (gmask & (1u << j)) {
              int rem = (j == 0) ? rem0 : (j == 1) ? rem1 : (j == 2) ? rem2 : rem3;
              if (here >= rem && above < rem) { winBin[j] = tid; winAbove[j] = above; }
            }
          }
        }
        __syncthreads();
#pragma unroll
        for (int j = 0; j < 4; j++) {
          if (gmask & (1u << j)) {
            unsigned add = ((unsigned)winBin[j]) << (level * 8);
            int sub = winAbove[j];
            if (j == 0) { pref0 |= add; rem0 -= sub; }
            else if (j == 1) { pref1 |= add; rem1 -= sub; }
            else if (j == 2) { pref2 |= add; rem2 -= sub; }
            else { pref3 |= add; rem3 -= sub; }
          }
        }
        procMask |= gmask;
        __syncthreads();
      }
    }
    if (tid == 0) {
      unsigned pr[4] = {pref0, pref1, pref2, pref3};
#pragma unroll
      for (int j = 0; j < 4; j++) {
        unsigned u = pr[j];
        int bits = (u >> 31) ? (int)(u ^ 0x80000000u) : (int)(~u);
        thrS[r][j] = __int_as_float(bits);
      }
    }
  }
  __syncthreads();

  // ---- e = exp(s - max), bucket assignment, partial Z sums ----
  float A1 = a1p[0], A2 = a2p[0], A3 = a3p[0], A4 = a4p[0];
  float za[4][4];
#pragma unroll
  for (int r = 0; r < 4; r++)
#pragma unroll
    for (int j = 0; j < 4; j++) za[r][j] = 0.f;
  for (int it = 0; it < 7; it++) {
    int m = tid + it * 256;
    if (m < NPOS) {
#pragma unroll
      for (int r = 0; r < 4; r++) {
        float s = S[r][m];
        float e = __expf(s - rmax[r]);
        int b = 4;
        if (s >= thrS[r][3]) b = 3;
        if (s >= thrS[r][2]) b = 2;
        if (s >= thrS[r][1]) b = 1;
        if (s >= thrS[r][0]) b = 0;
        S[r][m] = e;
        Bk[r][m] = (unsigned char)b;
        za[r][0] += (b == 0) ? e : 0.f;
        za[r][1] += (b <= 1) ? e : 0.f;
        za[r][2] += (b <= 2) ? e : 0.f;
        za[r][3] += (b <= 3) ? e : 0.f;
      }
    }
  }
#pragma unroll
  for (int r = 0; r < 4; r++)
#pragma unroll
    for (int j = 0; j < 4; j++) {
      float v = wsum(za[r][j]);
      if (lane == 0) wred[wave][r * 4 + j] = v;
    }
  __syncthreads();
  if (tid < 4) {
    int r = tid;
    float Z0 = wred[0][r * 4 + 0] + wred[1][r * 4 + 0] + wred[2][r * 4 + 0] + wred[3][r * 4 + 0];
    float Z1 = wred[0][r * 4 + 1] + wred[1][r * 4 + 1] + wred[2][r * 4 + 1] + wred[3][r * 4 + 1];
    float Z2 = wred[0][r * 4 + 2] + wred[1][r * 4 + 2] + wred[2][r * 4 + 2] + wred[3][r * 4 + 2];
    float Z3 = wred[0][r * 4 + 3] + wred[1][r * 4 + 3] + wred[2][r * 4 + 3] + wred[3][r * 4 + 3];
    float c3 = A4 / Z3;
    float c2 = c3 + A3 / Z2;
    float c1 = c2 + A2 / Z1;
    float c0 = c1 + A1 / Z0;
    ctab[r][0] = c0; ctab[r][1] = c1; ctab[r][2] = c2; ctab[r][3] = c3; ctab[r][4] = 0.f;
  }
  __syncthreads();

  // ---- fused PV: out[r][c] = sum_m e*coef(bucket) * v[c][m] ----
  float acc[4][16];
#pragma unroll
  for (int r = 0; r < 4; r++)
#pragma unroll
    for (int c = 0; c < 16; c++) acc[r][c] = 0.f;
  for (int it = 0; it < 7; it++) {
    int m = tid + it * 256;
    if (m < NPOS) {
      float w0 = S[0][m] * ctab[0][Bk[0][m]];
      float w1 = S[1][m] * ctab[1][Bk[1][m]];
      float w2 = S[2][m] * ctab[2][Bk[2][m]];
      float w3 = S[3][m] * ctab[3][Bk[3][m]];
#pragma unroll
      for (int c = 0; c < 16; c++) {
        float vv = vb[(h * CHD + c) * NPOS + m];
        acc[0][c] += w0 * vv;
        acc[1][c] += w1 * vv;
        acc[2][c] += w2 * vv;
        acc[3][c] += w3 * vv;
      }
    }
  }
#pragma unroll
  for (int r = 0; r < 4; r++)
#pragma unroll
    for (int c = 0; c < 16; c++) {
      float v = wsum(acc[r][c]);
      if (lane == 0) wred[wave][r * 16 + c] = v;
    }
  __syncthreads();
  if (tid < 64) {
    int r = tid >> 4, c = tid & 15;
    float v = wred[0][r * 16 + c] + wred[1][r * 16 + c] + wred[2][r * 16 + c] + wred[3][r * 16 + c];
    outA[(h * CHD + c) * NPOS + n0 + r] = v;
  }
}

// -------- final 1x1 conv --------
__global__ __launch_bounds__(128) void k_fconv(const float* __restrict__ outA,
                                               const float* __restrict__ ow,
                                               float* __restrict__ y) {
  int n0 = blockIdx.x * 8;
  int t = threadIdx.x;
  __shared__ float oc[DIMC][9];
  for (int j = t; j < DIMC * 8; j += 128) {
    int i = j >> 3, p = j & 7;
    oc[i][p] = outA[i * NPOS + n0 + p];
  }
  __syncthreads();
  float acc[8] = {0.f, 0.f, 0.f, 0.f, 0.f, 0.f, 0.f, 0.f};
  const float* wr = ow + t * DIMC;
  for (int i = 0; i < DIMC; i++) {
    float w = wr[i];
#pragma unroll
    for (int p = 0; p < 8; p++) acc[p] += w * oc[i][p];
  }
#pragma unroll
  for (int p = 0; p < 8; p++) y[t * NPOS + n0 + p] = acc[p];
}

extern "C" void kernel_launch(void* const* d_in, const int* in_sizes, int n_in,
                              void* d_out, int out_size, void* d_ws, size_t ws_size,
                              hipStream_t stream) {
  const float* x = (const float*)d_in[0];
  const float* pe_w = (const float*)d_in[1];
  const float* pe_b = (const float*)d_in[2];
  const float* ln_g = (const float*)d_in[3];
  const float* ln_b = (const float*)d_in[4];
  const float* aspp_w1 = (const float*)d_in[5];
  const float* bn1_g = (const float*)d_in[6];
  const float* bn1_b = (const float*)d_in[7];
  const float* bn1_m = (const float*)d_in[8];
  const float* bn1_v = (const float*)d_in[9];
  const float* aspp_w2 = (const float*)d_in[10];
  const float* bn2_g = (const float*)d_in[11];
  const float* bn2_b = (const float*)d_in[12];
  const float* bn2_m = (const float*)d_in[13];
  const float* bn2_v = (const float*)d_in[14];
  const float* proj_w = (const float*)d_in[15];
  const float* bnp_g = (const float*)d_in[16];
  const float* bnp_b = (const float*)d_in[17];
  const float* bnp_m = (const float*)d_in[18];
  const float* bnp_v = (const float*)d_in[19];
  const float* kv_w = (const float*)d_in[20];
  const float* kvdw_w = (const float*)d_in[21];
  const float* out_w = (const float*)d_in[22];
  const float* temperature = (const float*)d_in[23];
  const float* a1 = (const float*)d_in[24];
  const float* a2 = (const float*)d_in[25];
  const float* a3 = (const float*)d_in[26];
  const float* a4 = (const float*)d_in[27];

  float* ws = (float*)d_ws;
  float* xr = ws;
  float* qraw = ws + 204800;
  float* kv1t = ws + 409600;
  float* kbuf = ws + 819200;
  float* vbuf = ws + 1024000;
  float* qn = ws + 1228800;
  float* kn = ws + 1433600;
  float* outA = ws + 1638400;
  float* w1t = ws + 1843200;
  float* w2t = ws + 1990656;

  k_transw<<<576, 256, 0, stream>>>(aspp_w1, aspp_w2, w1t, w2t);
  k_pe_ln<<<1600, 128, 0, stream>>>(x, pe_w, pe_b, ln_g, ln_b, xr);
  k_aspp<<<200, 128, 0, stream>>>(xr, w1t, w2t, bn1_g, bn1_b, bn1_m, bn1_v,
                                  bn2_g, bn2_b, bn2_m, bn2_v, proj_w,
                                  bnp_g, bnp_b, bnp_m, bnp_v, qraw);
  k_kv1<<<200, 256, 0, stream>>>(xr, kv_w, kv1t);
  k_dw<<<200, 256, 0, stream>>>(kv1t, kvdw_w, kbuf, vbuf);
  k_norm<<<128, 256, 0, stream>>>(qraw, qn);
  k_norm<<<128, 256, 0, stream>>>(kbuf, kn);
  k_attn<<<3200, 256, 0, stream>>>(qn, kn, vbuf, temperature, a1, a2, a3, a4, outA);
  k_fconv<<<200, 128, 0, stream>>>(outA, out_w, (float*)d_out);
}

// Round 2
// 470.641 us; speedup vs baseline: 1.9172x; 1.9172x over previous
//
#include <hip/hip_runtime.h>

#define NPOS 1600
#define DIMC 128
#define NHEADS 8
#define CHD 16

// ---------------- workspace layout (floats) ----------------
// 0        xr      204800   (x + LN(pe(x)))
// 204800   qraw    204800   (channel-major, pre-norm q)
// 409600   kv1t    409600   (1600 x 256, position-major)
// 819200   kbuf    204800   (channel-major, pre-norm k)
// 1024000  vt      204800   (position-major [h][m][16])
// 1228800  qt      204800   (position-major [h][m][16], normalized)
// 1433600  kt      204800   (position-major [h][m][16], normalized)
// 1638400  outA    204800   (channel-major)
// 1843200  w1t     147456
// 1990656  w2t     147456

__device__ __forceinline__ float wsum(float v) {
#pragma unroll
  for (int off = 1; off < 64; off <<= 1) v += __shfl_xor(v, off);
  return v;
}
__device__ __forceinline__ float wmax(float v) {
#pragma unroll
  for (int off = 1; off < 64; off <<= 1) v = fmaxf(v, __shfl_xor(v, off));
  return v;
}

// -------- transpose 3x3 conv weights: [o][i][k] -> [k][o][i] --------
__global__ void k_transw(const float* __restrict__ w1, const float* __restrict__ w2,
                         float* __restrict__ w1t, float* __restrict__ w2t) {
  int idx = blockIdx.x * 256 + threadIdx.x;
  if (idx < DIMC * DIMC * 9) {
    int k = idx / (DIMC * DIMC);
    int rem = idx % (DIMC * DIMC);
    int o = rem / DIMC, i = rem % DIMC;
    w1t[idx] = w1[(o * DIMC + i) * 9 + k];
    w2t[idx] = w2[(o * DIMC + i) * 9 + k];
  }
}

// -------- pe (1x1 conv) + LayerNorm(ch) + residual --------
__global__ __launch_bounds__(128) void k_pe_ln(
    const float* __restrict__ x, const float* __restrict__ pw,
    const float* __restrict__ pb, const float* __restrict__ lg,
    const float* __restrict__ lb, float* __restrict__ xr) {
  int n = blockIdx.x, t = threadIdx.x;
  __shared__ float xcol[DIMC];
  __shared__ float wred[2];
  float xv = x[t * NPOS + n];
  xcol[t] = xv;
  __syncthreads();
  float acc = pb[t];
  const float4* w4 = (const float4*)(pw + t * DIMC);
  const float4* x4 = (const float4*)xcol;
#pragma unroll
  for (int i = 0; i < 32; i++) {
    float4 w = w4[i];
    float4 xx = x4[i];
    acc += w.x * xx.x + w.y * xx.y + w.z * xx.z + w.w * xx.w;
  }
  float s = wsum(acc);
  if ((t & 63) == 0) wred[t >> 6] = s;
  __syncthreads();
  float mu = (wred[0] + wred[1]) * (1.0f / 128.0f);
  float d = acc - mu;
  __syncthreads();
  float s2 = wsum(d * d);
  if ((t & 63) == 0) wred[t >> 6] = s2;
  __syncthreads();
  float var = (wred[0] + wred[1]) * (1.0f / 128.0f);
  float tv = d * rsqrtf(var + 1e-5f) * lg[t] + lb[t];
  xr[t * NPOS + n] = xv + tv;
}

// -------- ASPP branches + bn/relu + proj (1x1) + bn/relu --------
__global__ __launch_bounds__(128) void k_aspp(
    const float* __restrict__ xr, const float* __restrict__ w1t,
    const float* __restrict__ w2t, const float* __restrict__ bg1,
    const float* __restrict__ bb1, const float* __restrict__ bm1,
    const float* __restrict__ bv1, const float* __restrict__ bg2,
    const float* __restrict__ bb2, const float* __restrict__ bm2,
    const float* __restrict__ bv2, const float* __restrict__ pw,
    const float* __restrict__ bgp, const float* __restrict__ bbp,
    const float* __restrict__ bmp, const float* __restrict__ bvp,
    float* __restrict__ q) {
  int strip = blockIdx.x;
  int r = strip / 5, c0 = (strip % 5) * 8;
  int t = threadIdx.x;
  __shared__ float x3[DIMC][9];
  __shared__ float x5[DIMC][9];
  __shared__ float cat[2 * DIMC][9];
  float a1a[8] = {0.f, 0.f, 0.f, 0.f, 0.f, 0.f, 0.f, 0.f};
  float a2a[8] = {0.f, 0.f, 0.f, 0.f, 0.f, 0.f, 0.f, 0.f};
  for (int k = 0; k < 9; k++) {
    int dr = k / 3 - 1, dc = k % 3 - 1;
    int r3 = r + 3 * dr, r5 = r + 5 * dr;
#pragma unroll
    for (int p = 0; p < 8; p++) {
      int c3 = c0 + p + 3 * dc;
      x3[t][p] = (r3 >= 0 && r3 < 40 && c3 >= 0 && c3 < 40) ? xr[t * NPOS + r3 * 40 + c3] : 0.f;
      int c5 = c0 + p + 5 * dc;
      x5[t][p] = (r5 >= 0 && r5 < 40 && c5 >= 0 && c5 < 40) ? xr[t * NPOS + r5 * 40 + c5] : 0.f;
    }
    __syncthreads();
    const float* w1r = w1t + (k * DIMC + t) * DIMC;
    const float* w2r = w2t + (k * DIMC + t) * DIMC;
    for (int i = 0; i < DIMC; i++) {
      float wa = w1r[i], wb = w2r[i];
#pragma unroll
      for (int p = 0; p < 8; p++) {
        a1a[p] += wa * x3[i][p];
        a2a[p] += wb * x5[i][p];
      }
    }
    __syncthreads();
  }
  float sc1 = bg1[t] * rsqrtf(bv1[t] + 1e-5f);
  float sc2 = bg2[t] * rsqrtf(bv2[t] + 1e-5f);
#pragma unroll
  for (int p = 0; p < 8; p++) {
    cat[t][p] = fmaxf((a1a[p] - bm1[t]) * sc1 + bb1[t], 0.f);
    cat[DIMC + t][p] = fmaxf((a2a[p] - bm2[t]) * sc2 + bb2[t], 0.f);
  }
  __syncthreads();
  float qa[8] = {0.f, 0.f, 0.f, 0.f, 0.f, 0.f, 0.f, 0.f};
  const float* pr = pw + t * 256;
  for (int j = 0; j < 256; j++) {
    float w = pr[j];
#pragma unroll
    for (int p = 0; p < 8; p++) qa[p] += w * cat[j][p];
  }
  float scp = bgp[t] * rsqrtf(bvp[t] + 1e-5f);
#pragma unroll
  for (int p = 0; p < 8; p++)
    q[t * NPOS + r * 40 + c0 + p] = fmaxf((qa[p] - bmp[t]) * scp + bbp[t], 0.f);
}

// -------- kv 1x1 conv --------
__global__ __launch_bounds__(256) void k_kv1(const float* __restrict__ xr,
                                             const float* __restrict__ kw,
                                             float* __restrict__ kv1t) {
  int n0 = blockIdx.x * 8;
  int t = threadIdx.x;
  __shared__ float xc[DIMC][9];
  for (int j = t; j < DIMC * 8; j += 256) {
    int i = j >> 3, p = j & 7;
    xc[i][p] = xr[i * NPOS + n0 + p];
  }
  __syncthreads();
  float acc[8] = {0.f, 0.f, 0.f, 0.f, 0.f, 0.f, 0.f, 0.f};
  const float* wr = kw + t * DIMC;
  for (int i = 0; i < DIMC; i++) {
    float w = wr[i];
#pragma unroll
    for (int p = 0; p < 8; p++) acc[p] += w * xc[i][p];
  }
#pragma unroll
  for (int p = 0; p < 8; p++) kv1t[(n0 + p) * 256 + t] = acc[p];
}

// -------- depthwise 3x3: k -> channel-major kbuf, v -> position-major vt --------
__global__ __launch_bounds__(256) void k_dw(const float* __restrict__ kv1t,
                                            const float* __restrict__ dww,
                                            float* __restrict__ kbuf,
                                            float* __restrict__ vt) {
  int strip = blockIdx.x;
  int r = strip / 5, c0 = (strip % 5) * 8;
  int t = threadIdx.x;
  float wl[9];
#pragma unroll
  for (int k = 0; k < 9; k++) wl[k] = dww[t * 9 + k];
  for (int p = 0; p < 8; p++) {
    int c = c0 + p;
    float acc = 0.f;
#pragma unroll
    for (int kh = 0; kh < 3; kh++) {
      int rr = r + kh - 1;
      if (rr < 0 || rr >= 40) continue;
#pragma unroll
      for (int kw_ = 0; kw_ < 3; kw_++) {
        int cc = c + kw_ - 1;
        if (cc < 0 || cc >= 40) continue;
        acc += wl[kh * 3 + kw_] * kv1t[(rr * 40 + cc) * 256 + t];
      }
    }
    int pos = r * 40 + c;
    if (t < DIMC) {
      kbuf[t * NPOS + pos] = acc;
    } else {
      int cv = t - DIMC;
      vt[((cv >> 4) * NPOS + pos) * CHD + (cv & 15)] = acc;
    }
  }
}

// -------- per-channel L2 norm over N, write position-major [h][m][16] --------
__global__ __launch_bounds__(256) void k_norm(const float* __restrict__ in,
                                              float* __restrict__ out_t) {
  int ch = blockIdx.x, t = threadIdx.x;
  __shared__ float wred[4];
  float ss = 0.f;
  for (int m = t; m < NPOS; m += 256) {
    float v = in[ch * NPOS + m];
    ss += v * v;
  }
  ss = wsum(ss);
  if ((t & 63) == 0) wred[t >> 6] = ss;
  __syncthreads();
  float tot = wred[0] + wred[1] + wred[2] + wred[3];
  float inv = 1.0f / fmaxf(sqrtf(tot), 1e-12f);
  int h = ch >> 4, c = ch & 15;
  for (int m = t; m < NPOS; m += 256)
    out_t[((h * NPOS) + m) * CHD + c] = in[ch * NPOS + m] * inv;
}

// -------- fused attention: barrier-free, wave = row --------
// scores live in registers as monotone-uint32; wave-private radix select.
__global__ __launch_bounds__(256, 4) void k_attn(
    const float* __restrict__ qt, const float* __restrict__ kt,
    const float* __restrict__ vt, const float* __restrict__ temp,
    const float* __restrict__ a1p, const float* __restrict__ a2p,
    const float* __restrict__ a3p, const float* __restrict__ a4p,
    float* __restrict__ outA) {
  __shared__ __align__(16) unsigned int hist[4][256];

  int tid = threadIdx.x;
  int lane = tid & 63, w = tid >> 6;
  int bid = blockIdx.x;
  int h = bid / 400;
  int n = (bid % 400) * 4 + w;

  // ---- load q (broadcast, 16 floats) ----
  const float4* q4 = (const float4*)(qt + (size_t)(h * NPOS + n) * CHD);
  float4 qa = q4[0], qb = q4[1], qc = q4[2], qd = q4[3];
  float tmpr = temp[h];

  // ---- QK^T: 25 positions per lane, keep monotone-u32 in regs ----
  unsigned u[25];
  float smax = -1e30f;
#pragma unroll
  for (int i = 0; i < 25; i++) {
    int m = lane + 64 * i;
    const float4* k4 = (const float4*)(kt + (size_t)(h * NPOS + m) * CHD);
    float4 ka = k4[0], kb = k4[1], kc = k4[2], kd = k4[3];
    float s = qa.x * ka.x + qa.y * ka.y + qa.z * ka.z + qa.w * ka.w
            + qb.x * kb.x + qb.y * kb.y + qb.z * kb.z + qb.w * kb.w
            + qc.x * kc.x + qc.y * kc.y + qc.z * kc.z + qc.w * kc.w
            + qd.x * kd.x + qd.y * kd.y + qd.z * kd.z + qd.w * kd.w;
    s *= tmpr;
    smax = fmaxf(smax, s);
    int bi = __float_as_int(s);
    u[i] = ((unsigned)bi) ^ ((bi < 0) ? 0xFFFFFFFFu : 0x80000000u);
  }
  float rmax = wmax(smax);

  // ---- wave-private radix select: 4 ranks (k-th largest), exact ----
  unsigned up0 = 0, up1 = 0, up2 = 0, up3 = 0;
  int rm0 = 800, rm1 = 1066, rm2 = 1200, rm3 = 1280;
  for (int level = 3; level >= 0; level--) {
    int ls = level * 8;
    unsigned prefMask = (level == 3) ? 0u : (0xFFFFFFFFu << ((level + 1) * 8));
    unsigned procMask = 0;
    for (int j0 = 0; j0 < 4; j0++) {
      if (procMask & (1u << j0)) continue;
      unsigned pj = (j0 == 0) ? up0 : (j0 == 1) ? up1 : (j0 == 2) ? up2 : up3;
      unsigned hpv = pj & prefMask;
      unsigned gmask = 0;
      if (!(procMask & 1u) && (up0 & prefMask) == hpv) gmask |= 1u;
      if (!(procMask & 2u) && (up1 & prefMask) == hpv) gmask |= 2u;
      if (!(procMask & 4u) && (up2 & prefMask) == hpv) gmask |= 4u;
      if (!(procMask & 8u) && (up3 & prefMask) == hpv) gmask |= 8u;

      // zero wave-private histogram (wave-ordered LDS, no block barrier)
      *(uint4*)(&hist[w][lane * 4]) = make_uint4(0u, 0u, 0u, 0u);
      __builtin_amdgcn_wave_barrier();
#pragma unroll
      for (int i = 0; i < 25; i++) {
        if ((u[i] & prefMask) == hpv)
          atomicAdd(&hist[w][(u[i] >> ls) & 255], 1u);
      }
      __builtin_amdgcn_wave_barrier();
      uint4 hv = *(const uint4*)(&hist[w][lane * 4]);

      // suffix counts: lane owns bins [4*lane .. 4*lane+3]
      int sfx3 = (int)hv.w;
      int sfx2 = sfx3 + (int)hv.z;
      int sfx1 = sfx2 + (int)hv.y;
      int sfx0 = sfx1 + (int)hv.x;
      int T = sfx0, v = T;
#pragma unroll
      for (int off = 1; off < 64; off <<= 1) {
        int xx = __shfl_down(v, off);
        if (lane + off < 64) v += xx;
      }
      int abv = v - T;  // count in bins > 4*lane+3
      int ge0 = abv + sfx0, ge1 = abv + sfx1, ge2 = abv + sfx2, ge3 = abv + sfx3;

#pragma unroll
      for (int j = 0; j < 4; j++) {
        if (gmask & (1u << j)) {
          int rem = (j == 0) ? rm0 : (j == 1) ? rm1 : (j == 2) ? rm2 : rm3;
          bool c0_ = (ge0 >= rem) && (ge1 < rem);
          bool c1_ = (ge1 >= rem) && (ge2 < rem);
          bool c2_ = (ge2 >= rem) && (ge3 < rem);
          bool c3_ = (ge3 >= rem) && (abv < rem);
          int bl = c0_ ? (4 * lane) : c1_ ? (4 * lane + 1) : c2_ ? (4 * lane + 2) : (4 * lane + 3);
          int gl = c0_ ? ge1 : c1_ ? ge2 : c2_ ? ge3 : abv;
          unsigned long long bal = __ballot(c0_ || c1_ || c2_ || c3_);
          int wl = (int)__ffsll(bal) - 1;
          int bin = __shfl(bl, wl);
          int sub = __shfl(gl, wl);
          unsigned add = ((unsigned)bin) << ls;
          if (j == 0) { up0 |= add; rm0 -= sub; }
          else if (j == 1) { up1 |= add; rm1 -= sub; }
          else if (j == 2) { up2 |= add; rm2 -= sub; }
          else { up3 |= add; rm3 -= sub; }
        }
      }
      procMask |= gmask;
    }
  }
  // up0..up3 are the exact u-images of the 4 thresholds.

  // ---- exp + bucket Z-sums (u-domain compares == s >= thr, tie-exact) ----
  float e[25];
  float za0 = 0.f, za1 = 0.f, za2 = 0.f, za3 = 0.f;
#pragma unroll
  for (int i = 0; i < 25; i++) {
    unsigned uu = u[i];
    int bits = (uu & 0x80000000u) ? (int)(uu ^ 0x80000000u) : (int)(~uu);
    float s = __int_as_float(bits);
    float ee = __expf(s - rmax);
    e[i] = ee;
    za0 += (uu >= up0) ? ee : 0.f;
    za1 += (uu >= up1) ? ee : 0.f;
    za2 += (uu >= up2) ? ee : 0.f;
    za3 += (uu >= up3) ? ee : 0.f;
  }
  float Z0 = wsum(za0), Z1 = wsum(za1), Z2 = wsum(za2), Z3 = wsum(za3);
  float A1 = a1p[0], A2 = a2p[0], A3 = a3p[0], A4 = a4p[0];
  float c3v = A4 / Z3;
  float c2v = c3v + A3 / Z2;
  float c1v = c2v + A2 / Z1;
  float c0v = c1v + A1 / Z0;

  // fold coefficient into weight
#pragma unroll
  for (int i = 0; i < 25; i++) {
    unsigned uu = u[i];
    float cf = (uu >= up0) ? c0v : (uu >= up1) ? c1v : (uu >= up2) ? c2v
             : (uu >= up3) ? c3v : 0.f;
    e[i] *= cf;
  }

  // ---- PV: acc[c] = sum_m w[m] * v[m][c] ----
  float4 aA = make_float4(0.f, 0.f, 0.f, 0.f);
  float4 aB = make_float4(0.f, 0.f, 0.f, 0.f);
  float4 aC = make_float4(0.f, 0.f, 0.f, 0.f);
  float4 aD = make_float4(0.f, 0.f, 0.f, 0.f);
#pragma unroll
  for (int i = 0; i < 25; i++) {
    int m = lane + 64 * i;
    const float4* v4 = (const float4*)(vt + (size_t)(h * NPOS + m) * CHD);
    float wg = e[i];
    float4 va = v4[0], vb = v4[1], vc = v4[2], vd = v4[3];
    aA.x += wg * va.x; aA.y += wg * va.y; aA.z += wg * va.z; aA.w += wg * va.w;
    aB.x += wg * vb.x; aB.y += wg * vb.y; aB.z += wg * vb.z; aB.w += wg * vb.w;
    aC.x += wg * vc.x; aC.y += wg * vc.y; aC.z += wg * vc.z; aC.w += wg * vc.w;
    aD.x += wg * vd.x; aD.y += wg * vd.y; aD.z += wg * vd.z; aD.w += wg * vd.w;
  }
  float rr[16] = {aA.x, aA.y, aA.z, aA.w, aB.x, aB.y, aB.z, aB.w,
                  aC.x, aC.y, aC.z, aC.w, aD.x, aD.y, aD.z, aD.w};
#pragma unroll
  for (int c = 0; c < 16; c++) rr[c] = wsum(rr[c]);
  float outv = 0.f;
#pragma unroll
  for (int c = 0; c < 16; c++) outv = (lane == c) ? rr[c] : outv;
  if (lane < 16) outA[(h * CHD + lane) * NPOS + n] = outv;
}

// -------- final 1x1 conv --------
__global__ __launch_bounds__(128) void k_fconv(const float* __restrict__ outA,
                                               const float* __restrict__ ow,
                                               float* __restrict__ y) {
  int n0 = blockIdx.x * 8;
  int t = threadIdx.x;
  __shared__ float oc[DIMC][9];
  for (int j = t; j < DIMC * 8; j += 128) {
    int i = j >> 3, p = j & 7;
    oc[i][p] = outA[i * NPOS + n0 + p];
  }
  __syncthreads();
  float acc[8] = {0.f, 0.f, 0.f, 0.f, 0.f, 0.f, 0.f, 0.f};
  const float* wr = ow + t * DIMC;
  for (int i = 0; i < DIMC; i++) {
    float w = wr[i];
#pragma unroll
    for (int p = 0; p < 8; p++) acc[p] += w * oc[i][p];
  }
#pragma unroll
  for (int p = 0; p < 8; p++) y[t * NPOS + n0 + p] = acc[p];
}

extern "C" void kernel_launch(void* const* d_in, const int* in_sizes, int n_in,
                              void* d_out, int out_size, void* d_ws, size_t ws_size,
                              hipStream_t stream) {
  const float* x = (const float*)d_in[0];
  const float* pe_w = (const float*)d_in[1];
  const float* pe_b = (const float*)d_in[2];
  const float* ln_g = (const float*)d_in[3];
  const float* ln_b = (const float*)d_in[4];
  const float* aspp_w1 = (const float*)d_in[5];
  const float* bn1_g = (const float*)d_in[6];
  const float* bn1_b = (const float*)d_in[7];
  const float* bn1_m = (const float*)d_in[8];
  const float* bn1_v = (const float*)d_in[9];
  const float* aspp_w2 = (const float*)d_in[10];
  const float* bn2_g = (const float*)d_in[11];
  const float* bn2_b = (const float*)d_in[12];
  const float* bn2_m = (const float*)d_in[13];
  const float* bn2_v = (const float*)d_in[14];
  const float* proj_w = (const float*)d_in[15];
  const float* bnp_g = (const float*)d_in[16];
  const float* bnp_b = (const float*)d_in[17];
  const float* bnp_m = (const float*)d_in[18];
  const float* bnp_v = (const float*)d_in[19];
  const float* kv_w = (const float*)d_in[20];
  const float* kvdw_w = (const float*)d_in[21];
  const float* out_w = (const float*)d_in[22];
  const float* temperature = (const float*)d_in[23];
  const float* a1 = (const float*)d_in[24];
  const float* a2 = (const float*)d_in[25];
  const float* a3 = (const float*)d_in[26];
  const float* a4 = (const float*)d_in[27];

  float* ws = (float*)d_ws;
  float* xr = ws;
  float* qraw = ws + 204800;
  float* kv1t = ws + 409600;
  float* kbuf = ws + 819200;
  float* vt = ws + 1024000;
  float* qt = ws + 1228800;
  float* kt = ws + 1433600;
  float* outA = ws + 1638400;
  float* w1t = ws + 1843200;
  float* w2t = ws + 1990656;

  k_transw<<<576, 256, 0, stream>>>(aspp_w1, aspp_w2, w1t, w2t);
  k_pe_ln<<<1600, 128, 0, stream>>>(x, pe_w, pe_b, ln_g, ln_b, xr);
  k_aspp<<<200, 128, 0, stream>>>(xr, w1t, w2t, bn1_g, bn1_b, bn1_m, bn1_v,
                                  bn2_g, bn2_b, bn2_m, bn2_v, proj_w,
                                  bnp_g, bnp_b, bnp_m, bnp_v, qraw);
  k_kv1<<<200, 256, 0, stream>>>(xr, kv_w, kv1t);
  k_dw<<<200, 256, 0, stream>>>(kv1t, kvdw_w, kbuf, vt);
  k_norm<<<128, 256, 0, stream>>>(qraw, qt);
  k_norm<<<128, 256, 0, stream>>>(kbuf, kt);
  k_attn<<<3200, 256, 0, stream>>>(qt, kt, vt, temperature, a1, a2, a3, a4, outA);
  k_fconv<<<200, 128, 0, stream>>>(outA, out_w, (float*)d_out);
}

// Round 3
// 412.627 us; speedup vs baseline: 2.1867x; 1.1406x over previous
//
#include <hip/hip_runtime.h>

#define NPOS 1600
#define DIMC 128
#define NHEADS 8
#define CHD 16

// ---------------- workspace layout (floats) ----------------
// 0        xr      204800   (x + LN(pe(x)))
// 204800   qraw    204800   (channel-major, pre-norm q)
// 409600   kv1t    409600   (1600 x 256, position-major)
// 819200   kbuf    204800   (channel-major, pre-norm k)
// 1024000  vt      204800   (position-major [h][m][16])
// 1228800  qt      204800   (position-major [h][m][16], normalized)
// 1433600  kt      204800   (position-major [h][m][16], normalized)
// 1638400  outA    204800   (position-major [h][m][16])
// 1843200  w1t     147456
// 1990656  w2t     147456

__device__ __forceinline__ float wsum(float v) {
#pragma unroll
  for (int off = 1; off < 64; off <<= 1) v += __shfl_xor(v, off);
  return v;
}
__device__ __forceinline__ float wmax(float v) {
#pragma unroll
  for (int off = 1; off < 64; off <<= 1) v = fmaxf(v, __shfl_xor(v, off));
  return v;
}

// -------- transpose 3x3 conv weights: [o][i][k] -> [k][o][i] --------
__global__ void k_transw(const float* __restrict__ w1, const float* __restrict__ w2,
                         float* __restrict__ w1t, float* __restrict__ w2t) {
  int idx = blockIdx.x * 256 + threadIdx.x;
  if (idx < DIMC * DIMC * 9) {
    int k = idx / (DIMC * DIMC);
    int rem = idx % (DIMC * DIMC);
    int o = rem / DIMC, i = rem % DIMC;
    w1t[idx] = w1[(o * DIMC + i) * 9 + k];
    w2t[idx] = w2[(o * DIMC + i) * 9 + k];
  }
}

// -------- pe (1x1 conv) + LayerNorm(ch) + residual --------
__global__ __launch_bounds__(128) void k_pe_ln(
    const float* __restrict__ x, const float* __restrict__ pw,
    const float* __restrict__ pb, const float* __restrict__ lg,
    const float* __restrict__ lb, float* __restrict__ xr) {
  int n = blockIdx.x, t = threadIdx.x;
  __shared__ float xcol[DIMC];
  __shared__ float wred[2];
  float xv = x[t * NPOS + n];
  xcol[t] = xv;
  __syncthreads();
  float acc = pb[t];
  const float4* w4 = (const float4*)(pw + t * DIMC);
  const float4* x4 = (const float4*)xcol;
#pragma unroll
  for (int i = 0; i < 32; i++) {
    float4 w = w4[i];
    float4 xx = x4[i];
    acc += w.x * xx.x + w.y * xx.y + w.z * xx.z + w.w * xx.w;
  }
  float s = wsum(acc);
  if ((t & 63) == 0) wred[t >> 6] = s;
  __syncthreads();
  float mu = (wred[0] + wred[1]) * (1.0f / 128.0f);
  float d = acc - mu;
  __syncthreads();
  float s2 = wsum(d * d);
  if ((t & 63) == 0) wred[t >> 6] = s2;
  __syncthreads();
  float var = (wred[0] + wred[1]) * (1.0f / 128.0f);
  float tv = d * rsqrtf(var + 1e-5f) * lg[t] + lb[t];
  xr[t * NPOS + n] = xv + tv;
}

// -------- ASPP branches + bn/relu + proj (1x1) + bn/relu --------
// 256 threads: ch = t&127, br = t>>7 (branch split), proj split by position half.
__global__ __launch_bounds__(256) void k_aspp(
    const float* __restrict__ xr, const float* __restrict__ w1t,
    const float* __restrict__ w2t, const float* __restrict__ bg1,
    const float* __restrict__ bb1, const float* __restrict__ bm1,
    const float* __restrict__ bv1, const float* __restrict__ bg2,
    const float* __restrict__ bb2, const float* __restrict__ bm2,
    const float* __restrict__ bv2, const float* __restrict__ pw,
    const float* __restrict__ bgp, const float* __restrict__ bbp,
    const float* __restrict__ bmp, const float* __restrict__ bvp,
    float* __restrict__ q) {
  int strip = blockIdx.x;
  int r = strip / 5, c0 = (strip % 5) * 8;
  int t = threadIdx.x;
  int ch = t & 127, br = t >> 7;
  __shared__ float xs[2][DIMC][9];
  __shared__ float cat[2 * DIMC][9];
  float aa[8] = {0.f, 0.f, 0.f, 0.f, 0.f, 0.f, 0.f, 0.f};
  int dil = br ? 5 : 3;
  const float* wt = br ? w2t : w1t;
  for (int k = 0; k < 9; k++) {
    int dr = k / 3 - 1, dc = k % 3 - 1;
    int rr = r + dil * dr;
#pragma unroll
    for (int p = 0; p < 8; p++) {
      int cc = c0 + p + dil * dc;
      xs[br][ch][p] = (rr >= 0 && rr < 40 && cc >= 0 && cc < 40) ? xr[ch * NPOS + rr * 40 + cc] : 0.f;
    }
    __syncthreads();
    const float* wrow = wt + (k * DIMC + ch) * DIMC;
    for (int i = 0; i < DIMC; i++) {
      float wv = wrow[i];
#pragma unroll
      for (int p = 0; p < 8; p++) aa[p] += wv * xs[br][i][p];
    }
    __syncthreads();
  }
  float sc = br ? bg2[ch] * rsqrtf(bv2[ch] + 1e-5f) : bg1[ch] * rsqrtf(bv1[ch] + 1e-5f);
  float bm = br ? bm2[ch] : bm1[ch];
  float bb = br ? bb2[ch] : bb1[ch];
#pragma unroll
  for (int p = 0; p < 8; p++) cat[br * DIMC + ch][p] = fmaxf((aa[p] - bm) * sc + bb, 0.f);
  __syncthreads();
  // proj: out-ch = ch, positions [br*4, br*4+4)
  float qa[4] = {0.f, 0.f, 0.f, 0.f};
  const float* pr = pw + ch * 256;
  int pbase = br * 4;
  for (int j = 0; j < 256; j++) {
    float wv = pr[j];
#pragma unroll
    for (int p = 0; p < 4; p++) qa[p] += wv * cat[j][pbase + p];
  }
  float scp = bgp[ch] * rsqrtf(bvp[ch] + 1e-5f);
#pragma unroll
  for (int p = 0; p < 4; p++)
    q[ch * NPOS + r * 40 + c0 + pbase + p] = fmaxf((qa[p] - bmp[ch]) * scp + bbp[ch], 0.f);
}

// -------- kv 1x1 conv --------
__global__ __launch_bounds__(256) void k_kv1(const float* __restrict__ xr,
                                             const float* __restrict__ kw,
                                             float* __restrict__ kv1t) {
  int n0 = blockIdx.x * 8;
  int t = threadIdx.x;
  __shared__ float xc[DIMC][9];
  for (int j = t; j < DIMC * 8; j += 256) {
    int i = j >> 3, p = j & 7;
    xc[i][p] = xr[i * NPOS + n0 + p];
  }
  __syncthreads();
  float acc[8] = {0.f, 0.f, 0.f, 0.f, 0.f, 0.f, 0.f, 0.f};
  const float* wr = kw + t * DIMC;
  for (int i = 0; i < DIMC; i++) {
    float w = wr[i];
#pragma unroll
    for (int p = 0; p < 8; p++) acc[p] += w * xc[i][p];
  }
#pragma unroll
  for (int p = 0; p < 8; p++) kv1t[(n0 + p) * 256 + t] = acc[p];
}

// -------- depthwise 3x3: k -> channel-major kbuf, v -> position-major vt --------
__global__ __launch_bounds__(256) void k_dw(const float* __restrict__ kv1t,
                                            const float* __restrict__ dww,
                                            float* __restrict__ kbuf,
                                            float* __restrict__ vt) {
  int strip = blockIdx.x;
  int r = strip / 5, c0 = (strip % 5) * 8;
  int t = threadIdx.x;
  float wl[9];
#pragma unroll
  for (int k = 0; k < 9; k++) wl[k] = dww[t * 9 + k];
  for (int p = 0; p < 8; p++) {
    int c = c0 + p;
    float acc = 0.f;
#pragma unroll
    for (int kh = 0; kh < 3; kh++) {
      int rr = r + kh - 1;
      if (rr < 0 || rr >= 40) continue;
#pragma unroll
      for (int kw_ = 0; kw_ < 3; kw_++) {
        int cc = c + kw_ - 1;
        if (cc < 0 || cc >= 40) continue;
        acc += wl[kh * 3 + kw_] * kv1t[(rr * 40 + cc) * 256 + t];
      }
    }
    int pos = r * 40 + c;
    if (t < DIMC) {
      kbuf[t * NPOS + pos] = acc;
    } else {
      int cv = t - DIMC;
      vt[((size_t)(cv >> 4) * NPOS + pos) * CHD + (cv & 15)] = acc;
    }
  }
}

// -------- per-channel L2 norm over N, write position-major [h][m][16] --------
__global__ __launch_bounds__(256) void k_norm(const float* __restrict__ in,
                                              float* __restrict__ out_t) {
  int ch = blockIdx.x, t = threadIdx.x;
  __shared__ float wred[4];
  float ss = 0.f;
  for (int m = t; m < NPOS; m += 256) {
    float v = in[ch * NPOS + m];
    ss += v * v;
  }
  ss = wsum(ss);
  if ((t & 63) == 0) wred[t >> 6] = ss;
  __syncthreads();
  float tot = wred[0] + wred[1] + wred[2] + wred[3];
  float inv = 1.0f / fmaxf(sqrtf(tot), 1e-12f);
  int h = ch >> 4, c = ch & 15;
  for (int m = t; m < NPOS; m += 256)
    out_t[((size_t)(h * NPOS) + m) * CHD + c] = in[ch * NPOS + m] * inv;
}

// -------- fused attention: barrier-free, wave = row, no register spills --------
__global__ __launch_bounds__(256) void k_attn(
    const float* __restrict__ qt, const float* __restrict__ kt,
    const float* __restrict__ vt, const float* __restrict__ temp,
    const float* __restrict__ a1p, const float* __restrict__ a2p,
    const float* __restrict__ a3p, const float* __restrict__ a4p,
    float* __restrict__ outA) {
  __shared__ __align__(16) unsigned int hist[4][4][256];  // [wave][group][bin]

  int tid = threadIdx.x;
  int lane = tid & 63, w = tid >> 6;
  int bid = blockIdx.x;
  int h = bid / 400;
  int n = (bid % 400) * 4 + w;

  float tmpr = temp[h];
  unsigned u[25];
  float smax = -1e30f;
  {
    const float4* q4 = (const float4*)(qt + (size_t)(h * NPOS + n) * CHD);
    float4 qa = q4[0], qb = q4[1], qc = q4[2], qd = q4[3];
#pragma unroll
    for (int i = 0; i < 25; i++) {
      int m = lane + (i << 6);
      const float4* k4 = (const float4*)(kt + (size_t)(h * NPOS + m) * CHD);
      float4 ka = k4[0], kb = k4[1], kc = k4[2], kd = k4[3];
      float s = qa.x * ka.x + qa.y * ka.y + qa.z * ka.z + qa.w * ka.w
              + qb.x * kb.x + qb.y * kb.y + qb.z * kb.z + qb.w * kb.w
              + qc.x * kc.x + qc.y * kc.y + qc.z * kc.z + qc.w * kc.w
              + qd.x * kd.x + qd.y * kd.y + qd.z * kd.z + qd.w * kd.w;
      s *= tmpr;
      smax = fmaxf(smax, s);
      int bi = __float_as_int(s);
      u[i] = ((unsigned)bi) ^ ((bi < 0) ? 0xFFFFFFFFu : 0x80000000u);
    }
  }
  float rmax = wmax(smax);

  // ---- exact radix select, 4 ranks, one multi-group histogram pass per level ----
  unsigned up0 = 0, up1 = 0, up2 = 0, up3 = 0;
  int rm0 = 800, rm1 = 1066, rm2 = 1200, rm3 = 1280;
  for (int level = 3; level >= 0; level--) {
    int ls = level * 8;
    unsigned pm = (level == 3) ? 0u : (0xFFFFFFFFu << (ls + 8));
    unsigned p0 = up0 & pm, p1 = up1 & pm, p2 = up2 & pm, p3 = up3 & pm;
    bool L1 = (p1 != p0), L2 = (p2 != p1), L3 = (p3 != p2);

    uint4 z = make_uint4(0u, 0u, 0u, 0u);
    *(uint4*)&hist[w][0][lane * 4] = z;
    *(uint4*)&hist[w][1][lane * 4] = z;
    *(uint4*)&hist[w][2][lane * 4] = z;
    *(uint4*)&hist[w][3][lane * 4] = z;
    __builtin_amdgcn_wave_barrier();
#pragma unroll
    for (int i = 0; i < 25; i++) {
      unsigned pf = u[i] & pm;
      int g = -1;
      if (pf == p0) g = 0;
      else if (L1 && pf == p1) g = 1;
      else if (L2 && pf == p2) g = 2;
      else if (L3 && pf == p3) g = 3;
      if (g >= 0) atomicAdd(&hist[w][g][(u[i] >> ls) & 255], 1u);
    }
    __builtin_amdgcn_wave_barrier();
    uint4 h0 = *(const uint4*)&hist[w][0][lane * 4];
    uint4 h1 = *(const uint4*)&hist[w][1][lane * 4];
    uint4 h2 = *(const uint4*)&hist[w][2][lane * 4];
    uint4 h3 = *(const uint4*)&hist[w][3][lane * 4];

    // lane-local suffix per group
    int s3g0 = h0.w, s2g0 = s3g0 + h0.z, s1g0 = s2g0 + h0.y, s0g0 = s1g0 + h0.x;
    int s3g1 = h1.w, s2g1 = s3g1 + h1.z, s1g1 = s2g1 + h1.y, s0g1 = s1g1 + h1.x;
    int s3g2 = h2.w, s2g2 = s3g2 + h2.z, s1g2 = s2g2 + h2.y, s0g2 = s1g2 + h2.x;
    int s3g3 = h3.w, s2g3 = s3g3 + h3.z, s1g3 = s2g3 + h3.y, s0g3 = s1g3 + h3.x;

    // packed cross-lane suffix scan (two u32, 16-bit fields; counts <= 1600)
    unsigned vA = (unsigned)s0g0 | ((unsigned)s0g1 << 16);
    unsigned vB = (unsigned)s0g2 | ((unsigned)s0g3 << 16);
#pragma unroll
    for (int off = 1; off < 64; off <<= 1) {
      unsigned xA = __shfl_down(vA, off);
      unsigned xB = __shfl_down(vB, off);
      if (lane + off < 64) { vA += xA; vB += xB; }
    }
    int abv0 = (int)(vA & 0xFFFFu) - s0g0;
    int abv1 = (int)(vA >> 16) - s0g1;
    int abv2 = (int)(vB & 0xFFFFu) - s0g2;
    int abv3 = (int)(vB >> 16) - s0g3;

    // group index per rank (wave-uniform)
    int g1 = L1 ? 1 : 0;
    int g2 = L2 ? 2 : g1;
    int g3 = L3 ? 3 : g2;

#pragma unroll
    for (int j = 0; j < 4; j++) {
      int gj = (j == 0) ? 0 : (j == 1) ? g1 : (j == 2) ? g2 : g3;
      int a  = (gj == 0) ? abv0 : (gj == 1) ? abv1 : (gj == 2) ? abv2 : abv3;
      int t0 = (gj == 0) ? s0g0 : (gj == 1) ? s0g1 : (gj == 2) ? s0g2 : s0g3;
      int t1 = (gj == 0) ? s1g0 : (gj == 1) ? s1g1 : (gj == 2) ? s1g2 : s1g3;
      int t2 = (gj == 0) ? s2g0 : (gj == 1) ? s2g1 : (gj == 2) ? s2g2 : s2g3;
      int t3 = (gj == 0) ? s3g0 : (gj == 1) ? s3g1 : (gj == 2) ? s3g2 : s3g3;
      int rem = (j == 0) ? rm0 : (j == 1) ? rm1 : (j == 2) ? rm2 : rm3;
      int ge0 = a + t0, ge1 = a + t1, ge2 = a + t2, ge3 = a + t3;
      bool c0_ = (ge0 >= rem) && (ge1 < rem);
      bool c1_ = (ge1 >= rem) && (ge2 < rem);
      bool c2_ = (ge2 >= rem) && (ge3 < rem);
      bool c3_ = (ge3 >= rem) && (a < rem);
      int bl = c0_ ? (4 * lane) : c1_ ? (4 * lane + 1) : c2_ ? (4 * lane + 2) : (4 * lane + 3);
      int gl = c0_ ? ge1 : c1_ ? ge2 : c2_ ? ge3 : a;
      unsigned long long bal = __ballot(c0_ || c1_ || c2_ || c3_);
      int wl = (int)__ffsll(bal) - 1;
      int bin = __shfl(bl, wl);
      int sub = __shfl(gl, wl);
      unsigned add = ((unsigned)bin) << ls;
      if (j == 0) { up0 |= add; rm0 -= sub; }
      else if (j == 1) { up1 |= add; rm1 -= sub; }
      else if (j == 2) { up2 |= add; rm2 -= sub; }
      else { up3 |= add; rm3 -= sub; }
    }
  }

  // ---- Z sums per bucket (recompute exp; no e[] array -> no spills) ----
  float za0 = 0.f, za1 = 0.f, za2 = 0.f, za3 = 0.f;
#pragma unroll
  for (int i = 0; i < 25; i++) {
    unsigned uu = u[i];
    int bits = (uu & 0x80000000u) ? (int)(uu ^ 0x80000000u) : (int)(~uu);
    float s = __int_as_float(bits);
    float ee = __expf(s - rmax);
    za0 += (uu >= up0) ? ee : 0.f;
    za1 += (uu >= up1) ? ee : 0.f;
    za2 += (uu >= up2) ? ee : 0.f;
    za3 += (uu >= up3) ? ee : 0.f;
  }
  float Z0 = wsum(za0), Z1 = wsum(za1), Z2 = wsum(za2), Z3 = wsum(za3);
  float A1 = a1p[0], A2 = a2p[0], A3 = a3p[0], A4 = a4p[0];
  float c3v = A4 / Z3;
  float c2v = c3v + A3 / Z2;
  float c1v = c2v + A2 / Z1;
  float c0v = c1v + A1 / Z0;

  // ---- PV with fused coefficient ----
  float4 aA = make_float4(0.f, 0.f, 0.f, 0.f);
  float4 aB = make_float4(0.f, 0.f, 0.f, 0.f);
  float4 aC = make_float4(0.f, 0.f, 0.f, 0.f);
  float4 aD = make_float4(0.f, 0.f, 0.f, 0.f);
#pragma unroll
  for (int i = 0; i < 25; i++) {
    unsigned uu = u[i];
    int bits = (uu & 0x80000000u) ? (int)(uu ^ 0x80000000u) : (int)(~uu);
    float s = __int_as_float(bits);
    float cf = (uu >= up0) ? c0v : (uu >= up1) ? c1v : (uu >= up2) ? c2v
             : (uu >= up3) ? c3v : 0.f;
    float wg = __expf(s - rmax) * cf;
    int m = lane + (i << 6);
    const float4* v4 = (const float4*)(vt + (size_t)(h * NPOS + m) * CHD);
    float4 va = v4[0], vb = v4[1], vc = v4[2], vd = v4[3];
    aA.x += wg * va.x; aA.y += wg * va.y; aA.z += wg * va.z; aA.w += wg * va.w;
    aB.x += wg * vb.x; aB.y += wg * vb.y; aB.z += wg * vb.z; aB.w += wg * vb.w;
    aC.x += wg * vc.x; aC.y += wg * vc.y; aC.z += wg * vc.z; aC.w += wg * vc.w;
    aD.x += wg * vd.x; aD.y += wg * vd.y; aD.z += wg * vd.z; aD.w += wg * vd.w;
  }
  float rr[16] = {aA.x, aA.y, aA.z, aA.w, aB.x, aB.y, aB.z, aB.w,
                  aC.x, aC.y, aC.z, aC.w, aD.x, aD.y, aD.z, aD.w};
#pragma unroll
  for (int c = 0; c < 16; c++) rr[c] = wsum(rr[c]);
  // lanes 0..3 each store one float4 (position-major outA)
  float o0 = (lane == 0) ? rr[0] : (lane == 1) ? rr[4] : (lane == 2) ? rr[8] : rr[12];
  float o1 = (lane == 0) ? rr[1] : (lane == 1) ? rr[5] : (lane == 2) ? rr[9] : rr[13];
  float o2 = (lane == 0) ? rr[2] : (lane == 1) ? rr[6] : (lane == 2) ? rr[10] : rr[14];
  float o3 = (lane == 0) ? rr[3] : (lane == 1) ? rr[7] : (lane == 2) ? rr[11] : rr[15];
  if (lane < 4)
    *(float4*)(outA + (size_t)(h * NPOS + n) * CHD + lane * 4) = make_float4(o0, o1, o2, o3);
}

// -------- final 1x1 conv (consumes position-major outA) --------
__global__ __launch_bounds__(128) void k_fconv(const float* __restrict__ outA,
                                               const float* __restrict__ ow,
                                               float* __restrict__ y) {
  int n0 = blockIdx.x * 8;
  int t = threadIdx.x;
  __shared__ __align__(16) float oc[8][DIMC];
#pragma unroll
  for (int rp = 0; rp < 2; rp++) {
    int f4 = t + rp * 128;          // 256 float4 total
    int pos = f4 >> 5, ch4 = f4 & 31;
    int head = ch4 >> 2, qq = ch4 & 3;
    float4 v = *(const float4*)(outA + ((size_t)(head * NPOS) + n0 + pos) * CHD + qq * 4);
    *(float4*)&oc[pos][ch4 * 4] = v;
  }
  __syncthreads();
  float acc[8] = {0.f, 0.f, 0.f, 0.f, 0.f, 0.f, 0.f, 0.f};
  const float* wr = ow + t * DIMC;
  for (int i = 0; i < DIMC; i++) {
    float w = wr[i];
#pragma unroll
    for (int p = 0; p < 8; p++) acc[p] += w * oc[p][i];
  }
#pragma unroll
  for (int p = 0; p < 8; p++) y[t * NPOS + n0 + p] = acc[p];
}

extern "C" void kernel_launch(void* const* d_in, const int* in_sizes, int n_in,
                              void* d_out, int out_size, void* d_ws, size_t ws_size,
                              hipStream_t stream) {
  const float* x = (const float*)d_in[0];
  const float* pe_w = (const float*)d_in[1];
  const float* pe_b = (const float*)d_in[2];
  const float* ln_g = (const float*)d_in[3];
  const float* ln_b = (const float*)d_in[4];
  const float* aspp_w1 = (const float*)d_in[5];
  const float* bn1_g = (const float*)d_in[6];
  const float* bn1_b = (const float*)d_in[7];
  const float* bn1_m = (const float*)d_in[8];
  const float* bn1_v = (const float*)d_in[9];
  const float* aspp_w2 = (const float*)d_in[10];
  const float* bn2_g = (const float*)d_in[11];
  const float* bn2_b = (const float*)d_in[12];
  const float* bn2_m = (const float*)d_in[13];
  const float* bn2_v = (const float*)d_in[14];
  const float* proj_w = (const float*)d_in[15];
  const float* bnp_g = (const float*)d_in[16];
  const float* bnp_b = (const float*)d_in[17];
  const float* bnp_m = (const float*)d_in[18];
  const float* bnp_v = (const float*)d_in[19];
  const float* kv_w = (const float*)d_in[20];
  const float* kvdw_w = (const float*)d_in[21];
  const float* out_w = (const float*)d_in[22];
  const float* temperature = (const float*)d_in[23];
  const float* a1 = (const float*)d_in[24];
  const float* a2 = (const float*)d_in[25];
  const float* a3 = (const float*)d_in[26];
  const float* a4 = (const float*)d_in[27];

  float* ws = (float*)d_ws;
  float* xr = ws;
  float* qraw = ws + 204800;
  float* kv1t = ws + 409600;
  float* kbuf = ws + 819200;
  float* vt = ws + 1024000;
  float* qt = ws + 1228800;
  float* kt = ws + 1433600;
  float* outA = ws + 1638400;
  float* w1t = ws + 1843200;
  float* w2t = ws + 1990656;

  k_transw<<<576, 256, 0, stream>>>(aspp_w1, aspp_w2, w1t, w2t);
  k_pe_ln<<<1600, 128, 0, stream>>>(x, pe_w, pe_b, ln_g, ln_b, xr);
  k_aspp<<<200, 256, 0, stream>>>(xr, w1t, w2t, bn1_g, bn1_b, bn1_m, bn1_v,
                                  bn2_g, bn2_b, bn2_m, bn2_v, proj_w,
                                  bnp_g, bnp_b, bnp_m, bnp_v, qraw);
  k_kv1<<<200, 256, 0, stream>>>(xr, kv_w, kv1t);
  k_dw<<<200, 256, 0, stream>>>(kv1t, kvdw_w, kbuf, vt);
  k_norm<<<128, 256, 0, stream>>>(qraw, qt);
  k_norm<<<128, 256, 0, stream>>>(kbuf, kt);
  k_attn<<<3200, 256, 0, stream>>>(qt, kt, vt, temperature, a1, a2, a3, a4, outA);
  k_fconv<<<200, 128, 0, stream>>>(outA, out_w, (float*)d_out);
}

// Round 4
// 342.704 us; speedup vs baseline: 2.6329x; 1.2040x over previous
//
#include <hip/hip_runtime.h>

#define NPOS 1600
#define DIMC 128
#define NHEADS 8
#define CHD 16

// ---------------- workspace layout (floats) ----------------
// 0        xr      204800   (x + LN(pe(x)))
// 204800   qraw    204800   (channel-major, pre-norm q)
// 409600   kv1t    409600   (1600 x 256, position-major)
// 819200   kbuf    204800   (channel-major, pre-norm k)
// 1024000  vt      204800   (position-major [h][m][16])
// 1228800  qt      204800   (position-major [h][m][16], normalized)
// 1433600  kt      204800   (position-major [h][m][16], normalized)
// 1638400  outA    204800   (position-major [h][m][16])
// 1843200  w1t     147456
// 1990656  w2t     147456

__device__ __forceinline__ float wsum(float v) {
#pragma unroll
  for (int off = 1; off < 64; off <<= 1) v += __shfl_xor(v, off);
  return v;
}
__device__ __forceinline__ float wmax(float v) {
#pragma unroll
  for (int off = 1; off < 64; off <<= 1) v = fmaxf(v, __shfl_xor(v, off));
  return v;
}

// -------- transpose 3x3 conv weights: [o][i][k] -> [k][o][i] --------
__global__ void k_transw(const float* __restrict__ w1, const float* __restrict__ w2,
                         float* __restrict__ w1t, float* __restrict__ w2t) {
  int idx = blockIdx.x * 256 + threadIdx.x;
  if (idx < DIMC * DIMC * 9) {
    int k = idx / (DIMC * DIMC);
    int rem = idx % (DIMC * DIMC);
    int o = rem / DIMC, i = rem % DIMC;
    w1t[idx] = w1[(o * DIMC + i) * 9 + k];
    w2t[idx] = w2[(o * DIMC + i) * 9 + k];
  }
}

// -------- pe (1x1 conv) + LayerNorm(ch) + residual --------
__global__ __launch_bounds__(128) void k_pe_ln(
    const float* __restrict__ x, const float* __restrict__ pw,
    const float* __restrict__ pb, const float* __restrict__ lg,
    const float* __restrict__ lb, float* __restrict__ xr) {
  int n = blockIdx.x, t = threadIdx.x;
  __shared__ float xcol[DIMC];
  __shared__ float wred[2];
  float xv = x[t * NPOS + n];
  xcol[t] = xv;
  __syncthreads();
  float acc = pb[t];
  const float4* w4 = (const float4*)(pw + t * DIMC);
  const float4* x4 = (const float4*)xcol;
#pragma unroll
  for (int i = 0; i < 32; i++) {
    float4 w = w4[i];
    float4 xx = x4[i];
    acc += w.x * xx.x + w.y * xx.y + w.z * xx.z + w.w * xx.w;
  }
  float s = wsum(acc);
  if ((t & 63) == 0) wred[t >> 6] = s;
  __syncthreads();
  float mu = (wred[0] + wred[1]) * (1.0f / 128.0f);
  float d = acc - mu;
  __syncthreads();
  float s2 = wsum(d * d);
  if ((t & 63) == 0) wred[t >> 6] = s2;
  __syncthreads();
  float var = (wred[0] + wred[1]) * (1.0f / 128.0f);
  float tv = d * rsqrtf(var + 1e-5f) * lg[t] + lb[t];
  xr[t * NPOS + n] = xv + tv;
}

// -------- ASPP branches + bn/relu + proj (1x1) + bn/relu (4-col strips) --------
__global__ __launch_bounds__(256) void k_aspp(
    const float* __restrict__ xr, const float* __restrict__ w1t,
    const float* __restrict__ w2t, const float* __restrict__ bg1,
    const float* __restrict__ bb1, const float* __restrict__ bm1,
    const float* __restrict__ bv1, const float* __restrict__ bg2,
    const float* __restrict__ bb2, const float* __restrict__ bm2,
    const float* __restrict__ bv2, const float* __restrict__ pw,
    const float* __restrict__ bgp, const float* __restrict__ bbp,
    const float* __restrict__ bmp, const float* __restrict__ bvp,
    float* __restrict__ q) {
  int strip = blockIdx.x;
  int r = strip / 10, c0 = (strip % 10) * 4;
  int t = threadIdx.x;
  int ch = t & 127, br = t >> 7;
  __shared__ float xs[2][DIMC][4];
  __shared__ float cat[2 * DIMC][4];
  float aa[4] = {0.f, 0.f, 0.f, 0.f};
  int dil = br ? 5 : 3;
  const float* wt = br ? w2t : w1t;
  for (int k = 0; k < 9; k++) {
    int dr = k / 3 - 1, dc = k % 3 - 1;
    int rr = r + dil * dr;
#pragma unroll
    for (int p = 0; p < 4; p++) {
      int cc = c0 + p + dil * dc;
      xs[br][ch][p] = (rr >= 0 && rr < 40 && cc >= 0 && cc < 40) ? xr[ch * NPOS + rr * 40 + cc] : 0.f;
    }
    __syncthreads();
    const float* wrow = wt + (k * DIMC + ch) * DIMC;
    for (int i = 0; i < DIMC; i++) {
      float wv = wrow[i];
#pragma unroll
      for (int p = 0; p < 4; p++) aa[p] += wv * xs[br][i][p];
    }
    __syncthreads();
  }
  float sc = br ? bg2[ch] * rsqrtf(bv2[ch] + 1e-5f) : bg1[ch] * rsqrtf(bv1[ch] + 1e-5f);
  float bm = br ? bm2[ch] : bm1[ch];
  float bb = br ? bb2[ch] : bb1[ch];
#pragma unroll
  for (int p = 0; p < 4; p++) cat[br * DIMC + ch][p] = fmaxf((aa[p] - bm) * sc + bb, 0.f);
  __syncthreads();
  float qa0 = 0.f, qa1 = 0.f;
  const float* pr = pw + ch * 256;
  int pbase = br * 2;
  for (int j = 0; j < 256; j++) {
    float wv = pr[j];
    qa0 += wv * cat[j][pbase];
    qa1 += wv * cat[j][pbase + 1];
  }
  float scp = bgp[ch] * rsqrtf(bvp[ch] + 1e-5f);
  q[ch * NPOS + r * 40 + c0 + pbase]     = fmaxf((qa0 - bmp[ch]) * scp + bbp[ch], 0.f);
  q[ch * NPOS + r * 40 + c0 + pbase + 1] = fmaxf((qa1 - bmp[ch]) * scp + bbp[ch], 0.f);
}

// -------- kv 1x1 conv (4 positions per block) --------
__global__ __launch_bounds__(256) void k_kv1(const float* __restrict__ xr,
                                             const float* __restrict__ kw,
                                             float* __restrict__ kv1t) {
  int n0 = blockIdx.x * 4;
  int t = threadIdx.x;
  __shared__ float xc[DIMC][4];
  for (int j = t; j < DIMC * 4; j += 256) {
    int i = j >> 2, p = j & 3;
    xc[i][p] = xr[i * NPOS + n0 + p];
  }
  __syncthreads();
  float acc[4] = {0.f, 0.f, 0.f, 0.f};
  const float* wr = kw + t * DIMC;
  for (int i = 0; i < DIMC; i++) {
    float w = wr[i];
#pragma unroll
    for (int p = 0; p < 4; p++) acc[p] += w * xc[i][p];
  }
#pragma unroll
  for (int p = 0; p < 4; p++) kv1t[(n0 + p) * 256 + t] = acc[p];
}

// -------- depthwise 3x3 (4-col strips): k -> channel-major, v -> position-major --------
__global__ __launch_bounds__(256) void k_dw(const float* __restrict__ kv1t,
                                            const float* __restrict__ dww,
                                            float* __restrict__ kbuf,
                                            float* __restrict__ vt) {
  int strip = blockIdx.x;
  int r = strip / 10, c0 = (strip % 10) * 4;
  int t = threadIdx.x;
  float wl[9];
#pragma unroll
  for (int k = 0; k < 9; k++) wl[k] = dww[t * 9 + k];
  for (int p = 0; p < 4; p++) {
    int c = c0 + p;
    float acc = 0.f;
#pragma unroll
    for (int kh = 0; kh < 3; kh++) {
      int rr = r + kh - 1;
      if (rr < 0 || rr >= 40) continue;
#pragma unroll
      for (int kw_ = 0; kw_ < 3; kw_++) {
        int cc = c + kw_ - 1;
        if (cc < 0 || cc >= 40) continue;
        acc += wl[kh * 3 + kw_] * kv1t[(rr * 40 + cc) * 256 + t];
      }
    }
    int pos = r * 40 + c;
    if (t < DIMC) {
      kbuf[t * NPOS + pos] = acc;
    } else {
      int cv = t - DIMC;
      vt[((size_t)(cv >> 4) * NPOS + pos) * CHD + (cv & 15)] = acc;
    }
  }
}

// -------- per-channel L2 norm (q and k merged), write position-major --------
__global__ __launch_bounds__(256) void k_norm(const float* __restrict__ qraw,
                                              const float* __restrict__ kbuf,
                                              float* __restrict__ qt,
                                              float* __restrict__ kt) {
  int b = blockIdx.x, t = threadIdx.x;
  const float* in = (b < 128) ? qraw : kbuf;
  float* out_t = (b < 128) ? qt : kt;
  int ch = b & 127;
  __shared__ float wred[4];
  float ss = 0.f;
  for (int m = t; m < NPOS; m += 256) {
    float v = in[ch * NPOS + m];
    ss += v * v;
  }
  ss = wsum(ss);
  if ((t & 63) == 0) wred[t >> 6] = ss;
  __syncthreads();
  float tot = wred[0] + wred[1] + wred[2] + wred[3];
  float inv = 1.0f / fmaxf(sqrtf(tot), 1e-12f);
  int h = ch >> 4, c = ch & 15;
  for (int m = t; m < NPOS; m += 256)
    out_t[((size_t)(h * NPOS) + m) * CHD + c] = in[ch * NPOS + m] * inv;
}

// -------- fused attention: block = 2 rows, 256 threads cooperative --------
// Per thread: 7 positions x 2 rows. Shared K/V loads across the 2 rows.
// Exact 4-rank top-k via block-cooperative radix select (4 levels, 8-bit).
__global__ __launch_bounds__(256) void k_attn(
    const float* __restrict__ qt, const float* __restrict__ kt,
    const float* __restrict__ vt, const float* __restrict__ temp,
    const float* __restrict__ a1p, const float* __restrict__ a2p,
    const float* __restrict__ a3p, const float* __restrict__ a4p,
    float* __restrict__ outA) {
  __shared__ unsigned hist[2][4][256];    // 8 KB
  __shared__ unsigned s_tot[4][4];        // per-wave packed scan totals
  __shared__ float s_rm[2][4];            // per-row per-wave maxima
  __shared__ int s_win[8], s_sub[8];      // winners (row*4 + rank)
  __shared__ float s_z[4][8];             // per-wave Z partials
  __shared__ float s_wr[4][32];           // per-wave PV partials

  int tid = threadIdx.x;
  int lane = tid & 63, w = tid >> 6;
  int n0 = blockIdx.x * 2;
  int h = blockIdx.y;

  float tmpr = temp[h];
  const float* kbase = kt + (size_t)h * NPOS * CHD;
  const float* vbase = vt + (size_t)h * NPOS * CHD;

  // q for both rows (broadcast loads)
  const float4* q4a = (const float4*)(qt + ((size_t)h * NPOS + n0) * CHD);
  const float4* q4b = (const float4*)(qt + ((size_t)h * NPOS + n0 + 1) * CHD);
  float4 qa0 = q4a[0], qa1 = q4a[1], qa2 = q4a[2], qa3 = q4a[3];
  float4 qb0 = q4b[0], qb1 = q4b[1], qb2 = q4b[2], qb3 = q4b[3];

  unsigned u0[7], u1[7];
  float smax0 = -1e30f, smax1 = -1e30f;
#pragma unroll
  for (int i = 0; i < 7; i++) {
    int m = tid + (i << 8);
    if (m < NPOS) {
      const float4* k4 = (const float4*)(kbase + (size_t)m * CHD);
      float4 ka = k4[0], kb = k4[1], kc = k4[2], kd = k4[3];
      float s0 = qa0.x * ka.x + qa0.y * ka.y + qa0.z * ka.z + qa0.w * ka.w
               + qa1.x * kb.x + qa1.y * kb.y + qa1.z * kb.z + qa1.w * kb.w
               + qa2.x * kc.x + qa2.y * kc.y + qa2.z * kc.z + qa2.w * kc.w
               + qa3.x * kd.x + qa3.y * kd.y + qa3.z * kd.z + qa3.w * kd.w;
      float s1 = qb0.x * ka.x + qb0.y * ka.y + qb0.z * ka.z + qb0.w * ka.w
               + qb1.x * kb.x + qb1.y * kb.y + qb1.z * kb.z + qb1.w * kb.w
               + qb2.x * kc.x + qb2.y * kc.y + qb2.z * kc.z + qb2.w * kc.w
               + qb3.x * kd.x + qb3.y * kd.y + qb3.z * kd.z + qb3.w * kd.w;
      s0 *= tmpr; s1 *= tmpr;
      smax0 = fmaxf(smax0, s0);
      smax1 = fmaxf(smax1, s1);
      int b0 = __float_as_int(s0), b1 = __float_as_int(s1);
      u0[i] = ((unsigned)b0) ^ ((b0 < 0) ? 0xFFFFFFFFu : 0x80000000u);
      u1[i] = ((unsigned)b1) ^ ((b1 < 0) ? 0xFFFFFFFFu : 0x80000000u);
    } else {
      u0[i] = 0u; u1[i] = 0u;
    }
  }
  {
    float m0 = wmax(smax0), m1 = wmax(smax1);
    if (lane == 0) { s_rm[0][w] = m0; s_rm[1][w] = m1; }
  }
  // visibility of s_rm guaranteed by barriers inside the select loop.

  unsigned t00 = 0, t01 = 0, t02 = 0, t03 = 0;
  unsigned t10 = 0, t11 = 0, t12 = 0, t13 = 0;
  int r00 = 800, r01 = 1066, r02 = 1200, r03 = 1280;
  int r10 = 800, r11 = 1066, r12 = 1200, r13 = 1280;

  for (int level = 3; level >= 0; level--) {
    const int ls = level * 8;
    const unsigned pm = (level == 3) ? 0u : (0xFFFFFFFFu << (ls + 8));
    unsigned P00 = t00 & pm, P01 = t01 & pm, P02 = t02 & pm, P03 = t03 & pm;
    unsigned P10 = t10 & pm, P11 = t11 & pm, P12 = t12 & pm, P13 = t13 & pm;
    bool L01 = (P01 != P00), L02 = (P02 != P01), L03 = (P03 != P02);
    bool L11 = (P11 != P10), L12 = (P12 != P11), L13 = (P13 != P12);

    uint4 z4 = make_uint4(0u, 0u, 0u, 0u);
    ((uint4*)hist)[tid] = z4;
    ((uint4*)hist)[tid + 256] = z4;
    __syncthreads();

#pragma unroll
    for (int i = 0; i < 7; i++) {
      {
        unsigned uu = u0[i], pf = uu & pm;
        int g = (pf == P00) ? 0 : (L01 && pf == P01) ? 1 : (L02 && pf == P02) ? 2
              : (L03 && pf == P03) ? 3 : -1;
        if (g >= 0) atomicAdd(&hist[0][g][(uu >> ls) & 255], 1u);
      }
      {
        unsigned uu = u1[i], pf = uu & pm;
        int g = (pf == P10) ? 0 : (L11 && pf == P11) ? 1 : (L12 && pf == P12) ? 2
              : (L13 && pf == P13) ? 3 : -1;
        if (g >= 0) atomicAdd(&hist[1][g][(uu >> ls) & 255], 1u);
      }
    }
    __syncthreads();

    unsigned c00 = hist[0][0][tid], c01 = hist[0][1][tid];
    unsigned c02 = hist[0][2][tid], c03 = hist[0][3][tid];
    unsigned c10 = hist[1][0][tid], c11 = hist[1][1][tid];
    unsigned c12 = hist[1][2][tid], c13 = hist[1][3][tid];
    unsigned sA = c00 | (c01 << 16), sB = c02 | (c03 << 16);
    unsigned sC = c10 | (c11 << 16), sD = c12 | (c13 << 16);
#pragma unroll
    for (int off = 1; off < 64; off <<= 1) {
      unsigned xA = __shfl_down(sA, off), xB = __shfl_down(sB, off);
      unsigned xC = __shfl_down(sC, off), xD = __shfl_down(sD, off);
      if (lane + off < 64) { sA += xA; sB += xB; sC += xC; sD += xD; }
    }
    if (lane == 0) { s_tot[w][0] = sA; s_tot[w][1] = sB; s_tot[w][2] = sC; s_tot[w][3] = sD; }
    __syncthreads();
    unsigned hA = 0, hB = 0, hC = 0, hD = 0;
    for (int w2 = w + 1; w2 < 4; w2++) {
      hA += s_tot[w2][0]; hB += s_tot[w2][1]; hC += s_tot[w2][2]; hD += s_tot[w2][3];
    }
    unsigned IA = sA + hA, IB = sB + hB, IC = sC + hC, ID = sD + hD;
    int i00 = IA & 0xFFFF, i01 = IA >> 16, i02 = IB & 0xFFFF, i03 = IB >> 16;
    int i10 = IC & 0xFFFF, i11 = IC >> 16, i12 = ID & 0xFFFF, i13 = ID >> 16;
    int g01 = L01 ? 1 : 0, g02 = L02 ? 2 : g01, g03 = L03 ? 3 : g02;
    int g11 = L11 ? 1 : 0, g12 = L12 ? 2 : g11, g13 = L13 ? 3 : g12;

    // row 0 winners
    {
      int incl = i00, own = (int)c00;
      if (incl >= r00 && incl - own < r00) { s_win[0] = tid; s_sub[0] = incl - own; }
    }
    {
      int incl = (g01 == 1) ? i01 : i00;
      int own  = (g01 == 1) ? (int)c01 : (int)c00;
      if (incl >= r01 && incl - own < r01) { s_win[1] = tid; s_sub[1] = incl - own; }
    }
    {
      int incl = (g02 == 2) ? i02 : (g02 == 1) ? i01 : i00;
      int own  = (g02 == 2) ? (int)c02 : (g02 == 1) ? (int)c01 : (int)c00;
      if (incl >= r02 && incl - own < r02) { s_win[2] = tid; s_sub[2] = incl - own; }
    }
    {
      int incl = (g03 == 3) ? i03 : (g03 == 2) ? i02 : (g03 == 1) ? i01 : i00;
      int own  = (g03 == 3) ? (int)c03 : (g03 == 2) ? (int)c02 : (g03 == 1) ? (int)c01 : (int)c00;
      if (incl >= r03 && incl - own < r03) { s_win[3] = tid; s_sub[3] = incl - own; }
    }
    // row 1 winners
    {
      int incl = i10, own = (int)c10;
      if (incl >= r10 && incl - own < r10) { s_win[4] = tid; s_sub[4] = incl - own; }
    }
    {
      int incl = (g11 == 1) ? i11 : i10;
      int own  = (g11 == 1) ? (int)c11 : (int)c10;
      if (incl >= r11 && incl - own < r11) { s_win[5] = tid; s_sub[5] = incl - own; }
    }
    {
      int incl = (g12 == 2) ? i12 : (g12 == 1) ? i11 : i10;
      int own  = (g12 == 2) ? (int)c12 : (g12 == 1) ? (int)c11 : (int)c10;
      if (incl >= r12 && incl - own < r12) { s_win[6] = tid; s_sub[6] = incl - own; }
    }
    {
      int incl = (g13 == 3) ? i13 : (g13 == 2) ? i12 : (g13 == 1) ? i11 : i10;
      int own  = (g13 == 3) ? (int)c13 : (g13 == 2) ? (int)c12 : (g13 == 1) ? (int)c11 : (int)c10;
      if (incl >= r13 && incl - own < r13) { s_win[7] = tid; s_sub[7] = incl - own; }
    }
    __syncthreads();
    t00 |= ((unsigned)s_win[0]) << ls; r00 -= s_sub[0];
    t01 |= ((unsigned)s_win[1]) << ls; r01 -= s_sub[1];
    t02 |= ((unsigned)s_win[2]) << ls; r02 -= s_sub[2];
    t03 |= ((unsigned)s_win[3]) << ls; r03 -= s_sub[3];
    t10 |= ((unsigned)s_win[4]) << ls; r10 -= s_sub[4];
    t11 |= ((unsigned)s_win[5]) << ls; r11 -= s_sub[5];
    t12 |= ((unsigned)s_win[6]) << ls; r12 -= s_sub[6];
    t13 |= ((unsigned)s_win[7]) << ls; r13 -= s_sub[7];
  }

  // ---- Z sums per bucket per row ----
  float rmax0 = fmaxf(fmaxf(s_rm[0][0], s_rm[0][1]), fmaxf(s_rm[0][2], s_rm[0][3]));
  float rmax1 = fmaxf(fmaxf(s_rm[1][0], s_rm[1][1]), fmaxf(s_rm[1][2], s_rm[1][3]));
  float z00 = 0.f, z01 = 0.f, z02 = 0.f, z03 = 0.f;
  float z10 = 0.f, z11 = 0.f, z12 = 0.f, z13 = 0.f;
#pragma unroll
  for (int i = 0; i < 7; i++) {
    int m = tid + (i << 8);
    if (m < NPOS) {
      unsigned uu = u0[i];
      int bits = (uu & 0x80000000u) ? (int)(uu ^ 0x80000000u) : (int)(~uu);
      float e = __expf(__int_as_float(bits) - rmax0);
      z00 += (uu >= t00) ? e : 0.f;
      z01 += (uu >= t01) ? e : 0.f;
      z02 += (uu >= t02) ? e : 0.f;
      z03 += (uu >= t03) ? e : 0.f;
      uu = u1[i];
      bits = (uu & 0x80000000u) ? (int)(uu ^ 0x80000000u) : (int)(~uu);
      e = __expf(__int_as_float(bits) - rmax1);
      z10 += (uu >= t10) ? e : 0.f;
      z11 += (uu >= t11) ? e : 0.f;
      z12 += (uu >= t12) ? e : 0.f;
      z13 += (uu >= t13) ? e : 0.f;
    }
  }
  z00 = wsum(z00); z01 = wsum(z01); z02 = wsum(z02); z03 = wsum(z03);
  z10 = wsum(z10); z11 = wsum(z11); z12 = wsum(z12); z13 = wsum(z13);
  if (lane == 0) {
    s_z[w][0] = z00; s_z[w][1] = z01; s_z[w][2] = z02; s_z[w][3] = z03;
    s_z[w][4] = z10; s_z[w][5] = z11; s_z[w][6] = z12; s_z[w][7] = z13;
  }
  __syncthreads();
  float Z00 = s_z[0][0] + s_z[1][0] + s_z[2][0] + s_z[3][0];
  float Z01 = s_z[0][1] + s_z[1][1] + s_z[2][1] + s_z[3][1];
  float Z02 = s_z[0][2] + s_z[1][2] + s_z[2][2] + s_z[3][2];
  float Z03 = s_z[0][3] + s_z[1][3] + s_z[2][3] + s_z[3][3];
  float Z10 = s_z[0][4] + s_z[1][4] + s_z[2][4] + s_z[3][4];
  float Z11 = s_z[0][5] + s_z[1][5] + s_z[2][5] + s_z[3][5];
  float Z12 = s_z[0][6] + s_z[1][6] + s_z[2][6] + s_z[3][6];
  float Z13 = s_z[0][7] + s_z[1][7] + s_z[2][7] + s_z[3][7];
  float A1 = a1p[0], A2 = a2p[0], A3 = a3p[0], A4 = a4p[0];
  float c03v = A4 / Z03;
  float c02v = c03v + A3 / Z02;
  float c01v = c02v + A2 / Z01;
  float c00v = c01v + A1 / Z00;
  float c13v = A4 / Z13;
  float c12v = c13v + A3 / Z12;
  float c11v = c12v + A2 / Z11;
  float c10v = c11v + A1 / Z10;

  // ---- PV (shared V loads, 2 rows) ----
  float4 o0A = make_float4(0.f, 0.f, 0.f, 0.f), o0B = o0A, o0C = o0A, o0D = o0A;
  float4 o1A = o0A, o1B = o0A, o1C = o0A, o1D = o0A;
#pragma unroll
  for (int i = 0; i < 7; i++) {
    int m = tid + (i << 8);
    if (m < NPOS) {
      unsigned uu = u0[i];
      int bits = (uu & 0x80000000u) ? (int)(uu ^ 0x80000000u) : (int)(~uu);
      float cf = (uu >= t00) ? c00v : (uu >= t01) ? c01v : (uu >= t02) ? c02v
               : (uu >= t03) ? c03v : 0.f;
      float wg0 = __expf(__int_as_float(bits) - rmax0) * cf;
      uu = u1[i];
      bits = (uu & 0x80000000u) ? (int)(uu ^ 0x80000000u) : (int)(~uu);
      cf = (uu >= t10) ? c10v : (uu >= t11) ? c11v : (uu >= t12) ? c12v
         : (uu >= t13) ? c13v : 0.f;
      float wg1 = __expf(__int_as_float(bits) - rmax1) * cf;
      const float4* v4 = (const float4*)(vbase + (size_t)m * CHD);
      float4 va = v4[0], vb = v4[1], vc = v4[2], vd = v4[3];
      o0A.x += wg0 * va.x; o0A.y += wg0 * va.y; o0A.z += wg0 * va.z; o0A.w += wg0 * va.w;
      o0B.x += wg0 * vb.x; o0B.y += wg0 * vb.y; o0B.z += wg0 * vb.z; o0B.w += wg0 * vb.w;
      o0C.x += wg0 * vc.x; o0C.y += wg0 * vc.y; o0C.z += wg0 * vc.z; o0C.w += wg0 * vc.w;
      o0D.x += wg0 * vd.x; o0D.y += wg0 * vd.y; o0D.z += wg0 * vd.z; o0D.w += wg0 * vd.w;
      o1A.x += wg1 * va.x; o1A.y += wg1 * va.y; o1A.z += wg1 * va.z; o1A.w += wg1 * va.w;
      o1B.x += wg1 * vb.x; o1B.y += wg1 * vb.y; o1B.z += wg1 * vb.z; o1B.w += wg1 * vb.w;
      o1C.x += wg1 * vc.x; o1C.y += wg1 * vc.y; o1C.z += wg1 * vc.z; o1C.w += wg1 * vc.w;
      o1D.x += wg1 * vd.x; o1D.y += wg1 * vd.y; o1D.z += wg1 * vd.z; o1D.w += wg1 * vd.w;
    }
  }
  {
    float rr[32] = {o0A.x, o0A.y, o0A.z, o0A.w, o0B.x, o0B.y, o0B.z, o0B.w,
                    o0C.x, o0C.y, o0C.z, o0C.w, o0D.x, o0D.y, o0D.z, o0D.w,
                    o1A.x, o1A.y, o1A.z, o1A.w, o1B.x, o1B.y, o1B.z, o1B.w,
                    o1C.x, o1C.y, o1C.z, o1C.w, o1D.x, o1D.y, o1D.z, o1D.w};
#pragma unroll
    for (int c = 0; c < 32; c++) rr[c] = wsum(rr[c]);
    if (lane == 0) {
#pragma unroll
      for (int c = 0; c < 32; c++) s_wr[w][c] = rr[c];
    }
  }
  __syncthreads();
  if (tid < 8) {
    int r = tid >> 2, qn = tid & 3;
    int base = r * 16 + qn * 4;
    float4 o;
    o.x = s_wr[0][base + 0] + s_wr[1][base + 0] + s_wr[2][base + 0] + s_wr[3][base + 0];
    o.y = s_wr[0][base + 1] + s_wr[1][base + 1] + s_wr[2][base + 1] + s_wr[3][base + 1];
    o.z = s_wr[0][base + 2] + s_wr[1][base + 2] + s_wr[2][base + 2] + s_wr[3][base + 2];
    o.w = s_wr[0][base + 3] + s_wr[1][base + 3] + s_wr[2][base + 3] + s_wr[3][base + 3];
    *(float4*)(outA + ((size_t)h * NPOS + n0 + r) * CHD + qn * 4) = o;
  }
}

// -------- final 1x1 conv (4 positions per block, position-major outA) --------
__global__ __launch_bounds__(128) void k_fconv(const float* __restrict__ outA,
                                               const float* __restrict__ ow,
                                               float* __restrict__ y) {
  int n0 = blockIdx.x * 4;
  int t = threadIdx.x;
  __shared__ __align__(16) float oc[4][DIMC];
  {
    int pos = t >> 5, ch4 = t & 31;
    int head = ch4 >> 2, qq = ch4 & 3;
    float4 v = *(const float4*)(outA + ((size_t)(head * NPOS) + n0 + pos) * CHD + qq * 4);
    *(float4*)&oc[pos][ch4 * 4] = v;
  }
  __syncthreads();
  float acc[4] = {0.f, 0.f, 0.f, 0.f};
  const float* wr = ow + t * DIMC;
  for (int i = 0; i < DIMC; i++) {
    float w = wr[i];
#pragma unroll
    for (int p = 0; p < 4; p++) acc[p] += w * oc[p][i];
  }
#pragma unroll
  for (int p = 0; p < 4; p++) y[t * NPOS + n0 + p] = acc[p];
}

extern "C" void kernel_launch(void* const* d_in, const int* in_sizes, int n_in,
                              void* d_out, int out_size, void* d_ws, size_t ws_size,
                              hipStream_t stream) {
  const float* x = (const float*)d_in[0];
  const float* pe_w = (const float*)d_in[1];
  const float* pe_b = (const float*)d_in[2];
  const float* ln_g = (const float*)d_in[3];
  const float* ln_b = (const float*)d_in[4];
  const float* aspp_w1 = (const float*)d_in[5];
  const float* bn1_g = (const float*)d_in[6];
  const float* bn1_b = (const float*)d_in[7];
  const float* bn1_m = (const float*)d_in[8];
  const float* bn1_v = (const float*)d_in[9];
  const float* aspp_w2 = (const float*)d_in[10];
  const float* bn2_g = (const float*)d_in[11];
  const float* bn2_b = (const float*)d_in[12];
  const float* bn2_m = (const float*)d_in[13];
  const float* bn2_v = (const float*)d_in[14];
  const float* proj_w = (const float*)d_in[15];
  const float* bnp_g = (const float*)d_in[16];
  const float* bnp_b = (const float*)d_in[17];
  const float* bnp_m = (const float*)d_in[18];
  const float* bnp_v = (const float*)d_in[19];
  const float* kv_w = (const float*)d_in[20];
  const float* kvdw_w = (const float*)d_in[21];
  const float* out_w = (const float*)d_in[22];
  const float* temperature = (const float*)d_in[23];
  const float* a1 = (const float*)d_in[24];
  const float* a2 = (const float*)d_in[25];
  const float* a3 = (const float*)d_in[26];
  const float* a4 = (const float*)d_in[27];

  float* ws = (float*)d_ws;
  float* xr = ws;
  float* qraw = ws + 204800;
  float* kv1t = ws + 409600;
  float* kbuf = ws + 819200;
  float* vt = ws + 1024000;
  float* qt = ws + 1228800;
  float* kt = ws + 1433600;
  float* outA = ws + 1638400;
  float* w1t = ws + 1843200;
  float* w2t = ws + 1990656;

  k_transw<<<576, 256, 0, stream>>>(aspp_w1, aspp_w2, w1t, w2t);
  k_pe_ln<<<1600, 128, 0, stream>>>(x, pe_w, pe_b, ln_g, ln_b, xr);
  k_aspp<<<400, 256, 0, stream>>>(xr, w1t, w2t, bn1_g, bn1_b, bn1_m, bn1_v,
                                  bn2_g, bn2_b, bn2_m, bn2_v, proj_w,
                                  bnp_g, bnp_b, bnp_m, bnp_v, qraw);
  k_kv1<<<400, 256, 0, stream>>>(xr, kv_w, kv1t);
  k_dw<<<400, 256, 0, stream>>>(kv1t, kvdw_w, kbuf, vt);
  k_norm<<<256, 256, 0, stream>>>(qraw, kbuf, qt, kt);
  k_attn<<<dim3(800, 8), 256, 0, stream>>>(qt, kt, vt, temperature, a1, a2, a3, a4, outA);
  k_fconv<<<400, 128, 0, stream>>>(outA, out_w, (float*)d_out);
}

// Round 5
// 288.350 us; speedup vs baseline: 3.1292x; 1.1885x over previous
//
#include <hip/hip_runtime.h>

#define NPOS 1600
#define DIMC 128
#define NHEADS 8
#define CHD 16

// ---------------- workspace layout (floats) ----------------
// 0        xrt     204800   (x + LN(pe(x)), position-major [1600][128])
// 204800   qraw    204800   (channel-major, pre-norm q)
// 409600   kv1t    409600   (1600 x 256, position-major)
// 819200   kbuf    204800   (channel-major, pre-norm k)
// 1024000  vt      204800   (position-major [h][m][16])
// 1228800  pewt    16384    \
// 1245184  kvt     32768     } transient (qt region; dead before k_norm writes qt)
// 1277952  projt   32768    /
// 1228800  qt      204800   (written by k_norm, after transients consumed)
// 1433600  kt      204800
// 1638400  xt/outA 204800   (xt consumed before k_attn writes outA)
// 1843200  w1t     147456   ([k][i][o])
// 1990656  w2t     147456
// 2138112  outwt   16384

__device__ __forceinline__ float wsum(float v) {
#pragma unroll
  for (int off = 1; off < 64; off <<= 1) v += __shfl_xor(v, off);
  return v;
}
__device__ __forceinline__ float wmax(float v) {
#pragma unroll
  for (int off = 1; off < 64; off <<= 1) v = fmaxf(v, __shfl_xor(v, off));
  return v;
}

// -------- one-time weight transposes --------
__global__ void k_prep(const float* __restrict__ w1, const float* __restrict__ w2,
                       const float* __restrict__ proj, const float* __restrict__ kvw,
                       const float* __restrict__ outw, const float* __restrict__ pew,
                       float* __restrict__ w1t, float* __restrict__ w2t,
                       float* __restrict__ projt, float* __restrict__ kvt,
                       float* __restrict__ outwt, float* __restrict__ pewt) {
  int idx = blockIdx.x * 256 + threadIdx.x;
  if (idx < 9 * DIMC * DIMC) {  // [o][i][k] -> [k][i][o]
    int k = idx / (DIMC * DIMC);
    int rem = idx % (DIMC * DIMC);
    int i = rem >> 7, o = rem & 127;
    w1t[idx] = w1[(o * DIMC + i) * 9 + k];
    w2t[idx] = w2[(o * DIMC + i) * 9 + k];
  }
  if (idx < 256 * DIMC) {  // proj [o][ic] -> [ic][o]
    int ic = idx >> 7, o = idx & 127;
    projt[idx] = proj[o * 256 + ic];
  }
  if (idx < DIMC * 256) {  // kv [oc][i] -> [i][oc]
    int i = idx >> 8, oc = idx & 255;
    kvt[idx] = kvw[oc * DIMC + i];
  }
  if (idx < DIMC * DIMC) {  // [o][i] -> [i][o]
    int i = idx >> 7, o = idx & 127;
    outwt[idx] = outw[o * DIMC + i];
    pewt[idx] = pew[o * DIMC + i];
  }
}

// -------- transpose x: [128][1600] -> [1600][128] --------
__global__ __launch_bounds__(256) void k_xt(const float* __restrict__ x,
                                            float* __restrict__ xt) {
  int n0 = blockIdx.x * 16;
  int t = threadIdx.x;
  __shared__ float tile[DIMC][17];
#pragma unroll
  for (int pass = 0; pass < 2; pass++) {
    int ch = (t >> 2) + pass * 64, q = t & 3;
    float4 v = *(const float4*)(x + (size_t)ch * NPOS + n0 + q * 4);
    tile[ch][q * 4 + 0] = v.x; tile[ch][q * 4 + 1] = v.y;
    tile[ch][q * 4 + 2] = v.z; tile[ch][q * 4 + 3] = v.w;
  }
  __syncthreads();
  int pos = t >> 4, c8 = (t & 15) * 8;
#pragma unroll
  for (int k = 0; k < 8; k++)
    xt[(size_t)(n0 + pos) * DIMC + c8 + k] = tile[c8 + k][pos];
}

// -------- pe (1x1 conv) + LayerNorm(ch) + residual; position-major in/out --------
__global__ __launch_bounds__(128) void k_pe_ln(
    const float* __restrict__ xt, const float* __restrict__ pewt,
    const float* __restrict__ pb, const float* __restrict__ lg,
    const float* __restrict__ lb, float* __restrict__ xrt) {
  int n0 = blockIdx.x * 4;
  int t = threadIdx.x;
  __shared__ __align__(16) float xc[4][DIMC];
  __shared__ float red[2][2][4];
  {
    int pos = t >> 5, c4 = t & 31;
    *(float4*)&xc[pos][c4 * 4] =
        *(const float4*)(xt + (size_t)(n0 + pos) * DIMC + c4 * 4);
  }
  __syncthreads();
  float pbv = pb[t];
  float acc[4] = {pbv, pbv, pbv, pbv};
  for (int i = 0; i < DIMC; i++) {
    float wv = pewt[i * DIMC + t];
#pragma unroll
    for (int p = 0; p < 4; p++) acc[p] += wv * xc[p][i];
  }
  int w = t >> 6, lane = t & 63;
  {
    float s0 = wsum(acc[0]), s1 = wsum(acc[1]), s2 = wsum(acc[2]), s3 = wsum(acc[3]);
    if (lane == 0) { red[0][w][0] = s0; red[0][w][1] = s1; red[0][w][2] = s2; red[0][w][3] = s3; }
  }
  __syncthreads();
  float mu[4];
#pragma unroll
  for (int p = 0; p < 4; p++) mu[p] = (red[0][0][p] + red[0][1][p]) * (1.f / 128.f);
  {
    float d0 = acc[0] - mu[0], d1 = acc[1] - mu[1], d2 = acc[2] - mu[2], d3 = acc[3] - mu[3];
    float q0 = wsum(d0 * d0), q1 = wsum(d1 * d1), q2 = wsum(d2 * d2), q3 = wsum(d3 * d3);
    if (lane == 0) { red[1][w][0] = q0; red[1][w][1] = q1; red[1][w][2] = q2; red[1][w][3] = q3; }
  }
  __syncthreads();
  float lgv = lg[t], lbv = lb[t];
#pragma unroll
  for (int p = 0; p < 4; p++) {
    float var = (red[1][0][p] + red[1][1][p]) * (1.f / 128.f);
    float tv = (acc[p] - mu[p]) * rsqrtf(var + 1e-5f) * lgv + lbv;
    xrt[(size_t)(n0 + p) * DIMC + t] = xc[p][t] + tv;
  }
}

// -------- ASPP branches + bn/relu + proj (1x1) + bn/relu (4-col strips) --------
__global__ __launch_bounds__(256) void k_aspp(
    const float* __restrict__ xrt, const float* __restrict__ w1t,
    const float* __restrict__ w2t, const float* __restrict__ bg1,
    const float* __restrict__ bb1, const float* __restrict__ bm1,
    const float* __restrict__ bv1, const float* __restrict__ bg2,
    const float* __restrict__ bb2, const float* __restrict__ bm2,
    const float* __restrict__ bv2, const float* __restrict__ projt,
    const float* __restrict__ bgp, const float* __restrict__ bbp,
    const float* __restrict__ bmp, const float* __restrict__ bvp,
    float* __restrict__ q) {
  int strip = blockIdx.x;
  int r = strip / 10, c0 = (strip % 10) * 4;
  int t = threadIdx.x;
  int ch = t & 127, br = t >> 7;
  __shared__ float xs[2][DIMC][4];
  __shared__ float cat[2 * DIMC][4];
  float aa[4] = {0.f, 0.f, 0.f, 0.f};
  int dil = br ? 5 : 3;
  const float* wt = br ? w2t : w1t;
  for (int k = 0; k < 9; k++) {
    int dr = k / 3 - 1, dc = k % 3 - 1;
    int rr = r + dil * dr;
#pragma unroll
    for (int p = 0; p < 4; p++) {
      int cc = c0 + p + dil * dc;
      xs[br][ch][p] = (rr >= 0 && rr < 40 && cc >= 0 && cc < 40)
                          ? xrt[(size_t)(rr * 40 + cc) * DIMC + ch] : 0.f;
    }
    __syncthreads();
    const float* wrow = wt + (size_t)k * DIMC * DIMC + ch;
    for (int i = 0; i < DIMC; i++) {
      float wv = wrow[i * DIMC];
#pragma unroll
      for (int p = 0; p < 4; p++) aa[p] += wv * xs[br][i][p];
    }
    __syncthreads();
  }
  float sc = br ? bg2[ch] * rsqrtf(bv2[ch] + 1e-5f) : bg1[ch] * rsqrtf(bv1[ch] + 1e-5f);
  float bm = br ? bm2[ch] : bm1[ch];
  float bb = br ? bb2[ch] : bb1[ch];
#pragma unroll
  for (int p = 0; p < 4; p++) cat[br * DIMC + ch][p] = fmaxf((aa[p] - bm) * sc + bb, 0.f);
  __syncthreads();
  float qa0 = 0.f, qa1 = 0.f;
  int pbase = br * 2;
  for (int j = 0; j < 256; j++) {
    float wv = projt[j * DIMC + ch];
    qa0 += wv * cat[j][pbase];
    qa1 += wv * cat[j][pbase + 1];
  }
  float scp = bgp[ch] * rsqrtf(bvp[ch] + 1e-5f);
  q[ch * NPOS + r * 40 + c0 + pbase]     = fmaxf((qa0 - bmp[ch]) * scp + bbp[ch], 0.f);
  q[ch * NPOS + r * 40 + c0 + pbase + 1] = fmaxf((qa1 - bmp[ch]) * scp + bbp[ch], 0.f);
}

// -------- kv 1x1 conv (4 positions per block) --------
__global__ __launch_bounds__(256) void k_kv1(const float* __restrict__ xrt,
                                             const float* __restrict__ kvt,
                                             float* __restrict__ kv1t) {
  int n0 = blockIdx.x * 4;
  int t = threadIdx.x;
  __shared__ __align__(16) float xc[4][DIMC];
  if (t < 128) {
    int pos = t >> 5, c4 = t & 31;
    *(float4*)&xc[pos][c4 * 4] =
        *(const float4*)(xrt + (size_t)(n0 + pos) * DIMC + c4 * 4);
  }
  __syncthreads();
  float acc[4] = {0.f, 0.f, 0.f, 0.f};
  for (int i = 0; i < DIMC; i++) {
    float w = kvt[i * 256 + t];
#pragma unroll
    for (int p = 0; p < 4; p++) acc[p] += w * xc[p][i];
  }
#pragma unroll
  for (int p = 0; p < 4; p++) kv1t[(n0 + p) * 256 + t] = acc[p];
}

// -------- depthwise 3x3 (4-col strips): k -> channel-major, v -> position-major --------
__global__ __launch_bounds__(256) void k_dw(const float* __restrict__ kv1t,
                                            const float* __restrict__ dww,
                                            float* __restrict__ kbuf,
                                            float* __restrict__ vt) {
  int strip = blockIdx.x;
  int r = strip / 10, c0 = (strip % 10) * 4;
  int t = threadIdx.x;
  float wl[9];
#pragma unroll
  for (int k = 0; k < 9; k++) wl[k] = dww[t * 9 + k];
  for (int p = 0; p < 4; p++) {
    int c = c0 + p;
    float acc = 0.f;
#pragma unroll
    for (int kh = 0; kh < 3; kh++) {
      int rr = r + kh - 1;
      if (rr < 0 || rr >= 40) continue;
#pragma unroll
      for (int kw_ = 0; kw_ < 3; kw_++) {
        int cc = c + kw_ - 1;
        if (cc < 0 || cc >= 40) continue;
        acc += wl[kh * 3 + kw_] * kv1t[(rr * 40 + cc) * 256 + t];
      }
    }
    int pos = r * 40 + c;
    if (t < DIMC) {
      kbuf[t * NPOS + pos] = acc;
    } else {
      int cv = t - DIMC;
      vt[((size_t)(cv >> 4) * NPOS + pos) * CHD + (cv & 15)] = acc;
    }
  }
}

// -------- per-channel L2 norm (q and k merged), write position-major --------
__global__ __launch_bounds__(256) void k_norm(const float* __restrict__ qraw,
                                              const float* __restrict__ kbuf,
                                              float* __restrict__ qt,
                                              float* __restrict__ kt) {
  int b = blockIdx.x, t = threadIdx.x;
  const float* in = (b < 128) ? qraw : kbuf;
  float* out_t = (b < 128) ? qt : kt;
  int ch = b & 127;
  __shared__ float wred[4];
  float ss = 0.f;
  for (int m = t; m < NPOS; m += 256) {
    float v = in[ch * NPOS + m];
    ss += v * v;
  }
  ss = wsum(ss);
  if ((t & 63) == 0) wred[t >> 6] = ss;
  __syncthreads();
  float tot = wred[0] + wred[1] + wred[2] + wred[3];
  float inv = 1.0f / fmaxf(sqrtf(tot), 1e-12f);
  int h = ch >> 4, c = ch & 15;
  for (int m = t; m < NPOS; m += 256)
    out_t[((size_t)(h * NPOS) + m) * CHD + c] = in[ch * NPOS + m] * inv;
}

// -------- fused attention: 2 rows/block, wave-redundant radix select --------
#define RANK_STEP(INCL, S0, S1, S2, S3, REM, TT)                         \
  {                                                                      \
    int abv = (INCL) - (S0);                                             \
    int ge1 = abv + (S1), ge2 = abv + (S2), ge3 = abv + (S3);            \
    bool hit = ((INCL) >= (REM)) && (abv < (REM));                       \
    bool c0_ = hit && (ge1 < (REM));                                     \
    bool c1_ = hit && (ge1 >= (REM)) && (ge2 < (REM));                   \
    bool c2_ = hit && (ge2 >= (REM)) && (ge3 < (REM));                   \
    int bl = c0_ ? 4 * lane : c1_ ? 4 * lane + 1                         \
           : c2_ ? 4 * lane + 2 : 4 * lane + 3;                          \
    int gl = c0_ ? ge1 : c1_ ? ge2 : c2_ ? ge3 : abv;                    \
    unsigned long long bal = __ballot(hit);                              \
    int wl = (int)__ffsll(bal) - 1;                                      \
    TT |= ((unsigned)__shfl(bl, wl)) << ls;                              \
    REM -= __shfl(gl, wl);                                               \
  }

__global__ __launch_bounds__(256) void k_attn(
    const float* __restrict__ qt, const float* __restrict__ kt,
    const float* __restrict__ vt, const float* __restrict__ temp,
    const float* __restrict__ a1p, const float* __restrict__ a2p,
    const float* __restrict__ a3p, const float* __restrict__ a4p,
    float* __restrict__ outA) {
  __shared__ unsigned hist[2][2][4][256];  // [buf][row][group][bin], 16 KB
  __shared__ float s_rm[2][4];
  __shared__ float s_z[4][8];
  __shared__ float s_wr[4][32];

  int tid = threadIdx.x;
  int lane = tid & 63, w = tid >> 6;
  int n0 = blockIdx.x * 2;
  int h = blockIdx.y;

  float tmpr = temp[h];
  const float* kbase = kt + (size_t)h * NPOS * CHD;
  const float* vbase = vt + (size_t)h * NPOS * CHD;

  const float4* q4a = (const float4*)(qt + ((size_t)h * NPOS + n0) * CHD);
  const float4* q4b = (const float4*)(qt + ((size_t)h * NPOS + n0 + 1) * CHD);
  float4 qa0 = q4a[0], qa1 = q4a[1], qa2 = q4a[2], qa3 = q4a[3];
  float4 qb0 = q4b[0], qb1 = q4b[1], qb2 = q4b[2], qb3 = q4b[3];

  // zero buf0 (overlaps with QK^T)
  ((uint4*)hist)[tid] = make_uint4(0u, 0u, 0u, 0u);
  ((uint4*)hist)[tid + 256] = make_uint4(0u, 0u, 0u, 0u);

  unsigned u0[7], u1[7];
  float smax0 = -1e30f, smax1 = -1e30f;
#pragma unroll
  for (int i = 0; i < 7; i++) {
    int m = tid + (i << 8);
    const float4* k4 = (const float4*)(kbase + (size_t)m * CHD);
    float4 ka = k4[0], kb = k4[1], kc = k4[2], kd = k4[3];
    float s0 = qa0.x * ka.x + qa0.y * ka.y + qa0.z * ka.z + qa0.w * ka.w
             + qa1.x * kb.x + qa1.y * kb.y + qa1.z * kb.z + qa1.w * kb.w
             + qa2.x * kc.x + qa2.y * kc.y + qa2.z * kc.z + qa2.w * kc.w
             + qa3.x * kd.x + qa3.y * kd.y + qa3.z * kd.z + qa3.w * kd.w;
    float s1 = qb0.x * ka.x + qb0.y * ka.y + qb0.z * ka.z + qb0.w * ka.w
             + qb1.x * kb.x + qb1.y * kb.y + qb1.z * kb.z + qb1.w * kb.w
             + qb2.x * kc.x + qb2.y * kc.y + qb2.z * kc.z + qb2.w * kc.w
             + qb3.x * kd.x + qb3.y * kd.y + qb3.z * kd.z + qb3.w * kd.w;
    s0 *= tmpr; s1 *= tmpr;
    bool valid = (m < NPOS);
    smax0 = fmaxf(smax0, valid ? s0 : -1e30f);
    smax1 = fmaxf(smax1, valid ? s1 : -1e30f);
    int b0 = __float_as_int(s0), b1 = __float_as_int(s1);
    unsigned uu0 = ((unsigned)b0) ^ ((b0 < 0) ? 0xFFFFFFFFu : 0x80000000u);
    unsigned uu1 = ((unsigned)b1) ^ ((b1 < 0) ? 0xFFFFFFFFu : 0x80000000u);
    u0[i] = valid ? uu0 : 0x00800000u;  // pad decodes to -3.4e38 -> e = 0
    u1[i] = valid ? uu1 : 0x00800000u;
  }
  {
    float m0 = wmax(smax0), m1 = wmax(smax1);
    if (lane == 0) { s_rm[0][w] = m0; s_rm[1][w] = m1; }
  }
  __syncthreads();  // buf0 zeroed, s_rm written

  unsigned t00 = 0, t01 = 0, t02 = 0, t03 = 0;
  unsigned t10 = 0, t11 = 0, t12 = 0, t13 = 0;
  int r00 = 800, r01 = 1066, r02 = 1200, r03 = 1280;
  int r10 = 800, r11 = 1066, r12 = 1200, r13 = 1280;

#pragma unroll
  for (int level = 3; level >= 0; level--) {
    const int ls = level * 8;
    const unsigned pm = (level == 3) ? 0u : (0xFFFFFFFFu << (ls + 8));
    const int p = (3 - level) & 1;
    unsigned P00 = t00 & pm, P01 = t01 & pm, P02 = t02 & pm, P03 = t03 & pm;
    unsigned P10 = t10 & pm, P11 = t11 & pm, P12 = t12 & pm, P13 = t13 & pm;
    bool L01 = (P01 != P00), L02 = (P02 != P01), L03 = (P03 != P02);
    bool L11 = (P11 != P10), L12 = (P12 != P11), L13 = (P13 != P12);

#pragma unroll
    for (int i = 0; i < 7; i++) {
      {
        unsigned uu = u0[i], pf = uu & pm;
        int g = (pf == P00) ? 0 : (L01 && pf == P01) ? 1 : (L02 && pf == P02) ? 2
              : (L03 && pf == P03) ? 3 : -1;
        if (g >= 0) atomicAdd(&hist[p][0][g][(uu >> ls) & 255], 1u);
      }
      {
        unsigned uu = u1[i], pf = uu & pm;
        int g = (pf == P10) ? 0 : (L11 && pf == P11) ? 1 : (L12 && pf == P12) ? 2
              : (L13 && pf == P13) ? 3 : -1;
        if (g >= 0) atomicAdd(&hist[p][1][g][(uu >> ls) & 255], 1u);
      }
    }
    __syncthreads();  // atomics visible

    // zero the other buffer for next level (no one reads it this level)
    if (level != 0) {
      ((uint4*)(&hist[p ^ 1][0][0][0]))[tid] = make_uint4(0u, 0u, 0u, 0u);
      ((uint4*)(&hist[p ^ 1][0][0][0]))[tid + 256] = make_uint4(0u, 0u, 0u, 0u);
    }

    // wave-redundant select: each wave reads all bins (stride-16B, conflict-free)
    uint4 c00 = *(const uint4*)&hist[p][0][0][lane * 4];
    uint4 c01 = *(const uint4*)&hist[p][0][1][lane * 4];
    uint4 c02 = *(const uint4*)&hist[p][0][2][lane * 4];
    uint4 c03 = *(const uint4*)&hist[p][0][3][lane * 4];
    uint4 c10 = *(const uint4*)&hist[p][1][0][lane * 4];
    uint4 c11 = *(const uint4*)&hist[p][1][1][lane * 4];
    uint4 c12 = *(const uint4*)&hist[p][1][2][lane * 4];
    uint4 c13 = *(const uint4*)&hist[p][1][3][lane * 4];

    int s3_00 = c00.w, s2_00 = s3_00 + c00.z, s1_00 = s2_00 + c00.y, s0_00 = s1_00 + c00.x;
    int s3_01 = c01.w, s2_01 = s3_01 + c01.z, s1_01 = s2_01 + c01.y, s0_01 = s1_01 + c01.x;
    int s3_02 = c02.w, s2_02 = s3_02 + c02.z, s1_02 = s2_02 + c02.y, s0_02 = s1_02 + c02.x;
    int s3_03 = c03.w, s2_03 = s3_03 + c03.z, s1_03 = s2_03 + c03.y, s0_03 = s1_03 + c03.x;
    int s3_10 = c10.w, s2_10 = s3_10 + c10.z, s1_10 = s2_10 + c10.y, s0_10 = s1_10 + c10.x;
    int s3_11 = c11.w, s2_11 = s3_11 + c11.z, s1_11 = s2_11 + c11.y, s0_11 = s1_11 + c11.x;
    int s3_12 = c12.w, s2_12 = s3_12 + c12.z, s1_12 = s2_12 + c12.y, s0_12 = s1_12 + c12.x;
    int s3_13 = c13.w, s2_13 = s3_13 + c13.z, s1_13 = s2_13 + c13.y, s0_13 = s1_13 + c13.x;

    unsigned vA = (unsigned)s0_00 | ((unsigned)s0_01 << 16);
    unsigned vB = (unsigned)s0_02 | ((unsigned)s0_03 << 16);
    unsigned vC = (unsigned)s0_10 | ((unsigned)s0_11 << 16);
    unsigned vD = (unsigned)s0_12 | ((unsigned)s0_13 << 16);
#pragma unroll
    for (int off = 1; off < 64; off <<= 1) {
      unsigned xA = __shfl_down(vA, off), xB = __shfl_down(vB, off);
      unsigned xC = __shfl_down(vC, off), xD = __shfl_down(vD, off);
      if (lane + off < 64) { vA += xA; vB += xB; vC += xC; vD += xD; }
    }
    int i00 = (int)(vA & 0xFFFFu), i01 = (int)(vA >> 16);
    int i02 = (int)(vB & 0xFFFFu), i03 = (int)(vB >> 16);
    int i10 = (int)(vC & 0xFFFFu), i11 = (int)(vC >> 16);
    int i12 = (int)(vD & 0xFFFFu), i13 = (int)(vD >> 16);

    // row 0 ranks (with chained group selection)
    RANK_STEP(i00, s0_00, s1_00, s2_00, s3_00, r00, t00);
    int I1 = L01 ? i01 : i00;
    int S0a = L01 ? s0_01 : s0_00, S1a = L01 ? s1_01 : s1_00;
    int S2a = L01 ? s2_01 : s2_00, S3a = L01 ? s3_01 : s3_00;
    RANK_STEP(I1, S0a, S1a, S2a, S3a, r01, t01);
    int I2 = L02 ? i02 : I1;
    int S0b = L02 ? s0_02 : S0a, S1b = L02 ? s1_02 : S1a;
    int S2b = L02 ? s2_02 : S2a, S3b = L02 ? s3_02 : S3a;
    RANK_STEP(I2, S0b, S1b, S2b, S3b, r02, t02);
    int I3 = L03 ? i03 : I2;
    int S0c = L03 ? s0_03 : S0b, S1c = L03 ? s1_03 : S1b;
    int S2c = L03 ? s2_03 : S2b, S3c = L03 ? s3_03 : S3b;
    RANK_STEP(I3, S0c, S1c, S2c, S3c, r03, t03);
    // row 1 ranks
    RANK_STEP(i10, s0_10, s1_10, s2_10, s3_10, r10, t10);
    int J1 = L11 ? i11 : i10;
    int T0a = L11 ? s0_11 : s0_10, T1a = L11 ? s1_11 : s1_10;
    int T2a = L11 ? s2_11 : s2_10, T3a = L11 ? s3_11 : s3_10;
    RANK_STEP(J1, T0a, T1a, T2a, T3a, r11, t11);
    int J2 = L12 ? i12 : J1;
    int T0b = L12 ? s0_12 : T0a, T1b = L12 ? s1_12 : T1a;
    int T2b = L12 ? s2_12 : T2a, T3b = L12 ? s3_12 : T3a;
    RANK_STEP(J2, T0b, T1b, T2b, T3b, r12, t12);
    int J3 = L13 ? i13 : J2;
    int T0c = L13 ? s0_13 : T0b, T1c = L13 ? s1_13 : T1b;
    int T2c = L13 ? s2_13 : T2b, T3c = L13 ? s3_13 : T3b;
    RANK_STEP(J3, T0c, T1c, T2c, T3c, r13, t13);

    __syncthreads();  // zeroing done + all waves finished reading buf p
  }

  float rmax0 = fmaxf(fmaxf(s_rm[0][0], s_rm[0][1]), fmaxf(s_rm[0][2], s_rm[0][3]));
  float rmax1 = fmaxf(fmaxf(s_rm[1][0], s_rm[1][1]), fmaxf(s_rm[1][2], s_rm[1][3]));

  // ---- single exp pass: Z sums + pack (e, bucket) into u regs ----
  float z00 = 0.f, z01 = 0.f, z02 = 0.f, z03 = 0.f;
  float z10 = 0.f, z11 = 0.f, z12 = 0.f, z13 = 0.f;
#pragma unroll
  for (int i = 0; i < 7; i++) {
    {
      unsigned uu = u0[i];
      int bits = (uu & 0x80000000u) ? (int)(uu ^ 0x80000000u) : (int)(~uu);
      float e = __expf(__int_as_float(bits) - rmax0);
      int b; float ee;
      if (uu >= t01) { b = (uu >= t00) ? 0 : 1; ee = e; }
      else if (uu >= t03) { b = (uu >= t02) ? 2 : 3; ee = e; }
      else { b = 3; ee = 0.f; }
      z00 += (b == 0) ? ee : 0.f;
      z01 += (b <= 1) ? ee : 0.f;
      z02 += (b <= 2) ? ee : 0.f;
      z03 += ee;
      u0[i] = (__float_as_uint(ee) & ~3u) | (unsigned)b;
    }
    {
      unsigned uu = u1[i];
      int bits = (uu & 0x80000000u) ? (int)(uu ^ 0x80000000u) : (int)(~uu);
      float e = __expf(__int_as_float(bits) - rmax1);
      int b; float ee;
      if (uu >= t11) { b = (uu >= t10) ? 0 : 1; ee = e; }
      else if (uu >= t13) { b = (uu >= t12) ? 2 : 3; ee = e; }
      else { b = 3; ee = 0.f; }
      z10 += (b == 0) ? ee : 0.f;
      z11 += (b <= 1) ? ee : 0.f;
      z12 += (b <= 2) ? ee : 0.f;
      z13 += ee;
      u1[i] = (__float_as_uint(ee) & ~3u) | (unsigned)b;
    }
  }
  // butterfly distribute-reduce: 8 Z values
  {
    float zv[8] = {z00, z01, z02, z03, z10, z11, z12, z13};
#pragma unroll
    for (int k = 0; k < 4; k++) {
      float s = (lane & 1) ? zv[k] : zv[k + 4];
      float r = __shfl_xor(s, 1);
      zv[k] = ((lane & 1) ? zv[k + 4] : zv[k]) + r;
    }
#pragma unroll
    for (int k = 0; k < 2; k++) {
      float s = (lane & 2) ? zv[k] : zv[k + 2];
      float r = __shfl_xor(s, 2);
      zv[k] = ((lane & 2) ? zv[k + 2] : zv[k]) + r;
    }
    {
      float s = (lane & 4) ? zv[0] : zv[1];
      float r = __shfl_xor(s, 4);
      zv[0] = ((lane & 4) ? zv[1] : zv[0]) + r;
    }
    zv[0] += __shfl_xor(zv[0], 8);
    zv[0] += __shfl_xor(zv[0], 16);
    zv[0] += __shfl_xor(zv[0], 32);
    int zidx = ((lane & 1) << 2) | (lane & 2) | ((lane & 4) >> 2);
    if (lane < 8) s_z[w][zidx] = zv[0];
  }
  __syncthreads();
  float Z[8];
#pragma unroll
  for (int j = 0; j < 8; j++) Z[j] = s_z[0][j] + s_z[1][j] + s_z[2][j] + s_z[3][j];
  float A1 = a1p[0], A2 = a2p[0], A3 = a3p[0], A4 = a4p[0];
  float c03v = A4 / Z[3], c02v = c03v + A3 / Z[2];
  float c01v = c02v + A2 / Z[1], c00v = c01v + A1 / Z[0];
  float c13v = A4 / Z[7], c12v = c13v + A3 / Z[6];
  float c11v = c12v + A2 / Z[5], c10v = c11v + A1 / Z[4];

  // ---- PV ----
  float4 o0A = make_float4(0.f, 0.f, 0.f, 0.f), o0B = o0A, o0C = o0A, o0D = o0A;
  float4 o1A = o0A, o1B = o0A, o1C = o0A, o1D = o0A;
#pragma unroll
  for (int i = 0; i < 7; i++) {
    int m = tid + (i << 8);
    unsigned pe0 = u0[i];
    int b0 = pe0 & 3;
    float wg0 = __uint_as_float(pe0 & ~3u)
              * ((b0 == 0) ? c00v : (b0 == 1) ? c01v : (b0 == 2) ? c02v : c03v);
    unsigned pe1 = u1[i];
    int b1 = pe1 & 3;
    float wg1 = __uint_as_float(pe1 & ~3u)
              * ((b1 == 0) ? c10v : (b1 == 1) ? c11v : (b1 == 2) ? c12v : c13v);
    const float4* v4 = (const float4*)(vbase + (size_t)m * CHD);
    float4 va = v4[0], vb = v4[1], vc = v4[2], vd = v4[3];
    o0A.x += wg0 * va.x; o0A.y += wg0 * va.y; o0A.z += wg0 * va.z; o0A.w += wg0 * va.w;
    o0B.x += wg0 * vb.x; o0B.y += wg0 * vb.y; o0B.z += wg0 * vb.z; o0B.w += wg0 * vb.w;
    o0C.x += wg0 * vc.x; o0C.y += wg0 * vc.y; o0C.z += wg0 * vc.z; o0C.w += wg0 * vc.w;
    o0D.x += wg0 * vd.x; o0D.y += wg0 * vd.y; o0D.z += wg0 * vd.z; o0D.w += wg0 * vd.w;
    o1A.x += wg1 * va.x; o1A.y += wg1 * va.y; o1A.z += wg1 * va.z; o1A.w += wg1 * va.w;
    o1B.x += wg1 * vb.x; o1B.y += wg1 * vb.y; o1B.z += wg1 * vb.z; o1B.w += wg1 * vb.w;
    o1C.x += wg1 * vc.x; o1C.y += wg1 * vc.y; o1C.z += wg1 * vc.z; o1C.w += wg1 * vc.w;
    o1D.x += wg1 * vd.x; o1D.y += wg1 * vd.y; o1D.z += wg1 * vd.z; o1D.w += wg1 * vd.w;
  }
  {
    float rr[32] = {o0A.x, o0A.y, o0A.z, o0A.w, o0B.x, o0B.y, o0B.z, o0B.w,
                    o0C.x, o0C.y, o0C.z, o0C.w, o0D.x, o0D.y, o0D.z, o0D.w,
                    o1A.x, o1A.y, o1A.z, o1A.w, o1B.x, o1B.y, o1B.z, o1B.w,
                    o1C.x, o1C.y, o1C.z, o1C.w, o1D.x, o1D.y, o1D.z, o1D.w};
#pragma unroll
    for (int k = 0; k < 16; k++) {
      float s = (lane & 1) ? rr[k] : rr[k + 16];
      float r = __shfl_xor(s, 1);
      rr[k] = ((lane & 1) ? rr[k + 16] : rr[k]) + r;
    }
#pragma unroll
    for (int k = 0; k < 8; k++) {
      float s = (lane & 2) ? rr[k] : rr[k + 8];
      float r = __shfl_xor(s, 2);
      rr[k] = ((lane & 2) ? rr[k + 8] : rr[k]) + r;
    }
#pragma unroll
    for (int k = 0; k < 4; k++) {
      float s = (lane & 4) ? rr[k] : rr[k + 4];
      float r = __shfl_xor(s, 4);
      rr[k] = ((lane & 4) ? rr[k + 4] : rr[k]) + r;
    }
#pragma unroll
    for (int k = 0; k < 2; k++) {
      float s = (lane & 8) ? rr[k] : rr[k + 2];
      float r = __shfl_xor(s, 8);
      rr[k] = ((lane & 8) ? rr[k + 2] : rr[k]) + r;
    }
    {
      float s = (lane & 16) ? rr[0] : rr[1];
      float r = __shfl_xor(s, 16);
      rr[0] = ((lane & 16) ? rr[1] : rr[0]) + r;
    }
    rr[0] += __shfl_xor(rr[0], 32);
    int idx = ((lane & 1) << 4) | ((lane & 2) << 2) | (lane & 4)
            | ((lane & 8) >> 2) | ((lane & 16) >> 4);
    if (lane < 32) s_wr[w][idx] = rr[0];
  }
  __syncthreads();
  if (tid < 32) {
    float v = s_wr[0][tid] + s_wr[1][tid] + s_wr[2][tid] + s_wr[3][tid];
    int r = tid >> 4, c = tid & 15;
    outA[((size_t)h * NPOS + n0 + r) * CHD + c] = v;
  }
}

// -------- final 1x1 conv (4 positions per block, position-major outA) --------
__global__ __launch_bounds__(128) void k_fconv(const float* __restrict__ outA,
                                               const float* __restrict__ outwt,
                                               float* __restrict__ y) {
  int n0 = blockIdx.x * 4;
  int t = threadIdx.x;
  __shared__ __align__(16) float oc[4][DIMC];
  {
    int pos = t >> 5, ch4 = t & 31;
    int head = ch4 >> 2, qq = ch4 & 3;
    float4 v = *(const float4*)(outA + ((size_t)(head * NPOS) + n0 + pos) * CHD + qq * 4);
    *(float4*)&oc[pos][ch4 * 4] = v;
  }
  __syncthreads();
  float acc[4] = {0.f, 0.f, 0.f, 0.f};
  for (int i = 0; i < DIMC; i++) {
    float w = outwt[i * DIMC + t];
#pragma unroll
    for (int p = 0; p < 4; p++) acc[p] += w * oc[p][i];
  }
#pragma unroll
  for (int p = 0; p < 4; p++) y[t * NPOS + n0 + p] = acc[p];
}

extern "C" void kernel_launch(void* const* d_in, const int* in_sizes, int n_in,
                              void* d_out, int out_size, void* d_ws, size_t ws_size,
                              hipStream_t stream) {
  const float* x = (const float*)d_in[0];
  const float* pe_w = (const float*)d_in[1];
  const float* pe_b = (const float*)d_in[2];
  const float* ln_g = (const float*)d_in[3];
  const float* ln_b = (const float*)d_in[4];
  const float* aspp_w1 = (const float*)d_in[5];
  const float* bn1_g = (const float*)d_in[6];
  const float* bn1_b = (const float*)d_in[7];
  const float* bn1_m = (const float*)d_in[8];
  const float* bn1_v = (const float*)d_in[9];
  const float* aspp_w2 = (const float*)d_in[10];
  const float* bn2_g = (const float*)d_in[11];
  const float* bn2_b = (const float*)d_in[12];
  const float* bn2_m = (const float*)d_in[13];
  const float* bn2_v = (const float*)d_in[14];
  const float* proj_w = (const float*)d_in[15];
  const float* bnp_g = (const float*)d_in[16];
  const float* bnp_b = (const float*)d_in[17];
  const float* bnp_m = (const float*)d_in[18];
  const float* bnp_v = (const float*)d_in[19];
  const float* kv_w = (const float*)d_in[20];
  const float* kvdw_w = (const float*)d_in[21];
  const float* out_w = (const float*)d_in[22];
  const float* temperature = (const float*)d_in[23];
  const float* a1 = (const float*)d_in[24];
  const float* a2 = (const float*)d_in[25];
  const float* a3 = (const float*)d_in[26];
  const float* a4 = (const float*)d_in[27];

  float* ws = (float*)d_ws;
  float* xrt = ws;
  float* qraw = ws + 204800;
  float* kv1t = ws + 409600;
  float* kbuf = ws + 819200;
  float* vt = ws + 1024000;
  float* pewt = ws + 1228800;   // transient in qt region
  float* kvt = ws + 1245184;
  float* projt = ws + 1277952;
  float* qt = ws + 1228800;
  float* kt = ws + 1433600;
  float* xt = ws + 1638400;     // shares with outA
  float* outA = ws + 1638400;
  float* w1t = ws + 1843200;
  float* w2t = ws + 1990656;
  float* outwt = ws + 2138112;

  k_prep<<<576, 256, 0, stream>>>(aspp_w1, aspp_w2, proj_w, kv_w, out_w, pe_w,
                                  w1t, w2t, projt, kvt, outwt, pewt);
  k_xt<<<100, 256, 0, stream>>>(x, xt);
  k_pe_ln<<<400, 128, 0, stream>>>(xt, pewt, pe_b, ln_g, ln_b, xrt);
  k_aspp<<<400, 256, 0, stream>>>(xrt, w1t, w2t, bn1_g, bn1_b, bn1_m, bn1_v,
                                  bn2_g, bn2_b, bn2_m, bn2_v, projt,
                                  bnp_g, bnp_b, bnp_m, bnp_v, qraw);
  k_kv1<<<400, 256, 0, stream>>>(xrt, kvt, kv1t);
  k_dw<<<400, 256, 0, stream>>>(kv1t, kvdw_w, kbuf, vt);
  k_norm<<<256, 256, 0, stream>>>(qraw, kbuf, qt, kt);
  k_attn<<<dim3(800, 8), 256, 0, stream>>>(qt, kt, vt, temperature, a1, a2, a3, a4, outA);
  k_fconv<<<400, 128, 0, stream>>>(outA, outwt, (float*)d_out);
}

// Round 6
// 275.160 us; speedup vs baseline: 3.2792x; 1.0479x over previous
//
#include <hip/hip_runtime.h>

#define NPOS 1600
#define DIMC 128
#define NHEADS 8
#define CHD 16

// ---------------- workspace layout (floats) ----------------
// 0        xrt     204800   (x + LN(pe(x)), position-major [1600][128])
// 204800   qraw    204800   (channel-major, pre-norm q)
// 409600   kv1t    409600   (1600 x 256, position-major)
// 819200   kbuf    204800   (channel-major, pre-norm k)
// 1024000  vt      204800   (position-major [h][m][16])
// 1228800  pewt    16384    \
// 1245184  kvt     32768     } transient (qt region; dead before k_norm writes qt)
// 1277952  projt   32768    /
// 1228800  qt      204800   (written by k_norm, after transients consumed)
// 1433600  kt      204800
// 1638400  xt/outA 204800   (xt consumed before k_attn writes outA)
// 1843200  w1t     147456   ([k][i][o])
// 1990656  w2t     147456
// 2138112  outwt   16384

__device__ __forceinline__ float wsum(float v) {
#pragma unroll
  for (int off = 1; off < 64; off <<= 1) v += __shfl_xor(v, off);
  return v;
}
__device__ __forceinline__ float wmax(float v) {
#pragma unroll
  for (int off = 1; off < 64; off <<= 1) v = fmaxf(v, __shfl_xor(v, off));
  return v;
}

// -------- one-time weight transposes + x transpose (merged) --------
__global__ __launch_bounds__(256) void k_prep(
    const float* __restrict__ w1, const float* __restrict__ w2,
    const float* __restrict__ proj, const float* __restrict__ kvw,
    const float* __restrict__ outw, const float* __restrict__ pew,
    const float* __restrict__ x,
    float* __restrict__ w1t, float* __restrict__ w2t,
    float* __restrict__ projt, float* __restrict__ kvt,
    float* __restrict__ outwt, float* __restrict__ pewt,
    float* __restrict__ xt) {
  int bid = blockIdx.x;
  int t = threadIdx.x;
  __shared__ float tile[DIMC][17];
  if (bid < 576) {
    int idx = bid * 256 + t;
    if (idx < 9 * DIMC * DIMC) {  // [o][i][k] -> [k][i][o]
      int k = idx / (DIMC * DIMC);
      int rem = idx % (DIMC * DIMC);
      int i = rem >> 7, o = rem & 127;
      w1t[idx] = w1[(o * DIMC + i) * 9 + k];
      w2t[idx] = w2[(o * DIMC + i) * 9 + k];
    }
    if (idx < 256 * DIMC) {  // proj [o][ic] -> [ic][o]
      int ic = idx >> 7, o = idx & 127;
      projt[idx] = proj[o * 256 + ic];
    }
    if (idx < DIMC * 256) {  // kv [oc][i] -> [i][oc]
      int i = idx >> 8, oc = idx & 255;
      kvt[idx] = kvw[oc * DIMC + i];
    }
    if (idx < DIMC * DIMC) {  // [o][i] -> [i][o]
      int i = idx >> 7, o = idx & 127;
      outwt[idx] = outw[o * DIMC + i];
      pewt[idx] = pew[o * DIMC + i];
    }
  } else {
    int n0 = (bid - 576) * 16;
#pragma unroll
    for (int pass = 0; pass < 2; pass++) {
      int ch = (t >> 2) + pass * 64, q = t & 3;
      float4 v = *(const float4*)(x + (size_t)ch * NPOS + n0 + q * 4);
      tile[ch][q * 4 + 0] = v.x; tile[ch][q * 4 + 1] = v.y;
      tile[ch][q * 4 + 2] = v.z; tile[ch][q * 4 + 3] = v.w;
    }
    __syncthreads();
    int pos = t >> 4, c8 = (t & 15) * 8;
#pragma unroll
    for (int k = 0; k < 8; k++)
      xt[(size_t)(n0 + pos) * DIMC + c8 + k] = tile[c8 + k][pos];
  }
}

// -------- pe (1x1 conv) + LayerNorm(ch) + residual; position-major in/out --------
__global__ __launch_bounds__(128) void k_pe_ln(
    const float* __restrict__ xt, const float* __restrict__ pewt,
    const float* __restrict__ pb, const float* __restrict__ lg,
    const float* __restrict__ lb, float* __restrict__ xrt) {
  int n0 = blockIdx.x * 4;
  int t = threadIdx.x;
  __shared__ __align__(16) float xc[4][DIMC];
  __shared__ float red[2][2][4];
  {
    int pos = t >> 5, c4 = t & 31;
    *(float4*)&xc[pos][c4 * 4] =
        *(const float4*)(xt + (size_t)(n0 + pos) * DIMC + c4 * 4);
  }
  __syncthreads();
  float pbv = pb[t];
  float acc[4] = {pbv, pbv, pbv, pbv};
  for (int i = 0; i < DIMC; i++) {
    float wv = pewt[i * DIMC + t];
#pragma unroll
    for (int p = 0; p < 4; p++) acc[p] += wv * xc[p][i];
  }
  int w = t >> 6, lane = t & 63;
  {
    float s0 = wsum(acc[0]), s1 = wsum(acc[1]), s2 = wsum(acc[2]), s3 = wsum(acc[3]);
    if (lane == 0) { red[0][w][0] = s0; red[0][w][1] = s1; red[0][w][2] = s2; red[0][w][3] = s3; }
  }
  __syncthreads();
  float mu[4];
#pragma unroll
  for (int p = 0; p < 4; p++) mu[p] = (red[0][0][p] + red[0][1][p]) * (1.f / 128.f);
  {
    float d0 = acc[0] - mu[0], d1 = acc[1] - mu[1], d2 = acc[2] - mu[2], d3 = acc[3] - mu[3];
    float q0 = wsum(d0 * d0), q1 = wsum(d1 * d1), q2 = wsum(d2 * d2), q3 = wsum(d3 * d3);
    if (lane == 0) { red[1][w][0] = q0; red[1][w][1] = q1; red[1][w][2] = q2; red[1][w][3] = q3; }
  }
  __syncthreads();
  float lgv = lg[t], lbv = lb[t];
#pragma unroll
  for (int p = 0; p < 4; p++) {
    float var = (red[1][0][p] + red[1][1][p]) * (1.f / 128.f);
    float tv = (acc[p] - mu[p]) * rsqrtf(var + 1e-5f) * lgv + lbv;
    xrt[(size_t)(n0 + p) * DIMC + t] = xc[p][t] + tv;
  }
}

// -------- ASPP branches + bn/relu + proj (1x1) + bn/relu (4-col strips) --------
__global__ __launch_bounds__(256) void k_aspp(
    const float* __restrict__ xrt, const float* __restrict__ w1t,
    const float* __restrict__ w2t, const float* __restrict__ bg1,
    const float* __restrict__ bb1, const float* __restrict__ bm1,
    const float* __restrict__ bv1, const float* __restrict__ bg2,
    const float* __restrict__ bb2, const float* __restrict__ bm2,
    const float* __restrict__ bv2, const float* __restrict__ projt,
    const float* __restrict__ bgp, const float* __restrict__ bbp,
    const float* __restrict__ bmp, const float* __restrict__ bvp,
    float* __restrict__ q) {
  int strip = blockIdx.x;
  int r = strip / 10, c0 = (strip % 10) * 4;
  int t = threadIdx.x;
  int ch = t & 127, br = t >> 7;
  __shared__ float xs[2][DIMC][4];
  __shared__ float cat[2 * DIMC][4];
  float aa[4] = {0.f, 0.f, 0.f, 0.f};
  int dil = br ? 5 : 3;
  const float* wt = br ? w2t : w1t;
  for (int k = 0; k < 9; k++) {
    int dr = k / 3 - 1, dc = k % 3 - 1;
    int rr = r + dil * dr;
#pragma unroll
    for (int p = 0; p < 4; p++) {
      int cc = c0 + p + dil * dc;
      xs[br][ch][p] = (rr >= 0 && rr < 40 && cc >= 0 && cc < 40)
                          ? xrt[(size_t)(rr * 40 + cc) * DIMC + ch] : 0.f;
    }
    __syncthreads();
    const float* wrow = wt + (size_t)k * DIMC * DIMC + ch;
    for (int i = 0; i < DIMC; i++) {
      float wv = wrow[i * DIMC];
#pragma unroll
      for (int p = 0; p < 4; p++) aa[p] += wv * xs[br][i][p];
    }
    __syncthreads();
  }
  float sc = br ? bg2[ch] * rsqrtf(bv2[ch] + 1e-5f) : bg1[ch] * rsqrtf(bv1[ch] + 1e-5f);
  float bm = br ? bm2[ch] : bm1[ch];
  float bb = br ? bb2[ch] : bb1[ch];
#pragma unroll
  for (int p = 0; p < 4; p++) cat[br * DIMC + ch][p] = fmaxf((aa[p] - bm) * sc + bb, 0.f);
  __syncthreads();
  float qa0 = 0.f, qa1 = 0.f;
  int pbase = br * 2;
  for (int j = 0; j < 256; j++) {
    float wv = projt[j * DIMC + ch];
    qa0 += wv * cat[j][pbase];
    qa1 += wv * cat[j][pbase + 1];
  }
  float scp = bgp[ch] * rsqrtf(bvp[ch] + 1e-5f);
  q[ch * NPOS + r * 40 + c0 + pbase]     = fmaxf((qa0 - bmp[ch]) * scp + bbp[ch], 0.f);
  q[ch * NPOS + r * 40 + c0 + pbase + 1] = fmaxf((qa1 - bmp[ch]) * scp + bbp[ch], 0.f);
}

// -------- kv 1x1 conv (4 positions per block) --------
__global__ __launch_bounds__(256) void k_kv1(const float* __restrict__ xrt,
                                             const float* __restrict__ kvt,
                                             float* __restrict__ kv1t) {
  int n0 = blockIdx.x * 4;
  int t = threadIdx.x;
  __shared__ __align__(16) float xc[4][DIMC];
  if (t < 128) {
    int pos = t >> 5, c4 = t & 31;
    *(float4*)&xc[pos][c4 * 4] =
        *(const float4*)(xrt + (size_t)(n0 + pos) * DIMC + c4 * 4);
  }
  __syncthreads();
  float acc[4] = {0.f, 0.f, 0.f, 0.f};
  for (int i = 0; i < DIMC; i++) {
    float w = kvt[i * 256 + t];
#pragma unroll
    for (int p = 0; p < 4; p++) acc[p] += w * xc[p][i];
  }
#pragma unroll
  for (int p = 0; p < 4; p++) kv1t[(n0 + p) * 256 + t] = acc[p];
}

// -------- depthwise 3x3 (4-col strips): k -> channel-major, v -> position-major --------
__global__ __launch_bounds__(256) void k_dw(const float* __restrict__ kv1t,
                                            const float* __restrict__ dww,
                                            float* __restrict__ kbuf,
                                            float* __restrict__ vt) {
  int strip = blockIdx.x;
  int r = strip / 10, c0 = (strip % 10) * 4;
  int t = threadIdx.x;
  float wl[9];
#pragma unroll
  for (int k = 0; k < 9; k++) wl[k] = dww[t * 9 + k];
  for (int p = 0; p < 4; p++) {
    int c = c0 + p;
    float acc = 0.f;
#pragma unroll
    for (int kh = 0; kh < 3; kh++) {
      int rr = r + kh - 1;
      if (rr < 0 || rr >= 40) continue;
#pragma unroll
      for (int kw_ = 0; kw_ < 3; kw_++) {
        int cc = c + kw_ - 1;
        if (cc < 0 || cc >= 40) continue;
        acc += wl[kh * 3 + kw_] * kv1t[(rr * 40 + cc) * 256 + t];
      }
    }
    int pos = r * 40 + c;
    if (t < DIMC) {
      kbuf[t * NPOS + pos] = acc;
    } else {
      int cv = t - DIMC;
      vt[((size_t)(cv >> 4) * NPOS + pos) * CHD + (cv & 15)] = acc;
    }
  }
}

// -------- per-channel L2 norm (q and k merged), write position-major --------
__global__ __launch_bounds__(256) void k_norm(const float* __restrict__ qraw,
                                              const float* __restrict__ kbuf,
                                              float* __restrict__ qt,
                                              float* __restrict__ kt) {
  int b = blockIdx.x, t = threadIdx.x;
  const float* in = (b < 128) ? qraw : kbuf;
  float* out_t = (b < 128) ? qt : kt;
  int ch = b & 127;
  __shared__ float wred[4];
  float ss = 0.f;
  for (int m = t; m < NPOS; m += 256) {
    float v = in[ch * NPOS + m];
    ss += v * v;
  }
  ss = wsum(ss);
  if ((t & 63) == 0) wred[t >> 6] = ss;
  __syncthreads();
  float tot = wred[0] + wred[1] + wred[2] + wred[3];
  float inv = 1.0f / fmaxf(sqrtf(tot), 1e-12f);
  int h = ch >> 4, c = ch & 15;
  for (int m = t; m < NPOS; m += 256)
    out_t[((size_t)(h * NPOS) + m) * CHD + c] = in[ch * NPOS + m] * inv;
}

// -------- fused attention: 2 rows/block, row-split select --------
#define RANK_STEP(INCL, S0, S1, S2, S3, REM, TT)                         \
  {                                                                      \
    int abv = (INCL) - (S0);                                             \
    int ge1 = abv + (S1), ge2 = abv + (S2), ge3 = abv + (S3);            \
    bool hit = ((INCL) >= (REM)) && (abv < (REM));                       \
    bool c0_ = hit && (ge1 < (REM));                                     \
    bool c1_ = hit && (ge1 >= (REM)) && (ge2 < (REM));                   \
    bool c2_ = hit && (ge2 >= (REM)) && (ge3 < (REM));                   \
    int bl = c0_ ? 4 * lane : c1_ ? 4 * lane + 1                         \
           : c2_ ? 4 * lane + 2 : 4 * lane + 3;                          \
    int gl = c0_ ? ge1 : c1_ ? ge2 : c2_ ? ge3 : abv;                    \
    unsigned long long bal = __ballot(hit);                              \
    int wl = (int)__ffsll(bal) - 1;                                      \
    TT |= ((unsigned)__shfl(bl, wl)) << ls;                              \
    REM -= __shfl(gl, wl);                                               \
  }

__global__ __launch_bounds__(256) void k_attn(
    const float* __restrict__ qt, const float* __restrict__ kt,
    const float* __restrict__ vt, const float* __restrict__ temp,
    const float* __restrict__ a1p, const float* __restrict__ a2p,
    const float* __restrict__ a3p, const float* __restrict__ a4p,
    float* __restrict__ outA) {
  __shared__ unsigned hist[2][2][4][256];  // [buf][row][group|copy][bin], 16 KB
  __shared__ float s_rm[2][4];
  __shared__ unsigned s_thr[2][4];
  __shared__ float s_z[4][8];
  __shared__ float s_wr[4][32];

  int tid = threadIdx.x;
  int lane = tid & 63, w = tid >> 6;
  int myrow = w >> 1;
  int n0 = blockIdx.x * 2;
  int h = blockIdx.y;

  float tmpr = temp[h];
  const float* kbase = kt + (size_t)h * NPOS * CHD;
  const float* vbase = vt + (size_t)h * NPOS * CHD;

  const float4* q4a = (const float4*)(qt + ((size_t)h * NPOS + n0) * CHD);
  const float4* q4b = (const float4*)(qt + ((size_t)h * NPOS + n0 + 1) * CHD);
  float4 qa0 = q4a[0], qa1 = q4a[1], qa2 = q4a[2], qa3 = q4a[3];
  float4 qb0 = q4b[0], qb1 = q4b[1], qb2 = q4b[2], qb3 = q4b[3];

  // zero buf0 (overlaps with QK^T)
  ((uint4*)hist)[tid] = make_uint4(0u, 0u, 0u, 0u);
  ((uint4*)hist)[tid + 256] = make_uint4(0u, 0u, 0u, 0u);

  unsigned u0[7], u1[7];
  float smax0 = -1e30f, smax1 = -1e30f;
#pragma unroll
  for (int i = 0; i < 7; i++) {
    int m = tid + (i << 8);
    const float4* k4 = (const float4*)(kbase + (size_t)m * CHD);
    float4 ka = k4[0], kb = k4[1], kc = k4[2], kd = k4[3];
    float s0 = qa0.x * ka.x + qa0.y * ka.y + qa0.z * ka.z + qa0.w * ka.w
             + qa1.x * kb.x + qa1.y * kb.y + qa1.z * kb.z + qa1.w * kb.w
             + qa2.x * kc.x + qa2.y * kc.y + qa2.z * kc.z + qa2.w * kc.w
             + qa3.x * kd.x + qa3.y * kd.y + qa3.z * kd.z + qa3.w * kd.w;
    float s1 = qb0.x * ka.x + qb0.y * ka.y + qb0.z * ka.z + qb0.w * ka.w
             + qb1.x * kb.x + qb1.y * kb.y + qb1.z * kb.z + qb1.w * kb.w
             + qb2.x * kc.x + qb2.y * kc.y + qb2.z * kc.z + qb2.w * kc.w
             + qb3.x * kd.x + qb3.y * kd.y + qb3.z * kd.z + qb3.w * kd.w;
    s0 *= tmpr; s1 *= tmpr;
    bool valid = (m < NPOS);
    smax0 = fmaxf(smax0, valid ? s0 : -1e30f);
    smax1 = fmaxf(smax1, valid ? s1 : -1e30f);
    int b0 = __float_as_int(s0), b1 = __float_as_int(s1);
    unsigned uu0 = ((unsigned)b0) ^ ((b0 < 0) ? 0xFFFFFFFFu : 0x80000000u);
    unsigned uu1 = ((unsigned)b1) ^ ((b1 < 0) ? 0xFFFFFFFFu : 0x80000000u);
    u0[i] = valid ? uu0 : 0x00800000u;  // pad decodes to -3.4e38 -> e = 0
    u1[i] = valid ? uu1 : 0x00800000u;
  }
  {
    float m0 = wmax(smax0), m1 = wmax(smax1);
    if (lane == 0) { s_rm[0][w] = m0; s_rm[1][w] = m1; }
  }
  __syncthreads();  // buf0 zeroed, s_rm written

  unsigned t00 = 0, t01 = 0, t02 = 0, t03 = 0;
  unsigned t10 = 0, t11 = 0, t12 = 0, t13 = 0;
  int r00 = 800, r01 = 1066, r02 = 1200, r03 = 1280;
  int r10 = 800, r11 = 1066, r12 = 1200, r13 = 1280;

#pragma unroll
  for (int level = 3; level >= 0; level--) {
    const int ls = level * 8;
    const unsigned pm = (level == 3) ? 0u : (0xFFFFFFFFu << (ls + 8));
    const int p = (3 - level) & 1;

    if (level == 3) {
      // single prefix group -> use group slots as per-wave copies (4x less contention)
#pragma unroll
      for (int i = 0; i < 7; i++) {
        atomicAdd(&hist[p][0][w][u0[i] >> 24], 1u);
        atomicAdd(&hist[p][1][w][u1[i] >> 24], 1u);
      }
    } else {
      unsigned P00 = t00 & pm, P01 = t01 & pm, P02 = t02 & pm, P03 = t03 & pm;
      unsigned P10 = t10 & pm, P11 = t11 & pm, P12 = t12 & pm, P13 = t13 & pm;
      bool L01 = (P01 != P00), L02 = (P02 != P01), L03 = (P03 != P02);
      bool L11 = (P11 != P10), L12 = (P12 != P11), L13 = (P13 != P12);
#pragma unroll
      for (int i = 0; i < 7; i++) {
        {
          unsigned uu = u0[i], pf = uu & pm;
          int g = (pf == P00) ? 0 : (L01 && pf == P01) ? 1 : (L02 && pf == P02) ? 2
                : (L03 && pf == P03) ? 3 : -1;
          if (g >= 0) atomicAdd(&hist[p][0][g][(uu >> ls) & 255], 1u);
        }
        {
          unsigned uu = u1[i], pf = uu & pm;
          int g = (pf == P10) ? 0 : (L11 && pf == P11) ? 1 : (L12 && pf == P12) ? 2
                : (L13 && pf == P13) ? 3 : -1;
          if (g >= 0) atomicAdd(&hist[p][1][g][(uu >> ls) & 255], 1u);
        }
      }
    }
    __syncthreads();  // atomics visible

    // zero the other buffer for next level
    if (level != 0) {
      ((uint4*)(&hist[p ^ 1][0][0][0]))[tid] = make_uint4(0u, 0u, 0u, 0u);
      ((uint4*)(&hist[p ^ 1][0][0][0]))[tid + 256] = make_uint4(0u, 0u, 0u, 0u);
    }

    // ---- row-split select: waves 0-1 handle row 0, waves 2-3 row 1 ----
    unsigned ta0, ta1, ta2, ta3;
    int ra0, ra1, ra2, ra3;
    if (myrow == 0) { ta0 = t00; ta1 = t01; ta2 = t02; ta3 = t03;
                      ra0 = r00; ra1 = r01; ra2 = r02; ra3 = r03; }
    else            { ta0 = t10; ta1 = t11; ta2 = t12; ta3 = t13;
                      ra0 = r10; ra1 = r11; ra2 = r12; ra3 = r13; }

    uint4 c0 = *(const uint4*)&hist[p][myrow][0][lane * 4];
    uint4 c1 = *(const uint4*)&hist[p][myrow][1][lane * 4];
    uint4 c2 = *(const uint4*)&hist[p][myrow][2][lane * 4];
    uint4 c3 = *(const uint4*)&hist[p][myrow][3][lane * 4];
    bool L1, L2, L3;
    if (level == 3) {
      c0.x += c1.x + c2.x + c3.x;  // merge per-wave copies
      c0.y += c1.y + c2.y + c3.y;
      c0.z += c1.z + c2.z + c3.z;
      c0.w += c1.w + c2.w + c3.w;
      L1 = false; L2 = false; L3 = false;
    } else {
      L1 = ((ta1 & pm) != (ta0 & pm));
      L2 = ((ta2 & pm) != (ta1 & pm));
      L3 = ((ta3 & pm) != (ta2 & pm));
    }

    int s3_0 = c0.w, s2_0 = s3_0 + c0.z, s1_0 = s2_0 + c0.y, s0_0 = s1_0 + c0.x;
    int s3_1 = c1.w, s2_1 = s3_1 + c1.z, s1_1 = s2_1 + c1.y, s0_1 = s1_1 + c1.x;
    int s3_2 = c2.w, s2_2 = s3_2 + c2.z, s1_2 = s2_2 + c2.y, s0_2 = s1_2 + c2.x;
    int s3_3 = c3.w, s2_3 = s3_3 + c3.z, s1_3 = s2_3 + c3.y, s0_3 = s1_3 + c3.x;

    unsigned vA = (unsigned)s0_0 | ((unsigned)s0_1 << 16);
    unsigned vB = (unsigned)s0_2 | ((unsigned)s0_3 << 16);
#pragma unroll
    for (int off = 1; off < 64; off <<= 1) {
      unsigned xA = __shfl_down(vA, off), xB = __shfl_down(vB, off);
      if (lane + off < 64) { vA += xA; vB += xB; }
    }
    int i0 = (int)(vA & 0xFFFFu), i1 = (int)(vA >> 16);
    int i2 = (int)(vB & 0xFFFFu), i3 = (int)(vB >> 16);

    RANK_STEP(i0, s0_0, s1_0, s2_0, s3_0, ra0, ta0);
    int I1 = L1 ? i1 : i0;
    int S0a = L1 ? s0_1 : s0_0, S1a = L1 ? s1_1 : s1_0;
    int S2a = L1 ? s2_1 : s2_0, S3a = L1 ? s3_1 : s3_0;
    RANK_STEP(I1, S0a, S1a, S2a, S3a, ra1, ta1);
    int I2 = L2 ? i2 : I1;
    int S0b = L2 ? s0_2 : S0a, S1b = L2 ? s1_2 : S1a;
    int S2b = L2 ? s2_2 : S2a, S3b = L2 ? s3_2 : S3a;
    RANK_STEP(I2, S0b, S1b, S2b, S3b, ra2, ta2);
    int I3 = L3 ? i3 : I2;
    int S0c = L3 ? s0_3 : S0b, S1c = L3 ? s1_3 : S1b;
    int S2c = L3 ? s2_3 : S2b, S3c = L3 ? s3_3 : S3b;
    RANK_STEP(I3, S0c, S1c, S2c, S3c, ra3, ta3);

    // publish winners (one wave per row suffices; values wave-uniform)
    if (lane == 0 && (w & 1) == 0) {
      s_thr[myrow][0] = ta0; s_thr[myrow][1] = ta1;
      s_thr[myrow][2] = ta2; s_thr[myrow][3] = ta3;
    }
    // write back own-row registers
    if (myrow == 0) { t00 = ta0; t01 = ta1; t02 = ta2; t03 = ta3;
                      r00 = ra0; r01 = ra1; r02 = ra2; r03 = ra3; }
    else            { t10 = ta0; t11 = ta1; t12 = ta2; t13 = ta3;
                      r10 = ra0; r11 = ra1; r12 = ra2; r13 = ra3; }
    __syncthreads();  // zeroing + publications visible
    // refresh other row's prefixes (needed for next histogram / final passes)
    if (myrow == 0) { t10 = s_thr[1][0]; t11 = s_thr[1][1];
                      t12 = s_thr[1][2]; t13 = s_thr[1][3]; }
    else            { t00 = s_thr[0][0]; t01 = s_thr[0][1];
                      t02 = s_thr[0][2]; t03 = s_thr[0][3]; }
  }

  float rmax0 = fmaxf(fmaxf(s_rm[0][0], s_rm[0][1]), fmaxf(s_rm[0][2], s_rm[0][3]));
  float rmax1 = fmaxf(fmaxf(s_rm[1][0], s_rm[1][1]), fmaxf(s_rm[1][2], s_rm[1][3]));

  // ---- single exp pass: Z sums + pack (e, bucket) into u regs ----
  float z00 = 0.f, z01 = 0.f, z02 = 0.f, z03 = 0.f;
  float z10 = 0.f, z11 = 0.f, z12 = 0.f, z13 = 0.f;
#pragma unroll
  for (int i = 0; i < 7; i++) {
    {
      unsigned uu = u0[i];
      int bits = (uu & 0x80000000u) ? (int)(uu ^ 0x80000000u) : (int)(~uu);
      float e = __expf(__int_as_float(bits) - rmax0);
      int b; float ee;
      if (uu >= t01) { b = (uu >= t00) ? 0 : 1; ee = e; }
      else if (uu >= t03) { b = (uu >= t02) ? 2 : 3; ee = e; }
      else { b = 3; ee = 0.f; }
      z00 += (b == 0) ? ee : 0.f;
      z01 += (b <= 1) ? ee : 0.f;
      z02 += (b <= 2) ? ee : 0.f;
      z03 += ee;
      u0[i] = (__float_as_uint(ee) & ~3u) | (unsigned)b;
    }
    {
      unsigned uu = u1[i];
      int bits = (uu & 0x80000000u) ? (int)(uu ^ 0x80000000u) : (int)(~uu);
      float e = __expf(__int_as_float(bits) - rmax1);
      int b; float ee;
      if (uu >= t11) { b = (uu >= t10) ? 0 : 1; ee = e; }
      else if (uu >= t13) { b = (uu >= t12) ? 2 : 3; ee = e; }
      else { b = 3; ee = 0.f; }
      z10 += (b == 0) ? ee : 0.f;
      z11 += (b <= 1) ? ee : 0.f;
      z12 += (b <= 2) ? ee : 0.f;
      z13 += ee;
      u1[i] = (__float_as_uint(ee) & ~3u) | (unsigned)b;
    }
  }
  // butterfly distribute-reduce: 8 Z values
  {
    float zv[8] = {z00, z01, z02, z03, z10, z11, z12, z13};
#pragma unroll
    for (int k = 0; k < 4; k++) {
      float s = (lane & 1) ? zv[k] : zv[k + 4];
      float r = __shfl_xor(s, 1);
      zv[k] = ((lane & 1) ? zv[k + 4] : zv[k]) + r;
    }
#pragma unroll
    for (int k = 0; k < 2; k++) {
      float s = (lane & 2) ? zv[k] : zv[k + 2];
      float r = __shfl_xor(s, 2);
      zv[k] = ((lane & 2) ? zv[k + 2] : zv[k]) + r;
    }
    {
      float s = (lane & 4) ? zv[0] : zv[1];
      float r = __shfl_xor(s, 4);
      zv[0] = ((lane & 4) ? zv[1] : zv[0]) + r;
    }
    zv[0] += __shfl_xor(zv[0], 8);
    zv[0] += __shfl_xor(zv[0], 16);
    zv[0] += __shfl_xor(zv[0], 32);
    int zidx = ((lane & 1) << 2) | (lane & 2) | ((lane & 4) >> 2);
    if (lane < 8) s_z[w][zidx] = zv[0];
  }
  __syncthreads();
  float Z[8];
#pragma unroll
  for (int j = 0; j < 8; j++) Z[j] = s_z[0][j] + s_z[1][j] + s_z[2][j] + s_z[3][j];
  float A1 = a1p[0], A2 = a2p[0], A3 = a3p[0], A4 = a4p[0];
  float c03v = A4 / Z[3], c02v = c03v + A3 / Z[2];
  float c01v = c02v + A2 / Z[1], c00v = c01v + A1 / Z[0];
  float c13v = A4 / Z[7], c12v = c13v + A3 / Z[6];
  float c11v = c12v + A2 / Z[5], c10v = c11v + A1 / Z[4];

  // ---- PV ----
  float4 o0A = make_float4(0.f, 0.f, 0.f, 0.f), o0B = o0A, o0C = o0A, o0D = o0A;
  float4 o1A = o0A, o1B = o0A, o1C = o0A, o1D = o0A;
#pragma unroll
  for (int i = 0; i < 7; i++) {
    int m = tid + (i << 8);
    unsigned pe0 = u0[i];
    int b0 = pe0 & 3;
    float wg0 = __uint_as_float(pe0 & ~3u)
              * ((b0 == 0) ? c00v : (b0 == 1) ? c01v : (b0 == 2) ? c02v : c03v);
    unsigned pe1 = u1[i];
    int b1 = pe1 & 3;
    float wg1 = __uint_as_float(pe1 & ~3u)
              * ((b1 == 0) ? c10v : (b1 == 1) ? c11v : (b1 == 2) ? c12v : c13v);
    const float4* v4 = (const float4*)(vbase + (size_t)m * CHD);
    float4 va = v4[0], vb = v4[1], vc = v4[2], vd = v4[3];
    o0A.x += wg0 * va.x; o0A.y += wg0 * va.y; o0A.z += wg0 * va.z; o0A.w += wg0 * va.w;
    o0B.x += wg0 * vb.x; o0B.y += wg0 * vb.y; o0B.z += wg0 * vb.z; o0B.w += wg0 * vb.w;
    o0C.x += wg0 * vc.x; o0C.y += wg0 * vc.y; o0C.z += wg0 * vc.z; o0C.w += wg0 * vc.w;
    o0D.x += wg0 * vd.x; o0D.y += wg0 * vd.y; o0D.z += wg0 * vd.z; o0D.w += wg0 * vd.w;
    o1A.x += wg1 * va.x; o1A.y += wg1 * va.y; o1A.z += wg1 * va.z; o1A.w += wg1 * va.w;
    o1B.x += wg1 * vb.x; o1B.y += wg1 * vb.y; o1B.z += wg1 * vb.z; o1B.w += wg1 * vb.w;
    o1C.x += wg1 * vc.x; o1C.y += wg1 * vc.y; o1C.z += wg1 * vc.z; o1C.w += wg1 * vc.w;
    o1D.x += wg1 * vd.x; o1D.y += wg1 * vd.y; o1D.z += wg1 * vd.z; o1D.w += wg1 * vd.w;
  }
  {
    float rr[32] = {o0A.x, o0A.y, o0A.z, o0A.w, o0B.x, o0B.y, o0B.z, o0B.w,
                    o0C.x, o0C.y, o0C.z, o0C.w, o0D.x, o0D.y, o0D.z, o0D.w,
                    o1A.x, o1A.y, o1A.z, o1A.w, o1B.x, o1B.y, o1B.z, o1B.w,
                    o1C.x, o1C.y, o1C.z, o1C.w, o1D.x, o1D.y, o1D.z, o1D.w};
#pragma unroll
    for (int k = 0; k < 16; k++) {
      float s = (lane & 1) ? rr[k] : rr[k + 16];
      float r = __shfl_xor(s, 1);
      rr[k] = ((lane & 1) ? rr[k + 16] : rr[k]) + r;
    }
#pragma unroll
    for (int k = 0; k < 8; k++) {
      float s = (lane & 2) ? rr[k] : rr[k + 8];
      float r = __shfl_xor(s, 2);
      rr[k] = ((lane & 2) ? rr[k + 8] : rr[k]) + r;
    }
#pragma unroll
    for (int k = 0; k < 4; k++) {
      float s = (lane & 4) ? rr[k] : rr[k + 4];
      float r = __shfl_xor(s, 4);
      rr[k] = ((lane & 4) ? rr[k + 4] : rr[k]) + r;
    }
#pragma unroll
    for (int k = 0; k < 2; k++) {
      float s = (lane & 8) ? rr[k] : rr[k + 2];
      float r = __shfl_xor(s, 8);
      rr[k] = ((lane & 8) ? rr[k + 2] : rr[k]) + r;
    }
    {
      float s = (lane & 16) ? rr[0] : rr[1];
      float r = __shfl_xor(s, 16);
      rr[0] = ((lane & 16) ? rr[1] : rr[0]) + r;
    }
    rr[0] += __shfl_xor(rr[0], 32);
    int idx = ((lane & 1) << 4) | ((lane & 2) << 2) | (lane & 4)
            | ((lane & 8) >> 2) | ((lane & 16) >> 4);
    if (lane < 32) s_wr[w][idx] = rr[0];
  }
  __syncthreads();
  if (tid < 32) {
    float v = s_wr[0][tid] + s_wr[1][tid] + s_wr[2][tid] + s_wr[3][tid];
    int r = tid >> 4, c = tid & 15;
    outA[((size_t)h * NPOS + n0 + r) * CHD + c] = v;
  }
}

// -------- final 1x1 conv (4 positions per block, position-major outA) --------
__global__ __launch_bounds__(128) void k_fconv(const float* __restrict__ outA,
                                               const float* __restrict__ outwt,
                                               float* __restrict__ y) {
  int n0 = blockIdx.x * 4;
  int t = threadIdx.x;
  __shared__ __align__(16) float oc[4][DIMC];
  {
    int pos = t >> 5, ch4 = t & 31;
    int head = ch4 >> 2, qq = ch4 & 3;
    float4 v = *(const float4*)(outA + ((size_t)(head * NPOS) + n0 + pos) * CHD + qq * 4);
    *(float4*)&oc[pos][ch4 * 4] = v;
  }
  __syncthreads();
  float acc[4] = {0.f, 0.f, 0.f, 0.f};
  for (int i = 0; i < DIMC; i++) {
    float w = outwt[i * DIMC + t];
#pragma unroll
    for (int p = 0; p < 4; p++) acc[p] += w * oc[p][i];
  }
#pragma unroll
  for (int p = 0; p < 4; p++) y[t * NPOS + n0 + p] = acc[p];
}

extern "C" void kernel_launch(void* const* d_in, const int* in_sizes, int n_in,
                              void* d_out, int out_size, void* d_ws, size_t ws_size,
                              hipStream_t stream) {
  const float* x = (const float*)d_in[0];
  const float* pe_w = (const float*)d_in[1];
  const float* pe_b = (const float*)d_in[2];
  const float* ln_g = (const float*)d_in[3];
  const float* ln_b = (const float*)d_in[4];
  const float* aspp_w1 = (const float*)d_in[5];
  const float* bn1_g = (const float*)d_in[6];
  const float* bn1_b = (const float*)d_in[7];
  const float* bn1_m = (const float*)d_in[8];
  const float* bn1_v = (const float*)d_in[9];
  const float* aspp_w2 = (const float*)d_in[10];
  const float* bn2_g = (const float*)d_in[11];
  const float* bn2_b = (const float*)d_in[12];
  const float* bn2_m = (const float*)d_in[13];
  const float* bn2_v = (const float*)d_in[14];
  const float* proj_w = (const float*)d_in[15];
  const float* bnp_g = (const float*)d_in[16];
  const float* bnp_b = (const float*)d_in[17];
  const float* bnp_m = (const float*)d_in[18];
  const float* bnp_v = (const float*)d_in[19];
  const float* kv_w = (const float*)d_in[20];
  const float* kvdw_w = (const float*)d_in[21];
  const float* out_w = (const float*)d_in[22];
  const float* temperature = (const float*)d_in[23];
  const float* a1 = (const float*)d_in[24];
  const float* a2 = (const float*)d_in[25];
  const float* a3 = (const float*)d_in[26];
  const float* a4 = (const float*)d_in[27];

  float* ws = (float*)d_ws;
  float* xrt = ws;
  float* qraw = ws + 204800;
  float* kv1t = ws + 409600;
  float* kbuf = ws + 819200;
  float* vt = ws + 1024000;
  float* pewt = ws + 1228800;   // transient in qt region
  float* kvt = ws + 1245184;
  float* projt = ws + 1277952;
  float* qt = ws + 1228800;
  float* kt = ws + 1433600;
  float* xt = ws + 1638400;     // shares with outA
  float* outA = ws + 1638400;
  float* w1t = ws + 1843200;
  float* w2t = ws + 1990656;
  float* outwt = ws + 2138112;

  k_prep<<<676, 256, 0, stream>>>(aspp_w1, aspp_w2, proj_w, kv_w, out_w, pe_w, x,
                                  w1t, w2t, projt, kvt, outwt, pewt, xt);
  k_pe_ln<<<400, 128, 0, stream>>>(xt, pewt, pe_b, ln_g, ln_b, xrt);
  k_aspp<<<400, 256, 0, stream>>>(xrt, w1t, w2t, bn1_g, bn1_b, bn1_m, bn1_v,
                                  bn2_g, bn2_b, bn2_m, bn2_v, projt,
                                  bnp_g, bnp_b, bnp_m, bnp_v, qraw);
  k_kv1<<<400, 256, 0, stream>>>(xrt, kvt, kv1t);
  k_dw<<<400, 256, 0, stream>>>(kv1t, kvdw_w, kbuf, vt);
  k_norm<<<256, 256, 0, stream>>>(qraw, kbuf, qt, kt);
  k_attn<<<dim3(800, 8), 256, 0, stream>>>(qt, kt, vt, temperature, a1, a2, a3, a4, outA);
  k_fconv<<<400, 128, 0, stream>>>(outA, outwt, (float*)d_out);
}

// Round 7
// 253.405 us; speedup vs baseline: 3.5607x; 1.0859x over previous
//
#include <hip/hip_runtime.h>

#define NPOS 1600
#define DIMC 128
#define NHEADS 8
#define CHD 16

// ---------------- workspace layout (floats) ----------------
// 0        xrt     204800   (x + LN(pe(x)), position-major [1600][128])
// 204800   qraw    204800   (channel-major, pre-norm q)
// 409600   kv1t    409600   (1600 x 256, position-major)
// 819200   kbuf    204800   (channel-major, pre-norm k)
// 1024000  vt      204800   (position-major [h][m][16])
// 1228800  pewt    16384    \
// 1245184  kvt     32768     } transient (qt region; dead before k_norm writes qt)
// 1277952  projt   32768    /
// 1228800  qt      204800   (written by k_norm, after transients consumed)
// 1433600  kt      204800
// 1638400  xt/outA 204800   (xt consumed before k_attn writes outA)
// 1843200  w1t     147456   ([k][i][o])
// 1990656  w2t     147456
// 2138112  outwt   16384

__device__ __forceinline__ float wsum(float v) {
#pragma unroll
  for (int off = 1; off < 64; off <<= 1) v += __shfl_xor(v, off);
  return v;
}
__device__ __forceinline__ float wmax(float v) {
#pragma unroll
  for (int off = 1; off < 64; off <<= 1) v = fmaxf(v, __shfl_xor(v, off));
  return v;
}

// -------- one-time weight transposes + x transpose (merged) --------
__global__ __launch_bounds__(256) void k_prep(
    const float* __restrict__ w1, const float* __restrict__ w2,
    const float* __restrict__ proj, const float* __restrict__ kvw,
    const float* __restrict__ outw, const float* __restrict__ pew,
    const float* __restrict__ x,
    float* __restrict__ w1t, float* __restrict__ w2t,
    float* __restrict__ projt, float* __restrict__ kvt,
    float* __restrict__ outwt, float* __restrict__ pewt,
    float* __restrict__ xt) {
  int bid = blockIdx.x;
  int t = threadIdx.x;
  __shared__ float tile[DIMC][17];
  if (bid < 576) {
    int idx = bid * 256 + t;
    if (idx < 9 * DIMC * DIMC) {  // [o][i][k] -> [k][i][o]
      int k = idx / (DIMC * DIMC);
      int rem = idx % (DIMC * DIMC);
      int i = rem >> 7, o = rem & 127;
      w1t[idx] = w1[(o * DIMC + i) * 9 + k];
      w2t[idx] = w2[(o * DIMC + i) * 9 + k];
    }
    if (idx < 256 * DIMC) {  // proj [o][ic] -> [ic][o]
      int ic = idx >> 7, o = idx & 127;
      projt[idx] = proj[o * 256 + ic];
    }
    if (idx < DIMC * 256) {  // kv [oc][i] -> [i][oc]
      int i = idx >> 8, oc = idx & 255;
      kvt[idx] = kvw[oc * DIMC + i];
    }
    if (idx < DIMC * DIMC) {  // [o][i] -> [i][o]
      int i = idx >> 7, o = idx & 127;
      outwt[idx] = outw[o * DIMC + i];
      pewt[idx] = pew[o * DIMC + i];
    }
  } else {
    int n0 = (bid - 576) * 16;
#pragma unroll
    for (int pass = 0; pass < 2; pass++) {
      int ch = (t >> 2) + pass * 64, q = t & 3;
      float4 v = *(const float4*)(x + (size_t)ch * NPOS + n0 + q * 4);
      tile[ch][q * 4 + 0] = v.x; tile[ch][q * 4 + 1] = v.y;
      tile[ch][q * 4 + 2] = v.z; tile[ch][q * 4 + 3] = v.w;
    }
    __syncthreads();
    int pos = t >> 4, c8 = (t & 15) * 8;
#pragma unroll
    for (int k = 0; k < 8; k++)
      xt[(size_t)(n0 + pos) * DIMC + c8 + k] = tile[c8 + k][pos];
  }
}

// -------- pe (1x1 conv) + LayerNorm(ch) + residual; position-major in/out --------
__global__ __launch_bounds__(128) void k_pe_ln(
    const float* __restrict__ xt, const float* __restrict__ pewt,
    const float* __restrict__ pb, const float* __restrict__ lg,
    const float* __restrict__ lb, float* __restrict__ xrt) {
  int n0 = blockIdx.x * 4;
  int t = threadIdx.x;
  __shared__ __align__(16) float xc[4][DIMC];
  __shared__ float red[2][2][4];
  {
    int pos = t >> 5, c4 = t & 31;
    *(float4*)&xc[pos][c4 * 4] =
        *(const float4*)(xt + (size_t)(n0 + pos) * DIMC + c4 * 4);
  }
  __syncthreads();
  float pbv = pb[t];
  float acc[4] = {pbv, pbv, pbv, pbv};
  for (int i = 0; i < DIMC; i++) {
    float wv = pewt[i * DIMC + t];
#pragma unroll
    for (int p = 0; p < 4; p++) acc[p] += wv * xc[p][i];
  }
  int w = t >> 6, lane = t & 63;
  {
    float s0 = wsum(acc[0]), s1 = wsum(acc[1]), s2 = wsum(acc[2]), s3 = wsum(acc[3]);
    if (lane == 0) { red[0][w][0] = s0; red[0][w][1] = s1; red[0][w][2] = s2; red[0][w][3] = s3; }
  }
  __syncthreads();
  float mu[4];
#pragma unroll
  for (int p = 0; p < 4; p++) mu[p] = (red[0][0][p] + red[0][1][p]) * (1.f / 128.f);
  {
    float d0 = acc[0] - mu[0], d1 = acc[1] - mu[1], d2 = acc[2] - mu[2], d3 = acc[3] - mu[3];
    float q0 = wsum(d0 * d0), q1 = wsum(d1 * d1), q2 = wsum(d2 * d2), q3 = wsum(d3 * d3);
    if (lane == 0) { red[1][w][0] = q0; red[1][w][1] = q1; red[1][w][2] = q2; red[1][w][3] = q3; }
  }
  __syncthreads();
  float lgv = lg[t], lbv = lb[t];
#pragma unroll
  for (int p = 0; p < 4; p++) {
    float var = (red[1][0][p] + red[1][1][p]) * (1.f / 128.f);
    float tv = (acc[p] - mu[p]) * rsqrtf(var + 1e-5f) * lgv + lbv;
    xrt[(size_t)(n0 + p) * DIMC + t] = xc[p][t] + tv;
  }
}

// -------- merged: ASPP+proj (blocks 0..399) | kv 1x1 (blocks 400..799) --------
__global__ __launch_bounds__(256) void k_aspp_kv1(
    const float* __restrict__ xrt, const float* __restrict__ w1t,
    const float* __restrict__ w2t, const float* __restrict__ bg1,
    const float* __restrict__ bb1, const float* __restrict__ bm1,
    const float* __restrict__ bv1, const float* __restrict__ bg2,
    const float* __restrict__ bb2, const float* __restrict__ bm2,
    const float* __restrict__ bv2, const float* __restrict__ projt,
    const float* __restrict__ bgp, const float* __restrict__ bbp,
    const float* __restrict__ bmp, const float* __restrict__ bvp,
    float* __restrict__ q,
    const float* __restrict__ kvt, float* __restrict__ kv1t) {
  int t = threadIdx.x;
  if (blockIdx.x < 400) {
    // ---- ASPP role ----
    int strip = blockIdx.x;
    int r = strip / 10, c0 = (strip % 10) * 4;
    int ch = t & 127, br = t >> 7;
    __shared__ float xs[2][DIMC][4];
    __shared__ float cat[2 * DIMC][4];
    float aa[4] = {0.f, 0.f, 0.f, 0.f};
    int dil = br ? 5 : 3;
    const float* wt = br ? w2t : w1t;
    for (int k = 0; k < 9; k++) {
      int dr = k / 3 - 1, dc = k % 3 - 1;
      int rr = r + dil * dr;
#pragma unroll
      for (int p = 0; p < 4; p++) {
        int cc = c0 + p + dil * dc;
        xs[br][ch][p] = (rr >= 0 && rr < 40 && cc >= 0 && cc < 40)
                            ? xrt[(size_t)(rr * 40 + cc) * DIMC + ch] : 0.f;
      }
      __syncthreads();
      const float* wrow = wt + (size_t)k * DIMC * DIMC + ch;
      for (int i = 0; i < DIMC; i++) {
        float wv = wrow[i * DIMC];
#pragma unroll
        for (int p = 0; p < 4; p++) aa[p] += wv * xs[br][i][p];
      }
      __syncthreads();
    }
    float sc = br ? bg2[ch] * rsqrtf(bv2[ch] + 1e-5f) : bg1[ch] * rsqrtf(bv1[ch] + 1e-5f);
    float bm = br ? bm2[ch] : bm1[ch];
    float bb = br ? bb2[ch] : bb1[ch];
#pragma unroll
    for (int p = 0; p < 4; p++) cat[br * DIMC + ch][p] = fmaxf((aa[p] - bm) * sc + bb, 0.f);
    __syncthreads();
    float qa0 = 0.f, qa1 = 0.f;
    int pbase = br * 2;
    for (int j = 0; j < 256; j++) {
      float wv = projt[j * DIMC + ch];
      qa0 += wv * cat[j][pbase];
      qa1 += wv * cat[j][pbase + 1];
    }
    float scp = bgp[ch] * rsqrtf(bvp[ch] + 1e-5f);
    q[ch * NPOS + r * 40 + c0 + pbase]     = fmaxf((qa0 - bmp[ch]) * scp + bbp[ch], 0.f);
    q[ch * NPOS + r * 40 + c0 + pbase + 1] = fmaxf((qa1 - bmp[ch]) * scp + bbp[ch], 0.f);
  } else {
    // ---- kv1 role ----
    int n0 = (blockIdx.x - 400) * 4;
    __shared__ __align__(16) float xc[4][DIMC];
    if (t < 128) {
      int pos = t >> 5, c4 = t & 31;
      *(float4*)&xc[pos][c4 * 4] =
          *(const float4*)(xrt + (size_t)(n0 + pos) * DIMC + c4 * 4);
    }
    __syncthreads();
    float acc[4] = {0.f, 0.f, 0.f, 0.f};
    for (int i = 0; i < DIMC; i++) {
      float w = kvt[i * 256 + t];
#pragma unroll
      for (int p = 0; p < 4; p++) acc[p] += w * xc[p][i];
    }
#pragma unroll
    for (int p = 0; p < 4; p++) kv1t[(n0 + p) * 256 + t] = acc[p];
  }
}

// -------- depthwise 3x3 (4-col strips): k -> channel-major, v -> position-major --------
__global__ __launch_bounds__(256) void k_dw(const float* __restrict__ kv1t,
                                            const float* __restrict__ dww,
                                            float* __restrict__ kbuf,
                                            float* __restrict__ vt) {
  int strip = blockIdx.x;
  int r = strip / 10, c0 = (strip % 10) * 4;
  int t = threadIdx.x;
  float wl[9];
#pragma unroll
  for (int k = 0; k < 9; k++) wl[k] = dww[t * 9 + k];
  for (int p = 0; p < 4; p++) {
    int c = c0 + p;
    float acc = 0.f;
#pragma unroll
    for (int kh = 0; kh < 3; kh++) {
      int rr = r + kh - 1;
      if (rr < 0 || rr >= 40) continue;
#pragma unroll
      for (int kw_ = 0; kw_ < 3; kw_++) {
        int cc = c + kw_ - 1;
        if (cc < 0 || cc >= 40) continue;
        acc += wl[kh * 3 + kw_] * kv1t[(rr * 40 + cc) * 256 + t];
      }
    }
    int pos = r * 40 + c;
    if (t < DIMC) {
      kbuf[t * NPOS + pos] = acc;
    } else {
      int cv = t - DIMC;
      vt[((size_t)(cv >> 4) * NPOS + pos) * CHD + (cv & 15)] = acc;
    }
  }
}

// -------- per-channel L2 norm (q and k merged), write position-major --------
__global__ __launch_bounds__(256) void k_norm(const float* __restrict__ qraw,
                                              const float* __restrict__ kbuf,
                                              float* __restrict__ qt,
                                              float* __restrict__ kt) {
  int b = blockIdx.x, t = threadIdx.x;
  const float* in = (b < 128) ? qraw : kbuf;
  float* out_t = (b < 128) ? qt : kt;
  int ch = b & 127;
  __shared__ float wred[4];
  float ss = 0.f;
  for (int m = t; m < NPOS; m += 256) {
    float v = in[ch * NPOS + m];
    ss += v * v;
  }
  ss = wsum(ss);
  if ((t & 63) == 0) wred[t >> 6] = ss;
  __syncthreads();
  float tot = wred[0] + wred[1] + wred[2] + wred[3];
  float inv = 1.0f / fmaxf(sqrtf(tot), 1e-12f);
  int h = ch >> 4, c = ch & 15;
  for (int m = t; m < NPOS; m += 256)
    out_t[((size_t)(h * NPOS) + m) * CHD + c] = in[ch * NPOS + m] * inv;
}

// -------- fused attention: 2 rows/block, row-split select, 24-bit thresholds --------
#define RANK_STEP(INCL, S0, S1, S2, S3, REM, TT)                         \
  {                                                                      \
    int abv = (INCL) - (S0);                                             \
    int ge1 = abv + (S1), ge2 = abv + (S2), ge3 = abv + (S3);            \
    bool hit = ((INCL) >= (REM)) && (abv < (REM));                       \
    bool c0_ = hit && (ge1 < (REM));                                     \
    bool c1_ = hit && (ge1 >= (REM)) && (ge2 < (REM));                   \
    bool c2_ = hit && (ge2 >= (REM)) && (ge3 < (REM));                   \
    int bl = c0_ ? 4 * lane : c1_ ? 4 * lane + 1                         \
           : c2_ ? 4 * lane + 2 : 4 * lane + 3;                          \
    int gl = c0_ ? ge1 : c1_ ? ge2 : c2_ ? ge3 : abv;                    \
    unsigned long long bal = __ballot(hit);                              \
    int wl = (int)__ffsll(bal) - 1;                                      \
    TT |= ((unsigned)__shfl(bl, wl)) << ls;                              \
    REM -= __shfl(gl, wl);                                               \
  }

__global__ __launch_bounds__(256) void k_attn(
    const float* __restrict__ qt, const float* __restrict__ kt,
    const float* __restrict__ vt, const float* __restrict__ temp,
    const float* __restrict__ a1p, const float* __restrict__ a2p,
    const float* __restrict__ a3p, const float* __restrict__ a4p,
    float* __restrict__ outA) {
  __shared__ unsigned hist[2][2][4][256];  // [buf][row][group|copy][bin], 16 KB
  __shared__ float s_rm[2][4];
  __shared__ unsigned s_thr[2][4];
  __shared__ float s_z[4][8];
  __shared__ float s_wr[4][32];

  int tid = threadIdx.x;
  int lane = tid & 63, w = tid >> 6;
  int myrow = w >> 1;
  int n0 = blockIdx.x * 2;
  int h = blockIdx.y;

  float tmpr = temp[h];
  const float* kbase = kt + (size_t)h * NPOS * CHD;
  const float* vbase = vt + (size_t)h * NPOS * CHD;

  const float4* q4a = (const float4*)(qt + ((size_t)h * NPOS + n0) * CHD);
  const float4* q4b = (const float4*)(qt + ((size_t)h * NPOS + n0 + 1) * CHD);
  float4 qa0 = q4a[0], qa1 = q4a[1], qa2 = q4a[2], qa3 = q4a[3];
  float4 qb0 = q4b[0], qb1 = q4b[1], qb2 = q4b[2], qb3 = q4b[3];

  // zero buf0 (overlaps with QK^T)
  ((uint4*)hist)[tid] = make_uint4(0u, 0u, 0u, 0u);
  ((uint4*)hist)[tid + 256] = make_uint4(0u, 0u, 0u, 0u);

  unsigned u0[7], u1[7];
  float smax0 = -1e30f, smax1 = -1e30f;
#pragma unroll
  for (int i = 0; i < 7; i++) {
    int m = tid + (i << 8);
    const float4* k4 = (const float4*)(kbase + (size_t)m * CHD);
    float4 ka = k4[0], kb = k4[1], kc = k4[2], kd = k4[3];
    float s0 = qa0.x * ka.x + qa0.y * ka.y + qa0.z * ka.z + qa0.w * ka.w
             + qa1.x * kb.x + qa1.y * kb.y + qa1.z * kb.z + qa1.w * kb.w
             + qa2.x * kc.x + qa2.y * kc.y + qa2.z * kc.z + qa2.w * kc.w
             + qa3.x * kd.x + qa3.y * kd.y + qa3.z * kd.z + qa3.w * kd.w;
    float s1 = qb0.x * ka.x + qb0.y * ka.y + qb0.z * ka.z + qb0.w * ka.w
             + qb1.x * kb.x + qb1.y * kb.y + qb1.z * kb.z + qb1.w * kb.w
             + qb2.x * kc.x + qb2.y * kc.y + qb2.z * kc.z + qb2.w * kc.w
             + qb3.x * kd.x + qb3.y * kd.y + qb3.z * kd.z + qb3.w * kd.w;
    s0 *= tmpr; s1 *= tmpr;
    bool valid = (m < NPOS);
    smax0 = fmaxf(smax0, valid ? s0 : -1e30f);
    smax1 = fmaxf(smax1, valid ? s1 : -1e30f);
    int b0 = __float_as_int(s0), b1 = __float_as_int(s1);
    unsigned uu0 = ((unsigned)b0) ^ ((b0 < 0) ? 0xFFFFFFFFu : 0x80000000u);
    unsigned uu1 = ((unsigned)b1) ^ ((b1 < 0) ? 0xFFFFFFFFu : 0x80000000u);
    u0[i] = valid ? uu0 : 0x00800000u;  // pad decodes to -3.4e38 -> e = 0
    u1[i] = valid ? uu1 : 0x00800000u;
  }
  {
    float m0 = wmax(smax0), m1 = wmax(smax1);
    if (lane == 0) { s_rm[0][w] = m0; s_rm[1][w] = m1; }
  }
  __syncthreads();  // buf0 zeroed, s_rm written

  unsigned t00 = 0, t01 = 0, t02 = 0, t03 = 0;
  unsigned t10 = 0, t11 = 0, t12 = 0, t13 = 0;
  int r00 = 800, r01 = 1066, r02 = 1200, r03 = 1280;
  int r10 = 800, r11 = 1066, r12 = 1200, r13 = 1280;

  // 3 levels only: bytes 3,2,1. Final thresholds are 24-bit prefixes << 8;
  // `u >= thr` then includes all 24-bit ties (exact-equal to 2^-16 rel; ~never).
#pragma unroll
  for (int level = 3; level >= 1; level--) {
    const int ls = level * 8;
    const unsigned pm = (level == 3) ? 0u : (0xFFFFFFFFu << (ls + 8));
    const int p = (3 - level) & 1;  // 3->0, 2->1, 1->0

    if (level == 3) {
      // single prefix group -> use group slots as per-wave copies (4x less contention)
#pragma unroll
      for (int i = 0; i < 7; i++) {
        atomicAdd(&hist[p][0][w][u0[i] >> 24], 1u);
        atomicAdd(&hist[p][1][w][u1[i] >> 24], 1u);
      }
    } else {
      unsigned P00 = t00 & pm, P01 = t01 & pm, P02 = t02 & pm, P03 = t03 & pm;
      unsigned P10 = t10 & pm, P11 = t11 & pm, P12 = t12 & pm, P13 = t13 & pm;
      // first-match group id (nested prefixes make dedup flags unnecessary here)
#pragma unroll
      for (int i = 0; i < 7; i++) {
        {
          unsigned uu = u0[i], pf = uu & pm;
          int g = (pf == P00) ? 0 : (pf == P01) ? 1 : (pf == P02) ? 2
                : (pf == P03) ? 3 : -1;
          if (g >= 0) atomicAdd(&hist[p][0][g][(uu >> ls) & 255], 1u);
        }
        {
          unsigned uu = u1[i], pf = uu & pm;
          int g = (pf == P10) ? 0 : (pf == P11) ? 1 : (pf == P12) ? 2
                : (pf == P13) ? 3 : -1;
          if (g >= 0) atomicAdd(&hist[p][1][g][(uu >> ls) & 255], 1u);
        }
      }
    }
    __syncthreads();  // atomics visible

    // zero the other buffer for the next level (none needed after level 1)
    if (level != 1) {
      ((uint4*)(&hist[p ^ 1][0][0][0]))[tid] = make_uint4(0u, 0u, 0u, 0u);
      ((uint4*)(&hist[p ^ 1][0][0][0]))[tid + 256] = make_uint4(0u, 0u, 0u, 0u);
    }

    // ---- row-split select: waves 0-1 handle row 0, waves 2-3 row 1 ----
    unsigned ta0, ta1, ta2, ta3;
    int ra0, ra1, ra2, ra3;
    if (myrow == 0) { ta0 = t00; ta1 = t01; ta2 = t02; ta3 = t03;
                      ra0 = r00; ra1 = r01; ra2 = r02; ra3 = r03; }
    else            { ta0 = t10; ta1 = t11; ta2 = t12; ta3 = t13;
                      ra0 = r10; ra1 = r11; ra2 = r12; ra3 = r13; }

    uint4 c0 = *(const uint4*)&hist[p][myrow][0][lane * 4];
    uint4 c1 = *(const uint4*)&hist[p][myrow][1][lane * 4];
    uint4 c2 = *(const uint4*)&hist[p][myrow][2][lane * 4];
    uint4 c3 = *(const uint4*)&hist[p][myrow][3][lane * 4];
    bool L1, L2, L3;
    if (level == 3) {
      c0.x += c1.x + c2.x + c3.x;  // merge per-wave copies
      c0.y += c1.y + c2.y + c3.y;
      c0.z += c1.z + c2.z + c3.z;
      c0.w += c1.w + c2.w + c3.w;
      L1 = false; L2 = false; L3 = false;
    } else {
      L1 = ((ta1 & pm) != (ta0 & pm));
      L2 = ((ta2 & pm) != (ta1 & pm));
      L3 = ((ta3 & pm) != (ta2 & pm));
    }

    int s3_0 = c0.w, s2_0 = s3_0 + c0.z, s1_0 = s2_0 + c0.y, s0_0 = s1_0 + c0.x;
    int s3_1 = c1.w, s2_1 = s3_1 + c1.z, s1_1 = s2_1 + c1.y, s0_1 = s1_1 + c1.x;
    int s3_2 = c2.w, s2_2 = s3_2 + c2.z, s1_2 = s2_2 + c2.y, s0_2 = s1_2 + c2.x;
    int s3_3 = c3.w, s2_3 = s3_3 + c3.z, s1_3 = s2_3 + c3.y, s0_3 = s1_3 + c3.x;

    unsigned vA = (unsigned)s0_0 | ((unsigned)s0_1 << 16);
    unsigned vB = (unsigned)s0_2 | ((unsigned)s0_3 << 16);
#pragma unroll
    for (int off = 1; off < 64; off <<= 1) {
      unsigned xA = __shfl_down(vA, off), xB = __shfl_down(vB, off);
      if (lane + off < 64) { vA += xA; vB += xB; }
    }
    int i0 = (int)(vA & 0xFFFFu), i1 = (int)(vA >> 16);
    int i2 = (int)(vB & 0xFFFFu), i3 = (int)(vB >> 16);

    RANK_STEP(i0, s0_0, s1_0, s2_0, s3_0, ra0, ta0);
    int I1 = L1 ? i1 : i0;
    int S0a = L1 ? s0_1 : s0_0, S1a = L1 ? s1_1 : s1_0;
    int S2a = L1 ? s2_1 : s2_0, S3a = L1 ? s3_1 : s3_0;
    RANK_STEP(I1, S0a, S1a, S2a, S3a, ra1, ta1);
    int I2 = L2 ? i2 : I1;
    int S0b = L2 ? s0_2 : S0a, S1b = L2 ? s1_2 : S1a;
    int S2b = L2 ? s2_2 : S2a, S3b = L2 ? s3_2 : S3a;
    RANK_STEP(I2, S0b, S1b, S2b, S3b, ra2, ta2);
    int I3 = L3 ? i3 : I2;
    int S0c = L3 ? s0_3 : S0b, S1c = L3 ? s1_3 : S1b;
    int S2c = L3 ? s2_3 : S2b, S3c = L3 ? s3_3 : S3b;
    RANK_STEP(I3, S0c, S1c, S2c, S3c, ra3, ta3);

    // publish winners (one wave per row suffices; values wave-uniform)
    if (lane == 0 && (w & 1) == 0) {
      s_thr[myrow][0] = ta0; s_thr[myrow][1] = ta1;
      s_thr[myrow][2] = ta2; s_thr[myrow][3] = ta3;
    }
    // write back own-row registers
    if (myrow == 0) { t00 = ta0; t01 = ta1; t02 = ta2; t03 = ta3;
                      r00 = ra0; r01 = ra1; r02 = ra2; r03 = ra3; }
    else            { t10 = ta0; t11 = ta1; t12 = ta2; t13 = ta3;
                      r10 = ra0; r11 = ra1; r12 = ra2; r13 = ra3; }
    __syncthreads();  // zeroing + publications visible
    // refresh other row's prefixes (needed for next histogram pass)
    if (myrow == 0) { t10 = s_thr[1][0]; t11 = s_thr[1][1];
                      t12 = s_thr[1][2]; t13 = s_thr[1][3]; }
    else            { t00 = s_thr[0][0]; t01 = s_thr[0][1];
                      t02 = s_thr[0][2]; t03 = s_thr[0][3]; }
  }

  float rmax0 = fmaxf(fmaxf(s_rm[0][0], s_rm[0][1]), fmaxf(s_rm[0][2], s_rm[0][3]));
  float rmax1 = fmaxf(fmaxf(s_rm[1][0], s_rm[1][1]), fmaxf(s_rm[1][2], s_rm[1][3]));

  // ---- single exp pass: Z sums + pack (e, bucket) into u regs ----
  float z00 = 0.f, z01 = 0.f, z02 = 0.f, z03 = 0.f;
  float z10 = 0.f, z11 = 0.f, z12 = 0.f, z13 = 0.f;
#pragma unroll
  for (int i = 0; i < 7; i++) {
    {
      unsigned uu = u0[i];
      int bits = (uu & 0x80000000u) ? (int)(uu ^ 0x80000000u) : (int)(~uu);
      float e = __expf(__int_as_float(bits) - rmax0);
      int b; float ee;
      if (uu >= t01) { b = (uu >= t00) ? 0 : 1; ee = e; }
      else if (uu >= t03) { b = (uu >= t02) ? 2 : 3; ee = e; }
      else { b = 3; ee = 0.f; }
      z00 += (b == 0) ? ee : 0.f;
      z01 += (b <= 1) ? ee : 0.f;
      z02 += (b <= 2) ? ee : 0.f;
      z03 += ee;
      u0[i] = (__float_as_uint(ee) & ~3u) | (unsigned)b;
    }
    {
      unsigned uu = u1[i];
      int bits = (uu & 0x80000000u) ? (int)(uu ^ 0x80000000u) : (int)(~uu);
      float e = __expf(__int_as_float(bits) - rmax1);
      int b; float ee;
      if (uu >= t11) { b = (uu >= t10) ? 0 : 1; ee = e; }
      else if (uu >= t13) { b = (uu >= t12) ? 2 : 3; ee = e; }
      else { b = 3; ee = 0.f; }
      z10 += (b == 0) ? ee : 0.f;
      z11 += (b <= 1) ? ee : 0.f;
      z12 += (b <= 2) ? ee : 0.f;
      z13 += ee;
      u1[i] = (__float_as_uint(ee) & ~3u) | (unsigned)b;
    }
  }
  // butterfly distribute-reduce: 8 Z values
  {
    float zv[8] = {z00, z01, z02, z03, z10, z11, z12, z13};
#pragma unroll
    for (int k = 0; k < 4; k++) {
      float s = (lane & 1) ? zv[k] : zv[k + 4];
      float r = __shfl_xor(s, 1);
      zv[k] = ((lane & 1) ? zv[k + 4] : zv[k]) + r;
    }
#pragma unroll
    for (int k = 0; k < 2; k++) {
      float s = (lane & 2) ? zv[k] : zv[k + 2];
      float r = __shfl_xor(s, 2);
      zv[k] = ((lane & 2) ? zv[k + 2] : zv[k]) + r;
    }
    {
      float s = (lane & 4) ? zv[0] : zv[1];
      float r = __shfl_xor(s, 4);
      zv[0] = ((lane & 4) ? zv[1] : zv[0]) + r;
    }
    zv[0] += __shfl_xor(zv[0], 8);
    zv[0] += __shfl_xor(zv[0], 16);
    zv[0] += __shfl_xor(zv[0], 32);
    int zidx = ((lane & 1) << 2) | (lane & 2) | ((lane & 4) >> 2);
    if (lane < 8) s_z[w][zidx] = zv[0];
  }
  __syncthreads();
  float Z[8];
#pragma unroll
  for (int j = 0; j < 8; j++) Z[j] = s_z[0][j] + s_z[1][j] + s_z[2][j] + s_z[3][j];
  float A1 = a1p[0], A2 = a2p[0], A3 = a3p[0], A4 = a4p[0];
  float c03v = A4 / Z[3], c02v = c03v + A3 / Z[2];
  float c01v = c02v + A2 / Z[1], c00v = c01v + A1 / Z[0];
  float c13v = A4 / Z[7], c12v = c13v + A3 / Z[6];
  float c11v = c12v + A2 / Z[5], c10v = c11v + A1 / Z[4];

  // ---- PV ----
  float4 o0A = make_float4(0.f, 0.f, 0.f, 0.f), o0B = o0A, o0C = o0A, o0D = o0A;
  float4 o1A = o0A, o1B = o0A, o1C = o0A, o1D = o0A;
#pragma unroll
  for (int i = 0; i < 7; i++) {
    int m = tid + (i << 8);
    unsigned pe0 = u0[i];
    int b0 = pe0 & 3;
    float wg0 = __uint_as_float(pe0 & ~3u)
              * ((b0 == 0) ? c00v : (b0 == 1) ? c01v : (b0 == 2) ? c02v : c03v);
    unsigned pe1 = u1[i];
    int b1 = pe1 & 3;
    float wg1 = __uint_as_float(pe1 & ~3u)
              * ((b1 == 0) ? c10v : (b1 == 1) ? c11v : (b1 == 2) ? c12v : c13v);
    const float4* v4 = (const float4*)(vbase + (size_t)m * CHD);
    float4 va = v4[0], vb = v4[1], vc = v4[2], vd = v4[3];
    o0A.x += wg0 * va.x; o0A.y += wg0 * va.y; o0A.z += wg0 * va.z; o0A.w += wg0 * va.w;
    o0B.x += wg0 * vb.x; o0B.y += wg0 * vb.y; o0B.z += wg0 * vb.z; o0B.w += wg0 * vb.w;
    o0C.x += wg0 * vc.x; o0C.y += wg0 * vc.y; o0C.z += wg0 * vc.z; o0C.w += wg0 * vc.w;
    o0D.x += wg0 * vd.x; o0D.y += wg0 * vd.y; o0D.z += wg0 * vd.z; o0D.w += wg0 * vd.w;
    o1A.x += wg1 * va.x; o1A.y += wg1 * va.y; o1A.z += wg1 * va.z; o1A.w += wg1 * va.w;
    o1B.x += wg1 * vb.x; o1B.y += wg1 * vb.y; o1B.z += wg1 * vb.z; o1B.w += wg1 * vb.w;
    o1C.x += wg1 * vc.x; o1C.y += wg1 * vc.y; o1C.z += wg1 * vc.z; o1C.w += wg1 * vc.w;
    o1D.x += wg1 * vd.x; o1D.y += wg1 * vd.y; o1D.z += wg1 * vd.z; o1D.w += wg1 * vd.w;
  }
  {
    float rr[32] = {o0A.x, o0A.y, o0A.z, o0A.w, o0B.x, o0B.y, o0B.z, o0B.w,
                    o0C.x, o0C.y, o0C.z, o0C.w, o0D.x, o0D.y, o0D.z, o0D.w,
                    o1A.x, o1A.y, o1A.z, o1A.w, o1B.x, o1B.y, o1B.z, o1B.w,
                    o1C.x, o1C.y, o1C.z, o1C.w, o1D.x, o1D.y, o1D.z, o1D.w};
#pragma unroll
    for (int k = 0; k < 16; k++) {
      float s = (lane & 1) ? rr[k] : rr[k + 16];
      float r = __shfl_xor(s, 1);
      rr[k] = ((lane & 1) ? rr[k + 16] : rr[k]) + r;
    }
#pragma unroll
    for (int k = 0; k < 8; k++) {
      float s = (lane & 2) ? rr[k] : rr[k + 8];
      float r = __shfl_xor(s, 2);
      rr[k] = ((lane & 2) ? rr[k + 8] : rr[k]) + r;
    }
#pragma unroll
    for (int k = 0; k < 4; k++) {
      float s = (lane & 4) ? rr[k] : rr[k + 4];
      float r = __shfl_xor(s, 4);
      rr[k] = ((lane & 4) ? rr[k + 4] : rr[k]) + r;
    }
#pragma unroll
    for (int k = 0; k < 2; k++) {
      float s = (lane & 8) ? rr[k] : rr[k + 2];
      float r = __shfl_xor(s, 8);
      rr[k] = ((lane & 8) ? rr[k + 2] : rr[k]) + r;
    }
    {
      float s = (lane & 16) ? rr[0] : rr[1];
      float r = __shfl_xor(s, 16);
      rr[0] = ((lane & 16) ? rr[1] : rr[0]) + r;
    }
    rr[0] += __shfl_xor(rr[0], 32);
    int idx = ((lane & 1) << 4) | ((lane & 2) << 2) | (lane & 4)
            | ((lane & 8) >> 2) | ((lane & 16) >> 4);
    if (lane < 32) s_wr[w][idx] = rr[0];
  }
  __syncthreads();
  if (tid < 32) {
    float v = s_wr[0][tid] + s_wr[1][tid] + s_wr[2][tid] + s_wr[3][tid];
    int r = tid >> 4, c = tid & 15;
    outA[((size_t)h * NPOS + n0 + r) * CHD + c] = v;
  }
}

// -------- final 1x1 conv (4 positions per block, position-major outA) --------
__global__ __launch_bounds__(128) void k_fconv(const float* __restrict__ outA,
                                               const float* __restrict__ outwt,
                                               float* __restrict__ y) {
  int n0 = blockIdx.x * 4;
  int t = threadIdx.x;
  __shared__ __align__(16) float oc[4][DIMC];
  {
    int pos = t >> 5, ch4 = t & 31;
    int head = ch4 >> 2, qq = ch4 & 3;
    float4 v = *(const float4*)(outA + ((size_t)(head * NPOS) + n0 + pos) * CHD + qq * 4);
    *(float4*)&oc[pos][ch4 * 4] = v;
  }
  __syncthreads();
  float acc[4] = {0.f, 0.f, 0.f, 0.f};
  for (int i = 0; i < DIMC; i++) {
    float w = outwt[i * DIMC + t];
#pragma unroll
    for (int p = 0; p < 4; p++) acc[p] += w * oc[p][i];
  }
#pragma unroll
  for (int p = 0; p < 4; p++) y[t * NPOS + n0 + p] = acc[p];
}

extern "C" void kernel_launch(void* const* d_in, const int* in_sizes, int n_in,
                              void* d_out, int out_size, void* d_ws, size_t ws_size,
                              hipStream_t stream) {
  const float* x = (const float*)d_in[0];
  const float* pe_w = (const float*)d_in[1];
  const float* pe_b = (const float*)d_in[2];
  const float* ln_g = (const float*)d_in[3];
  const float* ln_b = (const float*)d_in[4];
  const float* aspp_w1 = (const float*)d_in[5];
  const float* bn1_g = (const float*)d_in[6];
  const float* bn1_b = (const float*)d_in[7];
  const float* bn1_m = (const float*)d_in[8];
  const float* bn1_v = (const float*)d_in[9];
  const float* aspp_w2 = (const float*)d_in[10];
  const float* bn2_g = (const float*)d_in[11];
  const float* bn2_b = (const float*)d_in[12];
  const float* bn2_m = (const float*)d_in[13];
  const float* bn2_v = (const float*)d_in[14];
  const float* proj_w = (const float*)d_in[15];
  const float* bnp_g = (const float*)d_in[16];
  const float* bnp_b = (const float*)d_in[17];
  const float* bnp_m = (const float*)d_in[18];
  const float* bnp_v = (const float*)d_in[19];
  const float* kv_w = (const float*)d_in[20];
  const float* kvdw_w = (const float*)d_in[21];
  const float* out_w = (const float*)d_in[22];
  const float* temperature = (const float*)d_in[23];
  const float* a1 = (const float*)d_in[24];
  const float* a2 = (const float*)d_in[25];
  const float* a3 = (const float*)d_in[26];
  const float* a4 = (const float*)d_in[27];

  float* ws = (float*)d_ws;
  float* xrt = ws;
  float* qraw = ws + 204800;
  float* kv1t = ws + 409600;
  float* kbuf = ws + 819200;
  float* vt = ws + 1024000;
  float* pewt = ws + 1228800;   // transient in qt region
  float* kvt = ws + 1245184;
  float* projt = ws + 1277952;
  float* qt = ws + 1228800;
  float* kt = ws + 1433600;
  float* xt = ws + 1638400;     // shares with outA
  float* outA = ws + 1638400;
  float* w1t = ws + 1843200;
  float* w2t = ws + 1990656;
  float* outwt = ws + 2138112;

  k_prep<<<676, 256, 0, stream>>>(aspp_w1, aspp_w2, proj_w, kv_w, out_w, pe_w, x,
                                  w1t, w2t, projt, kvt, outwt, pewt, xt);
  k_pe_ln<<<400, 128, 0, stream>>>(xt, pewt, pe_b, ln_g, ln_b, xrt);
  k_aspp_kv1<<<800, 256, 0, stream>>>(xrt, w1t, w2t, bn1_g, bn1_b, bn1_m, bn1_v,
                                      bn2_g, bn2_b, bn2_m, bn2_v, projt,
                                      bnp_g, bnp_b, bnp_m, bnp_v, qraw,
                                      kvt, kv1t);
  k_dw<<<400, 256, 0, stream>>>(kv1t, kvdw_w, kbuf, vt);
  k_norm<<<256, 256, 0, stream>>>(qraw, kbuf, qt, kt);
  k_attn<<<dim3(800, 8), 256, 0, stream>>>(qt, kt, vt, temperature, a1, a2, a3, a4, outA);
  k_fconv<<<400, 128, 0, stream>>>(outA, outwt, (float*)d_out);
}